// Round 2
// baseline (2733.302 us; speedup 1.0000x reference)
//
#include <hip/hip_runtime.h>

typedef unsigned short u16;
typedef unsigned int   u32;
typedef __bf16  bf16x8 __attribute__((ext_vector_type(8)));
typedef float   f32x4  __attribute__((ext_vector_type(4)));

#define B_   16
#define S_   512
#define H_   768
#define NH_  12
#define L_   6
#define FF_  3072
#define M_   8192     // B_*S_
#define LAB_ 10
#define STRQ 2304     // merged qkv row stride

// ---------- bf16 helpers (storage = u16 bits) ----------
__device__ __forceinline__ float b2f(u16 x) {
    u32 u = ((u32)x) << 16; float f; __builtin_memcpy(&f, &u, 4); return f;
}
__device__ __forceinline__ u16 f2b(float f) {
    u32 u; __builtin_memcpy(&u, &f, 4);
    u32 r = u + 0x7FFFu + ((u >> 16) & 1u);
    return (u16)(r >> 16);
}
__device__ __forceinline__ float lda(const void* p, size_t i, int bf) {
    return bf ? b2f(((const u16*)p)[i]) : ((const float*)p)[i];
}
__device__ __forceinline__ float gelu_tanh(float x) {
    return 0.5f * x * (1.0f + tanhf(0.7978845608028654f * (x + 0.044715f * x * x * x)));
}
// async global->LDS, 16B per lane; LDS dest must be wave-uniform base + lane*16
__device__ __forceinline__ void async_lds16(const u16* g, u16* l) {
    __builtin_amdgcn_global_load_lds(
        (const __attribute__((address_space(1))) u32*)(const void*)g,
        (__attribute__((address_space(3))) u32*)(void*)l, 16, 0, 0);
}
// counted vmcnt wait (immediate must be literal -> constexpr dispatch)
template<int N_> __device__ __forceinline__ void vmw() {
    if constexpr (N_ == 8)      asm volatile("s_waitcnt vmcnt(8)" ::: "memory");
    else if constexpr (N_ == 6) asm volatile("s_waitcnt vmcnt(6)" ::: "memory");
    else if constexpr (N_ == 4) asm volatile("s_waitcnt vmcnt(4)" ::: "memory");
    else if constexpr (N_ == 3) asm volatile("s_waitcnt vmcnt(3)" ::: "memory");
    else if constexpr (N_ == 2) asm volatile("s_waitcnt vmcnt(2)" ::: "memory");
    else                        asm volatile("s_waitcnt vmcnt(0)" ::: "memory");
}

// ---------- dtype detect: emb_ln_g is all ones ----------
__global__ void detect_kernel(const u32* __restrict__ g, int* __restrict__ flag) {
    flag[0] = (g[0] == 0x3F803F80u) ? 1 : 0;   // bf16 ones pair vs fp32 one
}

// ---------- block reduce (sum of two values), 256 threads ----------
__device__ __forceinline__ void block_reduce2(float& s, float& s2, float* red, int tid) {
    int lane = tid & 63, wave = tid >> 6;
    #pragma unroll
    for (int m = 32; m >= 1; m >>= 1) { s += __shfl_xor(s, m); s2 += __shfl_xor(s2, m); }
    if (lane == 0) { red[wave] = s; red[4 + wave] = s2; }
    __syncthreads();
    s  = red[0] + red[1] + red[2] + red[3];
    s2 = red[4] + red[5] + red[6] + red[7];
}

// ---------- weight transpose+convert: in (K x N) -> out bf16 (N x K) ----------
__global__ __launch_bounds__(256) void transpose_k(const void* __restrict__ in,
                                                   u16* __restrict__ out, int K, int N,
                                                   long in_lstride, long out_lstride,
                                                   const int* __restrict__ fl) {
    __shared__ u16 tile[64][65];
    const int bf = fl[0];
    const size_t ioff = (size_t)blockIdx.z * (size_t)in_lstride;
    const size_t ooff = (size_t)blockIdx.z * (size_t)out_lstride;
    int k0 = blockIdx.y * 64, n0 = blockIdx.x * 64;
    int c = threadIdx.x & 63, r0 = threadIdx.x >> 6;
    #pragma unroll
    for (int r = r0; r < 64; r += 4) {
        size_t idx = ioff + (size_t)(k0 + r) * N + n0 + c;
        tile[r][c] = bf ? ((const u16*)in)[idx] : f2b(((const float*)in)[idx]);
    }
    __syncthreads();
    #pragma unroll
    for (int r = r0; r < 64; r += 4)
        out[ooff + (size_t)(n0 + r) * K + k0 + c] = tile[c][r];
}

// ---------- bias prep: convert all GEMM biases to bf16, qkv concatenated ----------
// layout: [0,13824) bqkv (6 x 2304) | [13824,18432) bo | [18432,36864) bf1 | [36864,41472) bf2
__global__ __launch_bounds__(256) void prep_bias(
    const void* __restrict__ bq, const void* __restrict__ bk, const void* __restrict__ bv,
    const void* __restrict__ bo, const void* __restrict__ bf1, const void* __restrict__ bf2,
    u16* __restrict__ out, const int* __restrict__ fl) {
    const int bf = fl[0];
    int i = blockIdx.x * 256 + threadIdx.x;
    if (i >= 41472) return;
    float v;
    if (i < 13824) {
        int l = i / 2304, c = i % 2304;
        v = (c < 768) ? lda(bq, (size_t)l * 768 + c, bf)
          : (c < 1536) ? lda(bk, (size_t)l * 768 + c - 768, bf)
                       : lda(bv, (size_t)l * 768 + c - 1536, bf);
    } else if (i < 18432) v = lda(bo,  i - 13824, bf);
    else if (i < 36864)   v = lda(bf1, i - 18432, bf);
    else                  v = lda(bf2, i - 36864, bf);
    out[i] = f2b(v);
}

// ---------- embedding + LN + selection scale ----------
__global__ __launch_bounds__(256) void embed_kernel(
    const int* __restrict__ src, const int* __restrict__ seg, const int* __restrict__ tib,
    const void* __restrict__ we, const void* __restrict__ pe, const void* __restrict__ se,
    const void* __restrict__ g, const void* __restrict__ bb, const void* __restrict__ sf,
    float* __restrict__ x32, u16* __restrict__ xb, const int* __restrict__ fl) {
    __shared__ float red[8];
    const int bf = fl[0];
    const int r = blockIdx.x, tid = threadIdx.x;
    const int s = r & (S_ - 1);
    const int w = src[r], sg = seg[r];
    const float scale = lda(sf, tib[r], bf);
    float v[3]; int col[3];
    #pragma unroll
    for (int i = 0; i < 3; ++i) {
        col[i] = tid + i * 256;
        v[i] = lda(we, (size_t)w * H_ + col[i], bf) + lda(pe, (size_t)s * H_ + col[i], bf)
             + lda(se, (size_t)sg * H_ + col[i], bf);
    }
    float su = v[0] + v[1] + v[2];
    float sq = v[0]*v[0] + v[1]*v[1] + v[2]*v[2];
    block_reduce2(su, sq, red, tid);
    const float mean = su * (1.0f / H_);
    const float var  = sq * (1.0f / H_) - mean * mean;
    const float inv  = rsqrtf(var + 1e-5f);
    #pragma unroll
    for (int i = 0; i < 3; ++i) {
        float y = ((v[i] - mean) * inv * lda(g, col[i], bf) + lda(bb, col[i], bf)) * scale;
        x32[(size_t)r * H_ + col[i]] = y;
        xb [(size_t)r * H_ + col[i]] = f2b(y);
    }
}

// ---------- residual add + LN (x32 master, bf16 shadow out) ----------
__global__ __launch_bounds__(256) void add_ln_kernel(
    const float* __restrict__ xin, const u16* __restrict__ t,
    const void* __restrict__ g, const void* __restrict__ bb, long goff,
    float* __restrict__ xout, u16* __restrict__ xb, const int* __restrict__ fl) {
    __shared__ float red[8];
    const int bf = fl[0];
    const int r = blockIdx.x, tid = threadIdx.x;
    const size_t rb = (size_t)r * H_;
    float v[3]; int col[3];
    #pragma unroll
    for (int i = 0; i < 3; ++i) {
        col[i] = tid + i * 256;
        v[i] = xin[rb + col[i]] + b2f(t[rb + col[i]]);
    }
    float su = v[0] + v[1] + v[2];
    float sq = v[0]*v[0] + v[1]*v[1] + v[2]*v[2];
    block_reduce2(su, sq, red, tid);
    const float mean = su * (1.0f / H_);
    const float var  = sq * (1.0f / H_) - mean * mean;
    const float inv  = rsqrtf(var + 1e-5f);
    #pragma unroll
    for (int i = 0; i < 3; ++i) {
        float y = (v[i] - mean) * inv * lda(g, goff + col[i], bf) + lda(bb, goff + col[i], bf);
        xout[rb + col[i]] = y;
        xb  [rb + col[i]] = f2b(y);
    }
}

// =====================================================================
// 8-phase 256-wide MFMA GEMM: C[M,N] = A * Bt^T + bias
// BM=256, BK=64, 512 threads = 8 waves (2M x 4N). Double-buffered LDS,
// XOR chunk swizzle (pre-swizzled global source, swizzled ds_read).
// Round-2 fix: K-loop unrolled 2 tiles/iter so buffer parity is
// compile-time; ALL ds_read addresses = 4 precomputed lane bases +
// constexpr immediates; stage sources = loop-carried pointers + const.
// -> near-zero per-phase VALU (round-1 counters showed 33% VALUBusy
// from per-phase address recomputation).
// Counted vmcnt (8 for BN=256 / 6 for BN=128), never 0 except the
// peeled final iteration (drain 4/3 -> 2 -> 0).
// =====================================================================

#define SG_A0(EOFF, LOFF) do { async_lds16(sA00 + (EOFF), dA00 + (LOFF));  \
                               async_lds16(sA01 + (EOFF), dA01 + (LOFF)); } while (0)
#define SG_A1(EOFF, LOFF) do { async_lds16(sA10 + (EOFF), dA10 + (LOFF));  \
                               async_lds16(sA11 + (EOFF), dA11 + (LOFF)); } while (0)
#define SG_B0(EOFF, LOFF) do { async_lds16(sB00 + (EOFF), dB00 + (LOFF));  \
                               if constexpr (BN == 256) async_lds16(sB01 + (EOFF), dB01 + (LOFF)); } while (0)
#define SG_B1(EOFF, LOFF) do { async_lds16(sB10 + (EOFF), dB10 + (LOFF));  \
                               if constexpr (BN == 256) async_lds16(sB11 + (EOFF), dB11 + (LOFF)); } while (0)

// one phase: 12/10 ds_read (base+imm) || stage || counted-vmcnt || barrier ||
// setprio(1) MFMA cluster setprio(0) || lgkmcnt(0) barrier
#define PH(BUF, MI, NIX, STAGE, VMC) do {                                              \
    bf16x8 afr[4][2];                                                                  \
    _Pragma("unroll") for (int m = 0; m < 4; ++m) {                                    \
        afr[m][0] = *(const bf16x8*)(aB0 + (BUF) * ASZ + (MI) * 8192 + m * 1024);      \
        afr[m][1] = *(const bf16x8*)(aB1 + (BUF) * ASZ + (MI) * 8192 + m * 1024);      \
    }                                                                                  \
    bf16x8 bfr[NI][2];                                                                 \
    _Pragma("unroll") for (int n = 0; n < NI; ++n) {                                   \
        bfr[n][0] = *(const bf16x8*)(bB0 + (BUF) * BSZ + (NIX) * BST + n * 1024);      \
        bfr[n][1] = *(const bf16x8*)(bB1 + (BUF) * BSZ + (NIX) * BST + n * 1024);      \
    }                                                                                  \
    STAGE;                                                                             \
    vmw<(VMC)>();                                                                      \
    asm volatile("s_barrier" ::: "memory");                                            \
    __builtin_amdgcn_s_setprio(1);                                                     \
    _Pragma("unroll") for (int m = 0; m < 4; ++m)                                      \
    _Pragma("unroll") for (int n = 0; n < NI; ++n) {                                   \
        acc[(MI) * 4 + m][(NIX) * NI + n] = __builtin_amdgcn_mfma_f32_16x16x32_bf16(   \
            afr[m][0], bfr[n][0], acc[(MI) * 4 + m][(NIX) * NI + n], 0, 0, 0);         \
        acc[(MI) * 4 + m][(NIX) * NI + n] = __builtin_amdgcn_mfma_f32_16x16x32_bf16(   \
            afr[m][1], bfr[n][1], acc[(MI) * 4 + m][(NIX) * NI + n], 0, 0, 0);         \
    }                                                                                  \
    __builtin_amdgcn_s_setprio(0);                                                     \
    asm volatile("s_waitcnt lgkmcnt(0)" ::: "memory");                                 \
    asm volatile("s_barrier" ::: "memory");                                            \
} while (0)

template<int BN, int ACT>
__global__ __launch_bounds__(512, 1) void gemm8(
    const u16* __restrict__ A, const u16* __restrict__ Bt, const u16* __restrict__ bias,
    u16* __restrict__ C, int M, int N, int K) {
    constexpr int WN   = BN / 4;      // wave col span: 64 or 32
    constexpr int NREP = WN / 16;     // 4 or 2
    constexpr int NI   = NREP / 2;    // frags per phase: 2 or 1
    constexpr int ASZ  = 256 * 64;    // u16 per A buffer (32 KB)
    constexpr int BSZ  = BN * 64;
    constexpr int BST  = (BN == 256) ? 8192 : 4096;   // NIX stride (elems)
    constexpr int SVM  = (BN == 256) ? 8 : 6;         // steady vmcnt
    constexpr int TV5  = (BN == 256) ? 4 : 3;         // final-iter drains
    __shared__ alignas(16) u16 As[2 * ASZ];
    __shared__ alignas(16) u16 Bs[2 * BSZ];
    (void)M;

    const int tid  = threadIdx.x;
    const int wave = tid >> 6, lane = tid & 63;
    const int wm = wave >> 2, wn = wave & 3;
    const int qd = lane >> 4, l16 = lane & 15;
    const int l7 = l16 & 7;

    // XCD-aware bijective swizzle (all grids % 8 == 0)
    const int nbx = N / BN;
    const int nwg = (int)gridDim.x;
    const int b0  = (int)blockIdx.x;
    const int wg  = (b0 & 7) * (nwg >> 3) + (b0 >> 3);
    const int bm  = (wg / nbx) * 256, bn = (wg % nbx) * BN;

    const int NT = K >> 6;            // K-tiles of 64 (>= 12, even)

    // ---- per-lane ds_read bases (elems), swizzled chunk folded in ----
    const u16* aB0 = As + (wm * 64 + l16) * 64 + ((0 | qd) ^ l7) * 8;
    const u16* aB1 = As + (wm * 64 + l16) * 64 + ((4 | qd) ^ l7) * 8;
    const int bRow = (BN == 256) ? (wn * 32 + l16) : (wn * 16 + l16);
    const u16* bB0 = Bs + bRow * 64 + ((0 | qd) ^ l7) * 8;
    const u16* bB1 = Bs + bRow * 64 + ((4 | qd) ^ l7) * 8;

    // ---- staging: lane covers dest (row lr, chunk tid&7); src chunk pre-XOR-swizzled ----
    const int lr = tid >> 3;          // 0..63
    const int cs = (tid & 7) ^ (lr & 7);

    // A halves: LDS rows {0..63,64..127} = global rows {0..63,128..191} (A0), etc.
    const u16* sA00 = A + (size_t)(bm +   0 + lr) * K + cs * 8;
    const u16* sA01 = A + (size_t)(bm + 128 + lr) * K + cs * 8;
    const u16* sA10 = A + (size_t)(bm +  64 + lr) * K + cs * 8;
    const u16* sA11 = A + (size_t)(bm + 192 + lr) * K + cs * 8;
    u16* const dA00 = As +   0 * 64 + tid * 8;
    u16* const dA01 = As +  64 * 64 + tid * 8;
    u16* const dA10 = As + 128 * 64 + tid * 8;
    u16* const dA11 = As + 192 * 64 + tid * 8;

    const u16 *sB00, *sB01, *sB10, *sB11;
    u16 *dB00, *dB01, *dB10, *dB11;
    if constexpr (BN == 256) {
        const int g5 = lr >> 5, j31 = lr & 31;
        sB00 = Bt + (size_t)(bn + g5 * 64 +       j31) * K + cs * 8;
        sB01 = Bt + (size_t)(bn + (2 + g5) * 64 + j31) * K + cs * 8;
        sB10 = Bt + (size_t)(bn + g5 * 64 + 32 +  j31) * K + cs * 8;
        sB11 = Bt + (size_t)(bn + (2 + g5) * 64 + 32 + j31) * K + cs * 8;
        dB00 = Bs +   0 * 64 + tid * 8;
        dB01 = Bs +  64 * 64 + tid * 8;
        dB10 = Bs + 128 * 64 + tid * 8;
        dB11 = Bs + 192 * 64 + tid * 8;
    } else {
        const int g4 = lr >> 4, j15 = lr & 15;
        sB00 = Bt + (size_t)(bn + g4 * 32 +      j15) * K + cs * 8;
        sB10 = Bt + (size_t)(bn + g4 * 32 + 16 + j15) * K + cs * 8;
        sB01 = sB00; sB11 = sB10;
        dB00 = Bs +  0 * 64 + tid * 8;
        dB10 = Bs + 64 * 64 + tid * 8;
        dB01 = dB00; dB11 = dB10;
    }

    f32x4 acc[8][NREP];
    const f32x4 fz = {0.f, 0.f, 0.f, 0.f};
    #pragma unroll
    for (int i = 0; i < 8; ++i)
        #pragma unroll
        for (int j = 0; j < NREP; ++j) acc[i][j] = fz;

    // prologue: A0(0),B0(0),B1(0),A1(0),A0(1),B0(1); certify A0(0)+B0(0)
    SG_A0(0, 0); SG_B0(0, 0); SG_B1(0, 0); SG_A1(0, 0); SG_A0(64, ASZ); SG_B0(64, BSZ);
    vmw<SVM>();
    asm volatile("s_barrier" ::: "memory");

    // steady: 2 tiles (t0=2u even -> buf0, t0+1 -> buf1) per iteration.
    // stage schedule keeps 4 half-tile groups in flight; per-phase counted
    // vmcnt retires exactly the group consumed one phase later.
    const int NU = (NT >> 1) - 1;
    for (int u = 0; u < NU; ++u) {
        PH(0, 0, 0, SG_B1( 64, BSZ), SVM);
        PH(0, 0, 1, SG_A1( 64, ASZ), SVM);
        PH(0, 1, 0, SG_A0(128, 0  ), SVM);
        PH(0, 1, 1, SG_B0(128, 0  ), SVM);
        PH(1, 0, 0, SG_B1(128, 0  ), SVM);
        PH(1, 0, 1, SG_A1(128, 0  ), SVM);
        PH(1, 1, 0, SG_A0(192, ASZ), SVM);
        PH(1, 1, 1, SG_B0(192, BSZ), SVM);
        sA00 += 128; sA01 += 128; sA10 += 128; sA11 += 128;
        sB00 += 128; sB10 += 128;
        if constexpr (BN == 256) { sB01 += 128; sB11 += 128; }
    }

    // final iteration (tiles NT-2 -> buf0, NT-1 -> buf1): stage only B1/A1(NT-1)
    PH(0, 0, 0, SG_B1(64, BSZ), SVM);
    PH(0, 0, 1, SG_A1(64, ASZ), SVM);
    PH(0, 1, 0, (void)0, SVM);
    PH(0, 1, 1, (void)0, SVM);
    PH(1, 0, 0, (void)0, TV5);   // certify A0(NT-1)+B0(NT-1)
    PH(1, 0, 1, (void)0, 2);     // certify B1(NT-1)
    PH(1, 1, 0, (void)0, 0);     // certify A1(NT-1)
    PH(1, 1, 1, (void)0, 0);

    // epilogue: C/D layout col=l16, row=qd*4+r
    #pragma unroll
    for (int mi = 0; mi < 2; ++mi)
        #pragma unroll
        for (int m = 0; m < 4; ++m) {
            const int row0 = bm + wm * 128 + mi * 64 + m * 16 + qd * 4;
            #pragma unroll
            for (int j = 0; j < NREP; ++j) {
                const int col = bn + wn * WN + j * 16 + l16;
                const float bv = b2f(bias[col]);
                #pragma unroll
                for (int r = 0; r < 4; ++r) {
                    float v = acc[mi * 4 + m][j][r] + bv;
                    if (ACT) v = gelu_tanh(v);
                    C[(size_t)(row0 + r) * N + col] = f2b(v);
                }
            }
        }
}

// ---------- flash attention: 64 queries/block, online softmax, MFMA QK^T and PV ----------
__global__ __launch_bounds__(256) void attn_kernel(
    const u16* __restrict__ QKV, const int* __restrict__ seg, u16* __restrict__ Cb) {
    __shared__ alignas(16) u16 Qs[64 * 72];     // [q][d]
    __shared__ alignas(16) u16 Ks[128 * 72];    // [key][d]
    __shared__ alignas(16) u16 Vt[64 * 136];    // [d][key] with 16B-block xor swizzle
    __shared__ alignas(16) u16 Ps[64 * 136];    // [q][key]
    __shared__ float biasv[512];
    const int tid = threadIdx.x;
    const int qt = blockIdx.x, h = blockIdx.y, b = blockIdx.z;
    const int wave = tid >> 6, lane = tid & 63;
    const int qd = lane >> 4, l16 = lane & 15;
    const u16* Qg = QKV + (size_t)b * S_ * STRQ + h * 64;
    const u16* Kg = Qg + 768;
    const u16* Vg = Qg + 1536;

    for (int i = tid; i < 512; i += 256)
        biasv[i] = (seg[b * S_ + i] > 0) ? 0.0f : -1e9f;

    {   // stage Q tile 64x64 = 512 uint4 items
        int c = tid;
        #pragma unroll
        for (int u = 0; u < 2; ++u, c += 256) {
            int r = c >> 3, c8 = (c & 7) * 8;
            uint4 v4 = *(const uint4*)(Qg + (size_t)(qt * 64 + r) * STRQ + c8);
            *(uint4*)(Qs + r * 72 + c8) = v4;
        }
    }

    float m_run[4], l_run[4];
    f32x4 accO[4];
    #pragma unroll
    for (int r = 0; r < 4; ++r) { m_run[r] = -3.0e38f; l_run[r] = 0.f; }
    #pragma unroll
    for (int dt = 0; dt < 4; ++dt) accO[dt] = {0.f, 0.f, 0.f, 0.f};

    for (int kt = 0; kt < 512; kt += 128) {
        __syncthreads();                       // prev iter's Ks/Vt reads complete
        {   // stage K tile 128x64 = 1024 uint4 items
            int c = tid;
            #pragma unroll
            for (int u = 0; u < 4; ++u, c += 256) {
                int r = c >> 3, c8 = (c & 7) * 8;
                uint4 v4 = *(const uint4*)(Kg + (size_t)(kt + r) * STRQ + c8);
                *(uint4*)(Ks + r * 72 + c8) = v4;
            }
        }
        {   // stage V tile transposed: Vt[d][key], key-block xor-swizzled (1024 items)
            int c = tid;
            #pragma unroll
            for (int u = 0; u < 4; ++u, c += 256) {
                int r = c >> 3, d8 = (c & 7) * 8;
                uint4 v4 = *(const uint4*)(Vg + (size_t)(kt + r) * STRQ + d8);
                u16 tmp[8]; *(uint4*)tmp = v4;
                #pragma unroll
                for (int j = 0; j < 8; ++j) {
                    int d = d8 + j;
                    int blk = (r >> 3) ^ (d >> 3);
                    Vt[d * 136 + blk * 8 + (r & 7)] = tmp[j];
                }
            }
        }
        __syncthreads();

        // ---- QK^T: wave owns q rows wave*16..+15, all 128 keys ----
        f32x4 s[8];
        {
            bf16x8 aq[2];
            #pragma unroll
            for (int kd = 0; kd < 2; ++kd)
                aq[kd] = *(const bf16x8*)(Qs + (wave * 16 + l16) * 72 + kd * 32 + qd * 8);
            #pragma unroll
            for (int nt = 0; nt < 8; ++nt) {
                s[nt] = {0.f, 0.f, 0.f, 0.f};
                #pragma unroll
                for (int kd = 0; kd < 2; ++kd) {
                    bf16x8 bk = *(const bf16x8*)(Ks + (nt * 16 + l16) * 72 + kd * 32 + qd * 8);
                    s[nt] = __builtin_amdgcn_mfma_f32_16x16x32_bf16(aq[kd], bk, s[nt], 0, 0, 0);
                }
            }
        }
        // scale + mask bias (bias depends on key = col = nt*16+l16)
        #pragma unroll
        for (int nt = 0; nt < 8; ++nt) {
            const float bv = biasv[kt + nt * 16 + l16];
            #pragma unroll
            for (int r = 0; r < 4; ++r) s[nt][r] = s[nt][r] * 0.125f + bv;
        }
        // online softmax: rows live in (qd, r); reduce across 16 l16 lanes
        float alpha[4], rsum[4];
        #pragma unroll
        for (int r = 0; r < 4; ++r) {
            float m = s[0][r];
            #pragma unroll
            for (int nt = 1; nt < 8; ++nt) m = fmaxf(m, s[nt][r]);
            #pragma unroll
            for (int msk = 8; msk >= 1; msk >>= 1) m = fmaxf(m, __shfl_xor(m, msk));
            float mn = fmaxf(m_run[r], m);
            alpha[r] = __expf(m_run[r] - mn);
            m_run[r] = mn;
            rsum[r] = 0.f;
        }
        #pragma unroll
        for (int nt = 0; nt < 8; ++nt)
            #pragma unroll
            for (int r = 0; r < 4; ++r) {
                float p = __expf(s[nt][r] - m_run[r]);
                rsum[r] += p;
                Ps[(wave * 16 + qd * 4 + r) * 136 + nt * 16 + l16] = f2b(p);
            }
        #pragma unroll
        for (int r = 0; r < 4; ++r) {
            float t = rsum[r];
            #pragma unroll
            for (int msk = 8; msk >= 1; msk >>= 1) t += __shfl_xor(t, msk);
            l_run[r] = l_run[r] * alpha[r] + t;
        }
        #pragma unroll
        for (int dt = 0; dt < 4; ++dt)
            #pragma unroll
            for (int r = 0; r < 4; ++r) accO[dt][r] *= alpha[r];
        __syncthreads();                       // Ps visible (and Vt already staged)

        // ---- PV: O(16x64) += P(16x128) @ V(128x64) ----
        #pragma unroll
        for (int kk = 0; kk < 4; ++kk) {
            bf16x8 ap = *(const bf16x8*)(Ps + (wave * 16 + l16) * 136 + kk * 32 + qd * 8);
            #pragma unroll
            for (int dt = 0; dt < 4; ++dt) {
                const int d = dt * 16 + l16;
                const int blk = (kk * 4 + qd) ^ (d >> 3);
                bf16x8 bv = *(const bf16x8*)(Vt + d * 136 + blk * 8);
                accO[dt] = __builtin_amdgcn_mfma_f32_16x16x32_bf16(ap, bv, accO[dt], 0, 0, 0);
            }
        }
    }

    // epilogue: normalize and write ctx [row][h*64+d]
    #pragma unroll
    for (int r = 0; r < 4; ++r) {
        const int row = qt * 64 + wave * 16 + qd * 4 + r;
        const float inv = 1.0f / l_run[r];
        const size_t obase = ((size_t)b * S_ + row) * H_ + h * 64;
        #pragma unroll
        for (int dt = 0; dt < 4; ++dt)
            Cb[obase + dt * 16 + l16] = f2b(accO[dt][r] * inv);
    }
}

// ---------- head1: hid = tanh(pooled @ Wp1 + bp1) via MFMA, one wave per 16x16 tile ----------
__global__ __launch_bounds__(256) void head1_kernel(
    const u16* __restrict__ xb, const u16* __restrict__ Wp1T,
    const void* __restrict__ bp1, u16* __restrict__ hidb, const int* __restrict__ fl) {
    __shared__ alignas(16) u16 Xs[16 * 776];     // stride 776 breaks 16-way bank alias
    const int bf = fl[0];
    const int tid = threadIdx.x, wave = tid >> 6, lane = tid & 63;
    const int qd = lane >> 4, l16 = lane & 15;
    for (int i = tid; i < 16 * 96; i += 256) {   // 96 uint4 per pooled row
        int b = i / 96, c = (i % 96) * 8;
        *(uint4*)(Xs + b * 776 + c) = *(const uint4*)(xb + ((size_t)b * S_) * H_ + c);
    }
    __syncthreads();
    const int n0 = (blockIdx.x * 4 + wave) * 16;
    f32x4 acc = {0.f, 0.f, 0.f, 0.f};
    for (int k0 = 0; k0 < H_; k0 += 32) {
        bf16x8 a  = *(const bf16x8*)(Xs + l16 * 776 + k0 + qd * 8);
        bf16x8 bb = *(const bf16x8*)(Wp1T + (size_t)(n0 + l16) * H_ + k0 + qd * 8);
        acc = __builtin_amdgcn_mfma_f32_16x16x32_bf16(a, bb, acc, 0, 0, 0);
    }
    // C/D: col=l16 (j), row=qd*4+r (batch)
    #pragma unroll
    for (int r = 0; r < 4; ++r) {
        const int b = qd * 4 + r, j = n0 + l16;
        hidb[b * H_ + j] = f2b(tanhf(acc[r] + lda(bp1, j, bf)));
    }
}

// ---------- head2: logits, wave per (batch, label) ----------
__global__ __launch_bounds__(640) void head2_kernel(
    const u16* __restrict__ hidb, const void* __restrict__ Wp2, const void* __restrict__ bp2,
    float* __restrict__ lg, const int* __restrict__ fl) {
    const int bf = fl[0];
    const int b = blockIdx.x, j = threadIdx.x >> 6, lane = threadIdx.x & 63;
    float s = 0.f;
    for (int k = lane; k < H_; k += 64)
        s += b2f(hidb[b * H_ + k]) * lda(Wp2, (size_t)k * LAB_ + j, bf);
    #pragma unroll
    for (int m = 32; m >= 1; m >>= 1) s += __shfl_xor(s, m);
    if (lane == 0) lg[b * LAB_ + j] = s + lda(bp2, j, bf);
}

// ---------- head3: log-softmax loss + dual-format output ----------
__global__ __launch_bounds__(192) void head3_kernel(
    const float* __restrict__ lg, const int* __restrict__ tgt,
    void* __restrict__ outv, const int* __restrict__ fl) {
    __shared__ float lse[B_];
    const int bf = fl[0], t = threadIdx.x;
    if (t < B_) {
        float mx = -1e30f;
        for (int j = 0; j < LAB_; ++j) mx = fmaxf(mx, lg[t * LAB_ + j]);
        float s = 0.f;
        for (int j = 0; j < LAB_; ++j) s += expf(lg[t * LAB_ + j] - mx);
        lse[t] = mx + logf(s);
    }
    __syncthreads();
    float loss = 0.f;
    if (t == 0) {
        for (int b = 0; b < B_; ++b) loss += lse[b] - lg[b * LAB_ + tgt[b]];
        loss /= (float)B_;
    }
    if (bf) {
        u16* o = (u16*)outv;
        if (t == 0) o[0] = f2b(loss);
        if (t < B_ * LAB_) o[1 + t] = f2b(lg[t]);
    } else {
        float* o = (float*)outv;
        if (t == 0) o[0] = loss;
        if (t < B_ * LAB_) o[1 + t] = lg[t];
    }
}

// ---------- launch ----------
extern "C" void kernel_launch(void* const* d_in, const int* in_sizes, int n_in,
                              void* d_out, int out_size, void* d_ws, size_t ws_size,
                              hipStream_t stream) {
    (void)in_sizes; (void)n_in; (void)out_size; (void)ws_size;
    const int* src = (const int*)d_in[0];
    const int* seg = (const int*)d_in[1];
    const int* tgt = (const int*)d_in[2];
    const int* tib = (const int*)d_in[3];
    const void* we  = d_in[4];
    const void* pe  = d_in[5];
    const void* se  = d_in[6];
    const void* elg = d_in[7];
    const void* elb = d_in[8];
    const void* Wq  = d_in[9];
    const void* bq  = d_in[10];
    const void* Wk  = d_in[11];
    const void* bk  = d_in[12];
    const void* Wv  = d_in[13];
    const void* bv  = d_in[14];
    const void* Wo  = d_in[15];
    const void* bo  = d_in[16];
    const void* l1g = d_in[17];
    const void* l1b = d_in[18];
    const void* Wf1 = d_in[19];
    const void* bf1 = d_in[20];
    const void* Wf2 = d_in[21];
    const void* bf2 = d_in[22];
    const void* l2g = d_in[23];
    const void* l2b = d_in[24];
    const void* Wp1 = d_in[25];
    const void* bp1 = d_in[26];
    const void* Wp2 = d_in[27];
    const void* bp2 = d_in[28];
    const void* sf  = d_in[29];

    const size_t HH   = (size_t)H_ * H_;        // 589824
    const size_t HFF  = (size_t)H_ * FF_;       // 2359296
    const size_t MH   = (size_t)M_ * H_;        // 6291456
    const size_t MQKV = (size_t)M_ * STRQ;      // 18874368
    const size_t MFF  = (size_t)M_ * FF_;       // 25165824
    const size_t QKVW = (size_t)STRQ * H_;      // 1769472 (per-layer merged weight)

    char* w = (char*)d_ws;
    int* dflag  = (int*)w;  w += 256;
    u16* bias_ws = (u16*)w; w += 41472 * 2;     // prep_bias layout
    u16* WqkvT = (u16*)w;  w += L_ * QKVW * 2;
    u16* WoT   = (u16*)w;  w += L_ * HH  * 2;
    u16* Wf1T  = (u16*)w;  w += L_ * HFF * 2;
    u16* Wf2T  = (u16*)w;  w += L_ * HFF * 2;
    u16* Wp1T  = (u16*)w;  w += HH * 2;
    float* x32 = (float*)w; w += MH * 4;
    u16* xb    = (u16*)w;  w += MH * 2;
    u16* qkvb  = (u16*)w;  w += MQKV * 2;
    u16* ctxb  = (u16*)w;  w += MH * 2;
    u16* tmpb  = (u16*)w;  w += MH * 2;
    u16* ffb   = (u16*)w;  w += MFF * 2;
    u16* hidb  = (u16*)w;  w += (size_t)B_ * H_ * 2;
    float* lg  = (float*)w; w += (size_t)B_ * LAB_ * 4;

    u16* bqkv = bias_ws;            // 6 x 2304
    u16* bo6  = bias_ws + 13824;    // 6 x 768
    u16* bf16_= bias_ws + 18432;    // 6 x 3072
    u16* bf26 = bias_ws + 36864;    // 6 x 768

    const dim3 tb(256);
    const dim3 tg(512);
    detect_kernel<<<1, 1, 0, stream>>>((const u32*)elg, dflag);
    prep_bias<<<162, tb, 0, stream>>>(bq, bk, bv, bo, bf1, bf2, bias_ws, dflag);

    // weight transposes+convert; Wq/Wk/Wv interleave into per-layer 2304x768 blocks
    transpose_k<<<dim3(12, 12, 6), tb, 0, stream>>>(Wq, WqkvT,                    H_, H_, (long)HH, (long)QKVW, dflag);
    transpose_k<<<dim3(12, 12, 6), tb, 0, stream>>>(Wk, WqkvT + (size_t)768*768,  H_, H_, (long)HH, (long)QKVW, dflag);
    transpose_k<<<dim3(12, 12, 6), tb, 0, stream>>>(Wv, WqkvT + (size_t)1536*768, H_, H_, (long)HH, (long)QKVW, dflag);
    transpose_k<<<dim3(12, 12, 6), tb, 0, stream>>>(Wo,  WoT,  H_, H_,  (long)HH,  (long)HH,  dflag);
    transpose_k<<<dim3(48, 12, 6), tb, 0, stream>>>(Wf1, Wf1T, H_, FF_, (long)HFF, (long)HFF, dflag);
    transpose_k<<<dim3(12, 48, 6), tb, 0, stream>>>(Wf2, Wf2T, FF_, H_, (long)HFF, (long)HFF, dflag);
    transpose_k<<<dim3(12, 12, 1), tb, 0, stream>>>(Wp1, Wp1T, H_, H_,  (long)HH,  (long)HH,  dflag);

    embed_kernel<<<M_, tb, 0, stream>>>(src, seg, tib, we, pe, se, elg, elb, sf, x32, xb, dflag);

    for (int l = 0; l < L_; ++l) {
        // QKV: M x 2304 x 768, 288 blocks (BN=256)
        gemm8<256, 0><<<dim3((STRQ / 256) * (M_ / 256)), tg, 0, stream>>>(xb, WqkvT + l * QKVW, bqkv + l * STRQ, qkvb, M_, STRQ, H_);
        attn_kernel<<<dim3(S_ / 64, NH_, B_), tb, 0, stream>>>(qkvb, seg, ctxb);
        // Wo: M x 768 x 768, 192 blocks (BN=128 for occupancy at N=768)
        gemm8<128, 0><<<dim3((H_ / 128) * (M_ / 256)), tg, 0, stream>>>(ctxb, WoT + l * HH, bo6 + l * H_, tmpb, M_, H_, H_);
        add_ln_kernel<<<M_, tb, 0, stream>>>(x32, tmpb, l1g, l1b, (long)l * H_, x32, xb, dflag);
        // FF1: M x 3072 x 768 + gelu, 384 blocks
        gemm8<256, 1><<<dim3((FF_ / 256) * (M_ / 256)), tg, 0, stream>>>(xb, Wf1T + l * HFF, bf16_ + l * FF_, ffb, M_, FF_, H_);
        // FF2: M x 768 x 3072, 192 blocks
        gemm8<128, 0><<<dim3((H_ / 128) * (M_ / 256)), tg, 0, stream>>>(ffb, Wf2T + l * HFF, bf26 + l * H_, tmpb, M_, H_, FF_);
        add_ln_kernel<<<M_, tb, 0, stream>>>(x32, tmpb, l2g, l2b, (long)l * H_, x32, xb, dflag);
    }

    head1_kernel<<<12, tb, 0, stream>>>(xb, Wp1T, bp1, hidb, dflag);
    head2_kernel<<<B_, dim3(640), 0, stream>>>(hidb, Wp2, bp2, lg, dflag);
    head3_kernel<<<1, dim3(192), 0, stream>>>(lg, tgt, d_out, dflag);
}

// Round 3
// 2088.246 us; speedup vs baseline: 1.3089x; 1.3089x over previous
//
#include <hip/hip_runtime.h>

typedef unsigned short u16;
typedef unsigned int   u32;
typedef __bf16  bf16x8 __attribute__((ext_vector_type(8)));
typedef float   f32x4  __attribute__((ext_vector_type(4)));

#define B_   16
#define S_   512
#define H_   768
#define NH_  12
#define L_   6
#define FF_  3072
#define M_   8192     // B_*S_
#define LAB_ 10
#define STRQ 2304     // merged qkv row stride

// ---------- bf16 helpers (storage = u16 bits) ----------
__device__ __forceinline__ float b2f(u16 x) {
    u32 u = ((u32)x) << 16; float f; __builtin_memcpy(&f, &u, 4); return f;
}
__device__ __forceinline__ u16 f2b(float f) {
    u32 u; __builtin_memcpy(&u, &f, 4);
    u32 r = u + 0x7FFFu + ((u >> 16) & 1u);
    return (u16)(r >> 16);
}
__device__ __forceinline__ float lda(const void* p, size_t i, int bf) {
    return bf ? b2f(((const u16*)p)[i]) : ((const float*)p)[i];
}
__device__ __forceinline__ float gelu_tanh(float x) {
    return 0.5f * x * (1.0f + tanhf(0.7978845608028654f * (x + 0.044715f * x * x * x)));
}
// async global->LDS, 16B per lane; LDS dest must be wave-uniform base + lane*16
__device__ __forceinline__ void async_lds16(const u16* g, u16* l) {
    __builtin_amdgcn_global_load_lds(
        (const __attribute__((address_space(1))) u32*)(const void*)g,
        (__attribute__((address_space(3))) u32*)(void*)l, 16, 0, 0);
}

// ---------- dtype detect: emb_ln_g is all ones ----------
__global__ void detect_kernel(const u32* __restrict__ g, int* __restrict__ flag) {
    flag[0] = (g[0] == 0x3F803F80u) ? 1 : 0;   // bf16 ones pair vs fp32 one
}

// ---------- block reduce (sum of two values), 256 threads ----------
__device__ __forceinline__ void block_reduce2(float& s, float& s2, float* red, int tid) {
    int lane = tid & 63, wave = tid >> 6;
    #pragma unroll
    for (int m = 32; m >= 1; m >>= 1) { s += __shfl_xor(s, m); s2 += __shfl_xor(s2, m); }
    if (lane == 0) { red[wave] = s; red[4 + wave] = s2; }
    __syncthreads();
    s  = red[0] + red[1] + red[2] + red[3];
    s2 = red[4] + red[5] + red[6] + red[7];
}

// ---------- weight transpose+convert: in (K x N) -> out bf16 (N x K) ----------
__global__ __launch_bounds__(256) void transpose_k(const void* __restrict__ in,
                                                   u16* __restrict__ out, int K, int N,
                                                   long in_lstride, long out_lstride,
                                                   const int* __restrict__ fl) {
    __shared__ u16 tile[64][65];
    const int bf = fl[0];
    const size_t ioff = (size_t)blockIdx.z * (size_t)in_lstride;
    const size_t ooff = (size_t)blockIdx.z * (size_t)out_lstride;
    int k0 = blockIdx.y * 64, n0 = blockIdx.x * 64;
    int c = threadIdx.x & 63, r0 = threadIdx.x >> 6;
    #pragma unroll
    for (int r = r0; r < 64; r += 4) {
        size_t idx = ioff + (size_t)(k0 + r) * N + n0 + c;
        tile[r][c] = bf ? ((const u16*)in)[idx] : f2b(((const float*)in)[idx]);
    }
    __syncthreads();
    #pragma unroll
    for (int r = r0; r < 64; r += 4)
        out[ooff + (size_t)(n0 + r) * K + k0 + c] = tile[c][r];
}

// ---------- bias prep: convert all GEMM biases to bf16, qkv concatenated ----------
// layout: [0,13824) bqkv (6 x 2304) | [13824,18432) bo | [18432,36864) bf1 | [36864,41472) bf2
__global__ __launch_bounds__(256) void prep_bias(
    const void* __restrict__ bq, const void* __restrict__ bk, const void* __restrict__ bv,
    const void* __restrict__ bo, const void* __restrict__ bf1, const void* __restrict__ bf2,
    u16* __restrict__ out, const int* __restrict__ fl) {
    const int bf = fl[0];
    int i = blockIdx.x * 256 + threadIdx.x;
    if (i >= 41472) return;
    float v;
    if (i < 13824) {
        int l = i / 2304, c = i % 2304;
        v = (c < 768) ? lda(bq, (size_t)l * 768 + c, bf)
          : (c < 1536) ? lda(bk, (size_t)l * 768 + c - 768, bf)
                       : lda(bv, (size_t)l * 768 + c - 1536, bf);
    } else if (i < 18432) v = lda(bo,  i - 13824, bf);
    else if (i < 36864)   v = lda(bf1, i - 18432, bf);
    else                  v = lda(bf2, i - 36864, bf);
    out[i] = f2b(v);
}

// ---------- embedding + LN + selection scale ----------
__global__ __launch_bounds__(256) void embed_kernel(
    const int* __restrict__ src, const int* __restrict__ seg, const int* __restrict__ tib,
    const void* __restrict__ we, const void* __restrict__ pe, const void* __restrict__ se,
    const void* __restrict__ g, const void* __restrict__ bb, const void* __restrict__ sf,
    float* __restrict__ x32, u16* __restrict__ xb, const int* __restrict__ fl) {
    __shared__ float red[8];
    const int bf = fl[0];
    const int r = blockIdx.x, tid = threadIdx.x;
    const int s = r & (S_ - 1);
    const int w = src[r], sg = seg[r];
    const float scale = lda(sf, tib[r], bf);
    float v[3]; int col[3];
    #pragma unroll
    for (int i = 0; i < 3; ++i) {
        col[i] = tid + i * 256;
        v[i] = lda(we, (size_t)w * H_ + col[i], bf) + lda(pe, (size_t)s * H_ + col[i], bf)
             + lda(se, (size_t)sg * H_ + col[i], bf);
    }
    float su = v[0] + v[1] + v[2];
    float sq = v[0]*v[0] + v[1]*v[1] + v[2]*v[2];
    block_reduce2(su, sq, red, tid);
    const float mean = su * (1.0f / H_);
    const float var  = sq * (1.0f / H_) - mean * mean;
    const float inv  = rsqrtf(var + 1e-5f);
    #pragma unroll
    for (int i = 0; i < 3; ++i) {
        float y = ((v[i] - mean) * inv * lda(g, col[i], bf) + lda(bb, col[i], bf)) * scale;
        x32[(size_t)r * H_ + col[i]] = y;
        xb [(size_t)r * H_ + col[i]] = f2b(y);
    }
}

// ---------- residual add + LN (x32 master, bf16 shadow out) ----------
__global__ __launch_bounds__(256) void add_ln_kernel(
    const float* __restrict__ xin, const u16* __restrict__ t,
    const void* __restrict__ g, const void* __restrict__ bb, long goff,
    float* __restrict__ xout, u16* __restrict__ xb, const int* __restrict__ fl) {
    __shared__ float red[8];
    const int bf = fl[0];
    const int r = blockIdx.x, tid = threadIdx.x;
    const size_t rb = (size_t)r * H_;
    float v[3]; int col[3];
    #pragma unroll
    for (int i = 0; i < 3; ++i) {
        col[i] = tid + i * 256;
        v[i] = xin[rb + col[i]] + b2f(t[rb + col[i]]);
    }
    float su = v[0] + v[1] + v[2];
    float sq = v[0]*v[0] + v[1]*v[1] + v[2]*v[2];
    block_reduce2(su, sq, red, tid);
    const float mean = su * (1.0f / H_);
    const float var  = sq * (1.0f / H_) - mean * mean;
    const float inv  = rsqrtf(var + 1e-5f);
    #pragma unroll
    for (int i = 0; i < 3; ++i) {
        float y = (v[i] - mean) * inv * lda(g, goff + col[i], bf) + lda(bb, goff + col[i], bf);
        xout[rb + col[i]] = y;
        xb  [rb + col[i]] = f2b(y);
    }
}

// =====================================================================
// MFMA GEMM (m97-style, 128x128 tile, 256 thr, 3 blocks/CU): BK=64.
// vs round-0: BK 32->64 halves the per-K-step __syncthreads drain count
// (the known ~20% stall of this family). LDS 2x16KB=32KB keeps 3
// blocks/CU (m132's BK=128 regression was the 64KB occupancy cliff).
// 128B row stride would be a full bank conflict on ds_read_b128 ->
// XOR chunk swizzle: LDS linear, SOURCE chunk pre-swizzled, read
// swizzled (both-sides pair field-verified in rounds 1-2).
// =====================================================================
__global__ __launch_bounds__(256) void gemm_bt(
    const u16* __restrict__ A, const u16* __restrict__ Bt, const u16* __restrict__ bias,
    u16* __restrict__ C, int M, int N, int K, int act) {
    __shared__ alignas(16) u16 As[128 * 64];
    __shared__ alignas(16) u16 Bs[128 * 64];
    const int tid = threadIdx.x;
    const int bm = blockIdx.y * 128, bn = blockIdx.x * 128;
    const int wave = tid >> 6, lane = tid & 63;
    const int wm = (wave >> 1) * 64, wn = (wave & 1) * 64;
    const int qd = lane >> 4, l16 = lane & 15;
    const int l7 = l16 & 15 & 7;

    const f32x4 fz = {0.f, 0.f, 0.f, 0.f};
    f32x4 acc[4][4];
    #pragma unroll
    for (int i = 0; i < 4; ++i)
        #pragma unroll
        for (int j = 0; j < 4; ++j) acc[i][j] = fz;

    // staging: [128][64] tile = 1024 16B chunks; thread covers chunks tid+u*256.
    // LDS dest linear (chunk c at As+c*8); global source chunk = (c&7)^(row&7).
    const u16* Ag[4]; const u16* Bg[4]; int dofs[4];
    #pragma unroll
    for (int u = 0; u < 4; ++u) {
        const int c = tid + u * 256;
        const int r = c >> 3;
        const int cs = ((c & 7) ^ (r & 7)) * 8;
        Ag[u] = A  + (size_t)(bm + r) * K + cs;
        Bg[u] = Bt + (size_t)(bn + r) * K + cs;
        dofs[u] = c * 8;
    }

    for (int k0 = 0; k0 < K; k0 += 64) {
        __syncthreads();               // prev iter's LDS reads complete
        #pragma unroll
        for (int u = 0; u < 4; ++u) {
            async_lds16(Ag[u] + k0, As + dofs[u]);
            async_lds16(Bg[u] + k0, Bs + dofs[u]);
        }
        __syncthreads();               // vmcnt drained by barrier semantics
        bf16x8 af[4][2], bfv[4][2];
        #pragma unroll
        for (int i = 0; i < 4; ++i)
            #pragma unroll
            for (int kd = 0; kd < 2; ++kd) {
                const int sw = (((kd << 2) | qd) ^ l7) << 3;   // swizzled 16B chunk
                af[i][kd]  = *(const bf16x8*)(As + (wm + i * 16 + l16) * 64 + sw);
                bfv[i][kd] = *(const bf16x8*)(Bs + (wn + i * 16 + l16) * 64 + sw);
            }
        #pragma unroll
        for (int i = 0; i < 4; ++i)
            #pragma unroll
            for (int j = 0; j < 4; ++j)
                #pragma unroll
                for (int kd = 0; kd < 2; ++kd)
                    acc[i][j] = __builtin_amdgcn_mfma_f32_16x16x32_bf16(af[i][kd], bfv[j][kd], acc[i][j], 0, 0, 0);
    }

    // epilogue: C/D layout col=lane&15, row=(lane>>4)*4+reg
    #pragma unroll
    for (int i = 0; i < 4; ++i) {
        const int row0 = bm + wm + i * 16 + qd * 4;
        #pragma unroll
        for (int j = 0; j < 4; ++j) {
            const int col = bn + wn + j * 16 + l16;
            const float bv = b2f(bias[col]);
            #pragma unroll
            for (int r = 0; r < 4; ++r) {
                float v = acc[i][j][r] + bv;
                if (act == 1) v = gelu_tanh(v);
                C[(size_t)(row0 + r) * N + col] = f2b(v);
            }
        }
    }
}

// ---------- flash attention: 64 queries/block, online softmax, MFMA QK^T and PV ----------
__global__ __launch_bounds__(256) void attn_kernel(
    const u16* __restrict__ QKV, const int* __restrict__ seg, u16* __restrict__ Cb) {
    __shared__ alignas(16) u16 Qs[64 * 72];     // [q][d]
    __shared__ alignas(16) u16 Ks[128 * 72];    // [key][d]
    __shared__ alignas(16) u16 Vt[64 * 136];    // [d][key] with 16B-block xor swizzle
    __shared__ alignas(16) u16 Ps[64 * 136];    // [q][key]
    __shared__ float biasv[512];
    const int tid = threadIdx.x;
    const int qt = blockIdx.x, h = blockIdx.y, b = blockIdx.z;
    const int wave = tid >> 6, lane = tid & 63;
    const int qd = lane >> 4, l16 = lane & 15;
    const u16* Qg = QKV + (size_t)b * S_ * STRQ + h * 64;
    const u16* Kg = Qg + 768;
    const u16* Vg = Qg + 1536;

    for (int i = tid; i < 512; i += 256)
        biasv[i] = (seg[b * S_ + i] > 0) ? 0.0f : -1e9f;

    {   // stage Q tile 64x64 = 512 uint4 items
        int c = tid;
        #pragma unroll
        for (int u = 0; u < 2; ++u, c += 256) {
            int r = c >> 3, c8 = (c & 7) * 8;
            uint4 v4 = *(const uint4*)(Qg + (size_t)(qt * 64 + r) * STRQ + c8);
            *(uint4*)(Qs + r * 72 + c8) = v4;
        }
    }

    float m_run[4], l_run[4];
    f32x4 accO[4];
    #pragma unroll
    for (int r = 0; r < 4; ++r) { m_run[r] = -3.0e38f; l_run[r] = 0.f; }
    #pragma unroll
    for (int dt = 0; dt < 4; ++dt) accO[dt] = {0.f, 0.f, 0.f, 0.f};

    for (int kt = 0; kt < 512; kt += 128) {
        __syncthreads();                       // prev iter's Ks/Vt reads complete
        {   // stage K tile 128x64 = 1024 uint4 items
            int c = tid;
            #pragma unroll
            for (int u = 0; u < 4; ++u, c += 256) {
                int r = c >> 3, c8 = (c & 7) * 8;
                uint4 v4 = *(const uint4*)(Kg + (size_t)(kt + r) * STRQ + c8);
                *(uint4*)(Ks + r * 72 + c8) = v4;
            }
        }
        {   // stage V tile transposed: Vt[d][key], key-block xor-swizzled (1024 items)
            int c = tid;
            #pragma unroll
            for (int u = 0; u < 4; ++u, c += 256) {
                int r = c >> 3, d8 = (c & 7) * 8;
                uint4 v4 = *(const uint4*)(Vg + (size_t)(kt + r) * STRQ + d8);
                u16 tmp[8]; *(uint4*)tmp = v4;
                #pragma unroll
                for (int j = 0; j < 8; ++j) {
                    int d = d8 + j;
                    int blk = (r >> 3) ^ (d >> 3);
                    Vt[d * 136 + blk * 8 + (r & 7)] = tmp[j];
                }
            }
        }
        __syncthreads();

        // ---- QK^T: wave owns q rows wave*16..+15, all 128 keys ----
        f32x4 s[8];
        {
            bf16x8 aq[2];
            #pragma unroll
            for (int kd = 0; kd < 2; ++kd)
                aq[kd] = *(const bf16x8*)(Qs + (wave * 16 + l16) * 72 + kd * 32 + qd * 8);
            #pragma unroll
            for (int nt = 0; nt < 8; ++nt) {
                s[nt] = {0.f, 0.f, 0.f, 0.f};
                #pragma unroll
                for (int kd = 0; kd < 2; ++kd) {
                    bf16x8 bk = *(const bf16x8*)(Ks + (nt * 16 + l16) * 72 + kd * 32 + qd * 8);
                    s[nt] = __builtin_amdgcn_mfma_f32_16x16x32_bf16(aq[kd], bk, s[nt], 0, 0, 0);
                }
            }
        }
        // scale + mask bias (bias depends on key = col = nt*16+l16)
        #pragma unroll
        for (int nt = 0; nt < 8; ++nt) {
            const float bv = biasv[kt + nt * 16 + l16];
            #pragma unroll
            for (int r = 0; r < 4; ++r) s[nt][r] = s[nt][r] * 0.125f + bv;
        }
        // online softmax: rows live in (qd, r); reduce across 16 l16 lanes
        float alpha[4], rsum[4];
        #pragma unroll
        for (int r = 0; r < 4; ++r) {
            float m = s[0][r];
            #pragma unroll
            for (int nt = 1; nt < 8; ++nt) m = fmaxf(m, s[nt][r]);
            #pragma unroll
            for (int msk = 8; msk >= 1; msk >>= 1) m = fmaxf(m, __shfl_xor(m, msk));
            float mn = fmaxf(m_run[r], m);
            alpha[r] = __expf(m_run[r] - mn);
            m_run[r] = mn;
            rsum[r] = 0.f;
        }
        #pragma unroll
        for (int nt = 0; nt < 8; ++nt)
            #pragma unroll
            for (int r = 0; r < 4; ++r) {
                float p = __expf(s[nt][r] - m_run[r]);
                rsum[r] += p;
                Ps[(wave * 16 + qd * 4 + r) * 136 + nt * 16 + l16] = f2b(p);
            }
        #pragma unroll
        for (int r = 0; r < 4; ++r) {
            float t = rsum[r];
            #pragma unroll
            for (int msk = 8; msk >= 1; msk >>= 1) t += __shfl_xor(t, msk);
            l_run[r] = l_run[r] * alpha[r] + t;
        }
        #pragma unroll
        for (int dt = 0; dt < 4; ++dt)
            #pragma unroll
            for (int r = 0; r < 4; ++r) accO[dt][r] *= alpha[r];
        __syncthreads();                       // Ps visible (and Vt already staged)

        // ---- PV: O(16x64) += P(16x128) @ V(128x64) ----
        #pragma unroll
        for (int kk = 0; kk < 4; ++kk) {
            bf16x8 ap = *(const bf16x8*)(Ps + (wave * 16 + l16) * 136 + kk * 32 + qd * 8);
            #pragma unroll
            for (int dt = 0; dt < 4; ++dt) {
                const int d = dt * 16 + l16;
                const int blk = (kk * 4 + qd) ^ (d >> 3);
                bf16x8 bv = *(const bf16x8*)(Vt + d * 136 + blk * 8);
                accO[dt] = __builtin_amdgcn_mfma_f32_16x16x32_bf16(ap, bv, accO[dt], 0, 0, 0);
            }
        }
    }

    // epilogue: normalize and write ctx [row][h*64+d]
    #pragma unroll
    for (int r = 0; r < 4; ++r) {
        const int row = qt * 64 + wave * 16 + qd * 4 + r;
        const float inv = 1.0f / l_run[r];
        const size_t obase = ((size_t)b * S_ + row) * H_ + h * 64;
        #pragma unroll
        for (int dt = 0; dt < 4; ++dt)
            Cb[obase + dt * 16 + l16] = f2b(accO[dt][r] * inv);
    }
}

// ---------- head1: hid = tanh(pooled @ Wp1 + bp1) via MFMA, one wave per 16x16 tile ----------
__global__ __launch_bounds__(256) void head1_kernel(
    const u16* __restrict__ xb, const u16* __restrict__ Wp1T,
    const void* __restrict__ bp1, u16* __restrict__ hidb, const int* __restrict__ fl) {
    __shared__ alignas(16) u16 Xs[16 * 776];     // stride 776 breaks 16-way bank alias
    const int bf = fl[0];
    const int tid = threadIdx.x, wave = tid >> 6, lane = tid & 63;
    const int qd = lane >> 4, l16 = lane & 15;
    for (int i = tid; i < 16 * 96; i += 256) {   // 96 uint4 per pooled row
        int b = i / 96, c = (i % 96) * 8;
        *(uint4*)(Xs + b * 776 + c) = *(const uint4*)(xb + ((size_t)b * S_) * H_ + c);
    }
    __syncthreads();
    const int n0 = (blockIdx.x * 4 + wave) * 16;
    f32x4 acc = {0.f, 0.f, 0.f, 0.f};
    for (int k0 = 0; k0 < H_; k0 += 32) {
        bf16x8 a  = *(const bf16x8*)(Xs + l16 * 776 + k0 + qd * 8);
        bf16x8 bb = *(const bf16x8*)(Wp1T + (size_t)(n0 + l16) * H_ + k0 + qd * 8);
        acc = __builtin_amdgcn_mfma_f32_16x16x32_bf16(a, bb, acc, 0, 0, 0);
    }
    // C/D: col=l16 (j), row=qd*4+r (batch)
    #pragma unroll
    for (int r = 0; r < 4; ++r) {
        const int b = qd * 4 + r, j = n0 + l16;
        hidb[b * H_ + j] = f2b(tanhf(acc[r] + lda(bp1, j, bf)));
    }
}

// ---------- head2: logits, wave per (batch, label) ----------
__global__ __launch_bounds__(640) void head2_kernel(
    const u16* __restrict__ hidb, const void* __restrict__ Wp2, const void* __restrict__ bp2,
    float* __restrict__ lg, const int* __restrict__ fl) {
    const int bf = fl[0];
    const int b = blockIdx.x, j = threadIdx.x >> 6, lane = threadIdx.x & 63;
    float s = 0.f;
    for (int k = lane; k < H_; k += 64)
        s += b2f(hidb[b * H_ + k]) * lda(Wp2, (size_t)k * LAB_ + j, bf);
    #pragma unroll
    for (int m = 32; m >= 1; m >>= 1) s += __shfl_xor(s, m);
    if (lane == 0) lg[b * LAB_ + j] = s + lda(bp2, j, bf);
}

// ---------- head3: log-softmax loss + dual-format output ----------
__global__ __launch_bounds__(192) void head3_kernel(
    const float* __restrict__ lg, const int* __restrict__ tgt,
    void* __restrict__ outv, const int* __restrict__ fl) {
    __shared__ float lse[B_];
    const int bf = fl[0], t = threadIdx.x;
    if (t < B_) {
        float mx = -1e30f;
        for (int j = 0; j < LAB_; ++j) mx = fmaxf(mx, lg[t * LAB_ + j]);
        float s = 0.f;
        for (int j = 0; j < LAB_; ++j) s += expf(lg[t * LAB_ + j] - mx);
        lse[t] = mx + logf(s);
    }
    __syncthreads();
    float loss = 0.f;
    if (t == 0) {
        for (int b = 0; b < B_; ++b) loss += lse[b] - lg[b * LAB_ + tgt[b]];
        loss /= (float)B_;
    }
    if (bf) {
        u16* o = (u16*)outv;
        if (t == 0) o[0] = f2b(loss);
        if (t < B_ * LAB_) o[1 + t] = f2b(lg[t]);
    } else {
        float* o = (float*)outv;
        if (t == 0) o[0] = loss;
        if (t < B_ * LAB_) o[1 + t] = lg[t];
    }
}

// ---------- launch ----------
extern "C" void kernel_launch(void* const* d_in, const int* in_sizes, int n_in,
                              void* d_out, int out_size, void* d_ws, size_t ws_size,
                              hipStream_t stream) {
    (void)in_sizes; (void)n_in; (void)out_size; (void)ws_size;
    const int* src = (const int*)d_in[0];
    const int* seg = (const int*)d_in[1];
    const int* tgt = (const int*)d_in[2];
    const int* tib = (const int*)d_in[3];
    const void* we  = d_in[4];
    const void* pe  = d_in[5];
    const void* se  = d_in[6];
    const void* elg = d_in[7];
    const void* elb = d_in[8];
    const void* Wq  = d_in[9];
    const void* bq  = d_in[10];
    const void* Wk  = d_in[11];
    const void* bk  = d_in[12];
    const void* Wv  = d_in[13];
    const void* bv  = d_in[14];
    const void* Wo  = d_in[15];
    const void* bo  = d_in[16];
    const void* l1g = d_in[17];
    const void* l1b = d_in[18];
    const void* Wf1 = d_in[19];
    const void* bf1 = d_in[20];
    const void* Wf2 = d_in[21];
    const void* bf2 = d_in[22];
    const void* l2g = d_in[23];
    const void* l2b = d_in[24];
    const void* Wp1 = d_in[25];
    const void* bp1 = d_in[26];
    const void* Wp2 = d_in[27];
    const void* bp2 = d_in[28];
    const void* sf  = d_in[29];

    const size_t HH   = (size_t)H_ * H_;        // 589824
    const size_t HFF  = (size_t)H_ * FF_;       // 2359296
    const size_t MH   = (size_t)M_ * H_;        // 6291456
    const size_t MQKV = (size_t)M_ * STRQ;      // 18874368
    const size_t MFF  = (size_t)M_ * FF_;       // 25165824
    const size_t QKVW = (size_t)STRQ * H_;      // 1769472 (per-layer merged weight)

    char* w = (char*)d_ws;
    int* dflag  = (int*)w;  w += 256;
    u16* bias_ws = (u16*)w; w += 41472 * 2;     // prep_bias layout
    u16* WqkvT = (u16*)w;  w += L_ * QKVW * 2;
    u16* WoT   = (u16*)w;  w += L_ * HH  * 2;
    u16* Wf1T  = (u16*)w;  w += L_ * HFF * 2;
    u16* Wf2T  = (u16*)w;  w += L_ * HFF * 2;
    u16* Wp1T  = (u16*)w;  w += HH * 2;
    float* x32 = (float*)w; w += MH * 4;
    u16* xb    = (u16*)w;  w += MH * 2;
    u16* qkvb  = (u16*)w;  w += MQKV * 2;
    u16* ctxb  = (u16*)w;  w += MH * 2;
    u16* tmpb  = (u16*)w;  w += MH * 2;
    u16* ffb   = (u16*)w;  w += MFF * 2;
    u16* hidb  = (u16*)w;  w += (size_t)B_ * H_ * 2;
    float* lg  = (float*)w; w += (size_t)B_ * LAB_ * 4;

    u16* bqkv = bias_ws;            // 6 x 2304
    u16* bo6  = bias_ws + 13824;    // 6 x 768
    u16* bf16_= bias_ws + 18432;    // 6 x 3072
    u16* bf26 = bias_ws + 36864;    // 6 x 768

    const dim3 tb(256);
    detect_kernel<<<1, 1, 0, stream>>>((const u32*)elg, dflag);
    prep_bias<<<162, tb, 0, stream>>>(bq, bk, bv, bo, bf1, bf2, bias_ws, dflag);

    // weight transposes+convert; Wq/Wk/Wv interleave into per-layer 2304x768 blocks
    transpose_k<<<dim3(12, 12, 6), tb, 0, stream>>>(Wq, WqkvT,                    H_, H_, (long)HH, (long)QKVW, dflag);
    transpose_k<<<dim3(12, 12, 6), tb, 0, stream>>>(Wk, WqkvT + (size_t)768*768,  H_, H_, (long)HH, (long)QKVW, dflag);
    transpose_k<<<dim3(12, 12, 6), tb, 0, stream>>>(Wv, WqkvT + (size_t)1536*768, H_, H_, (long)HH, (long)QKVW, dflag);
    transpose_k<<<dim3(12, 12, 6), tb, 0, stream>>>(Wo,  WoT,  H_, H_,  (long)HH,  (long)HH,  dflag);
    transpose_k<<<dim3(48, 12, 6), tb, 0, stream>>>(Wf1, Wf1T, H_, FF_, (long)HFF, (long)HFF, dflag);
    transpose_k<<<dim3(12, 48, 6), tb, 0, stream>>>(Wf2, Wf2T, FF_, H_, (long)HFF, (long)HFF, dflag);
    transpose_k<<<dim3(12, 12, 1), tb, 0, stream>>>(Wp1, Wp1T, H_, H_,  (long)HH,  (long)HH,  dflag);

    embed_kernel<<<M_, tb, 0, stream>>>(src, seg, tib, we, pe, se, elg, elb, sf, x32, xb, dflag);

    for (int l = 0; l < L_; ++l) {
        gemm_bt<<<dim3(STRQ / 128, M_ / 128), tb, 0, stream>>>(xb, WqkvT + l * QKVW, bqkv + l * STRQ, qkvb, M_, STRQ, H_, 0);
        attn_kernel<<<dim3(S_ / 64, NH_, B_), tb, 0, stream>>>(qkvb, seg, ctxb);
        gemm_bt<<<dim3(H_ / 128, M_ / 128), tb, 0, stream>>>(ctxb, WoT + l * HH, bo6 + l * H_, tmpb, M_, H_, H_, 0);
        add_ln_kernel<<<M_, tb, 0, stream>>>(x32, tmpb, l1g, l1b, (long)l * H_, x32, xb, dflag);
        gemm_bt<<<dim3(FF_ / 128, M_ / 128), tb, 0, stream>>>(xb, Wf1T + l * HFF, bf16_ + l * FF_, ffb, M_, FF_, H_, 1);
        gemm_bt<<<dim3(H_ / 128, M_ / 128), tb, 0, stream>>>(ffb, Wf2T + l * HFF, bf26 + l * H_, tmpb, M_, H_, FF_, 0);
        add_ln_kernel<<<M_, tb, 0, stream>>>(x32, tmpb, l2g, l2b, (long)l * H_, x32, xb, dflag);
    }

    head1_kernel<<<12, tb, 0, stream>>>(xb, Wp1T, bp1, hidb, dflag);
    head2_kernel<<<B_, dim3(640), 0, stream>>>(hidb, Wp2, bp2, lg, dflag);
    head3_kernel<<<1, dim3(192), 0, stream>>>(lg, tgt, d_out, dflag);
}

// Round 4
// 2082.555 us; speedup vs baseline: 1.3125x; 1.0027x over previous
//
#include <hip/hip_runtime.h>

typedef unsigned short u16;
typedef unsigned int   u32;
typedef __bf16  bf16x8 __attribute__((ext_vector_type(8)));
typedef float   f32x4  __attribute__((ext_vector_type(4)));

#define B_   16
#define S_   512
#define H_   768
#define NH_  12
#define L_   6
#define FF_  3072
#define M_   8192     // B_*S_
#define LAB_ 10
#define STRQ 2304     // merged qkv row stride

// ---------- bf16 helpers (storage = u16 bits) ----------
__device__ __forceinline__ float b2f(u16 x) {
    u32 u = ((u32)x) << 16; float f; __builtin_memcpy(&f, &u, 4); return f;
}
__device__ __forceinline__ u16 f2b(float f) {
    u32 u; __builtin_memcpy(&u, &f, 4);
    u32 r = u + 0x7FFFu + ((u >> 16) & 1u);
    return (u16)(r >> 16);
}
__device__ __forceinline__ float lda(const void* p, size_t i, int bf) {
    return bf ? b2f(((const u16*)p)[i]) : ((const float*)p)[i];
}
__device__ __forceinline__ float gelu_tanh(float x) {
    return 0.5f * x * (1.0f + tanhf(0.7978845608028654f * (x + 0.044715f * x * x * x)));
}
// async global->LDS, 16B per lane; LDS dest must be wave-uniform base + lane*16
__device__ __forceinline__ void async_lds16(const u16* g, u16* l) {
    __builtin_amdgcn_global_load_lds(
        (const __attribute__((address_space(1))) u32*)(const void*)g,
        (__attribute__((address_space(3))) u32*)(void*)l, 16, 0, 0);
}

// ---------- dtype detect: emb_ln_g is all ones ----------
__global__ void detect_kernel(const u32* __restrict__ g, int* __restrict__ flag) {
    flag[0] = (g[0] == 0x3F803F80u) ? 1 : 0;   // bf16 ones pair vs fp32 one
}

// ---------- block reduce (sum of two values), 256 threads ----------
__device__ __forceinline__ void block_reduce2(float& s, float& s2, float* red, int tid) {
    int lane = tid & 63, wave = tid >> 6;
    #pragma unroll
    for (int m = 32; m >= 1; m >>= 1) { s += __shfl_xor(s, m); s2 += __shfl_xor(s2, m); }
    if (lane == 0) { red[wave] = s; red[4 + wave] = s2; }
    __syncthreads();
    s  = red[0] + red[1] + red[2] + red[3];
    s2 = red[4] + red[5] + red[6] + red[7];
}

// ---------- weight transpose+convert: in (K x N) -> out bf16 (N x K) ----------
__global__ __launch_bounds__(256) void transpose_k(const void* __restrict__ in,
                                                   u16* __restrict__ out, int K, int N,
                                                   long in_lstride, long out_lstride,
                                                   const int* __restrict__ fl) {
    __shared__ u16 tile[64][65];
    const int bf = fl[0];
    const size_t ioff = (size_t)blockIdx.z * (size_t)in_lstride;
    const size_t ooff = (size_t)blockIdx.z * (size_t)out_lstride;
    int k0 = blockIdx.y * 64, n0 = blockIdx.x * 64;
    int c = threadIdx.x & 63, r0 = threadIdx.x >> 6;
    #pragma unroll
    for (int r = r0; r < 64; r += 4) {
        size_t idx = ioff + (size_t)(k0 + r) * N + n0 + c;
        tile[r][c] = bf ? ((const u16*)in)[idx] : f2b(((const float*)in)[idx]);
    }
    __syncthreads();
    #pragma unroll
    for (int r = r0; r < 64; r += 4)
        out[ooff + (size_t)(n0 + r) * K + k0 + c] = tile[c][r];
}

// ---------- bias prep: convert all GEMM biases to bf16, qkv concatenated ----------
// layout: [0,13824) bqkv (6 x 2304) | [13824,18432) bo | [18432,36864) bf1 | [36864,41472) bf2
__global__ __launch_bounds__(256) void prep_bias(
    const void* __restrict__ bq, const void* __restrict__ bk, const void* __restrict__ bv,
    const void* __restrict__ bo, const void* __restrict__ bf1, const void* __restrict__ bf2,
    u16* __restrict__ out, const int* __restrict__ fl) {
    const int bf = fl[0];
    int i = blockIdx.x * 256 + threadIdx.x;
    if (i >= 41472) return;
    float v;
    if (i < 13824) {
        int l = i / 2304, c = i % 2304;
        v = (c < 768) ? lda(bq, (size_t)l * 768 + c, bf)
          : (c < 1536) ? lda(bk, (size_t)l * 768 + c - 768, bf)
                       : lda(bv, (size_t)l * 768 + c - 1536, bf);
    } else if (i < 18432) v = lda(bo,  i - 13824, bf);
    else if (i < 36864)   v = lda(bf1, i - 18432, bf);
    else                  v = lda(bf2, i - 36864, bf);
    out[i] = f2b(v);
}

// ---------- embedding + LN + selection scale ----------
__global__ __launch_bounds__(256) void embed_kernel(
    const int* __restrict__ src, const int* __restrict__ seg, const int* __restrict__ tib,
    const void* __restrict__ we, const void* __restrict__ pe, const void* __restrict__ se,
    const void* __restrict__ g, const void* __restrict__ bb, const void* __restrict__ sf,
    float* __restrict__ x32, u16* __restrict__ xb, const int* __restrict__ fl) {
    __shared__ float red[8];
    const int bf = fl[0];
    const int r = blockIdx.x, tid = threadIdx.x;
    const int s = r & (S_ - 1);
    const int w = src[r], sg = seg[r];
    const float scale = lda(sf, tib[r], bf);
    float v[3]; int col[3];
    #pragma unroll
    for (int i = 0; i < 3; ++i) {
        col[i] = tid + i * 256;
        v[i] = lda(we, (size_t)w * H_ + col[i], bf) + lda(pe, (size_t)s * H_ + col[i], bf)
             + lda(se, (size_t)sg * H_ + col[i], bf);
    }
    float su = v[0] + v[1] + v[2];
    float sq = v[0]*v[0] + v[1]*v[1] + v[2]*v[2];
    block_reduce2(su, sq, red, tid);
    const float mean = su * (1.0f / H_);
    const float var  = sq * (1.0f / H_) - mean * mean;
    const float inv  = rsqrtf(var + 1e-5f);
    #pragma unroll
    for (int i = 0; i < 3; ++i) {
        float y = ((v[i] - mean) * inv * lda(g, col[i], bf) + lda(bb, col[i], bf)) * scale;
        x32[(size_t)r * H_ + col[i]] = y;
        xb [(size_t)r * H_ + col[i]] = f2b(y);
    }
}

// ---------- residual add + LN (x32 master, bf16 shadow out) ----------
__global__ __launch_bounds__(256) void add_ln_kernel(
    const float* __restrict__ xin, const u16* __restrict__ t,
    const void* __restrict__ g, const void* __restrict__ bb, long goff,
    float* __restrict__ xout, u16* __restrict__ xb, const int* __restrict__ fl) {
    __shared__ float red[8];
    const int bf = fl[0];
    const int r = blockIdx.x, tid = threadIdx.x;
    const size_t rb = (size_t)r * H_;
    float v[3]; int col[3];
    #pragma unroll
    for (int i = 0; i < 3; ++i) {
        col[i] = tid + i * 256;
        v[i] = xin[rb + col[i]] + b2f(t[rb + col[i]]);
    }
    float su = v[0] + v[1] + v[2];
    float sq = v[0]*v[0] + v[1]*v[1] + v[2]*v[2];
    block_reduce2(su, sq, red, tid);
    const float mean = su * (1.0f / H_);
    const float var  = sq * (1.0f / H_) - mean * mean;
    const float inv  = rsqrtf(var + 1e-5f);
    #pragma unroll
    for (int i = 0; i < 3; ++i) {
        float y = (v[i] - mean) * inv * lda(g, goff + col[i], bf) + lda(bb, goff + col[i], bf);
        xout[rb + col[i]] = y;
        xb  [rb + col[i]] = f2b(y);
    }
}

// =====================================================================
// MFMA GEMM (m97-style, 128xBNT tile, 256 thr): BK=64, XOR chunk swizzle.
// BNT=128: QKV/FF1 (large-N grids, >=4 blocks/CU available).
// BNT=64:  Wo/FF2 (N=768): round-3 counters showed 6x64=384 blocks ->
//   1.2 blocks/CU -> Occupancy 15%, MfmaUtil 19% (latency-bound, all
//   pipes idle). 12x64=768 blocks -> 3 blocks/CU restores inter-block
//   overlap (m114). LDS 16+8=24KB (6 fit), VGPR ~84 unchanged.
// K-accumulation order per output element unchanged -> bit-identical.
// =====================================================================
template<int BNT>
__global__ __launch_bounds__(256) void gemm_bt(
    const u16* __restrict__ A, const u16* __restrict__ Bt, const u16* __restrict__ bias,
    u16* __restrict__ C, int M, int N, int K, int act) {
    constexpr int NREP = BNT / 32;          // n-frags per wave: 4 or 2
    constexpr int BCH  = BNT / 32;          // B staging chunks per thread: 4 or 2
    __shared__ alignas(16) u16 As[128 * 64];
    __shared__ alignas(16) u16 Bs[BNT * 64];
    const int tid = threadIdx.x;
    const int bm = blockIdx.y * 128, bn = blockIdx.x * BNT;
    const int wave = tid >> 6, lane = tid & 63;
    const int wm = (wave >> 1) * 64, wn = (wave & 1) * (BNT / 2);
    const int qd = lane >> 4, l16 = lane & 15;
    const int l7 = l16 & 7;

    const f32x4 fz = {0.f, 0.f, 0.f, 0.f};
    f32x4 acc[4][NREP];
    #pragma unroll
    for (int i = 0; i < 4; ++i)
        #pragma unroll
        for (int j = 0; j < NREP; ++j) acc[i][j] = fz;

    // staging: tile rows x 64 cols; thread covers chunks tid+u*256.
    // LDS dest linear (chunk c at base+c*8); global source chunk = (c&7)^(row&7).
    const u16* Ag[4]; int dofsA[4];
    #pragma unroll
    for (int u = 0; u < 4; ++u) {
        const int c = tid + u * 256;
        const int r = c >> 3;
        const int cs = ((c & 7) ^ (r & 7)) * 8;
        Ag[u] = A + (size_t)(bm + r) * K + cs;
        dofsA[u] = c * 8;
    }
    const u16* Bg[BCH]; int dofsB[BCH];
    #pragma unroll
    for (int u = 0; u < BCH; ++u) {
        const int c = tid + u * 256;
        const int r = c >> 3;
        const int cs = ((c & 7) ^ (r & 7)) * 8;
        Bg[u] = Bt + (size_t)(bn + r) * K + cs;
        dofsB[u] = c * 8;
    }

    for (int k0 = 0; k0 < K; k0 += 64) {
        __syncthreads();               // prev iter's LDS reads complete
        #pragma unroll
        for (int u = 0; u < 4; ++u) async_lds16(Ag[u] + k0, As + dofsA[u]);
        #pragma unroll
        for (int u = 0; u < BCH; ++u) async_lds16(Bg[u] + k0, Bs + dofsB[u]);
        __syncthreads();               // vmcnt drained by barrier semantics
        bf16x8 af[4][2], bfv[NREP][2];
        #pragma unroll
        for (int i = 0; i < 4; ++i)
            #pragma unroll
            for (int kd = 0; kd < 2; ++kd) {
                const int sw = (((kd << 2) | qd) ^ l7) << 3;   // swizzled 16B chunk
                af[i][kd] = *(const bf16x8*)(As + (wm + i * 16 + l16) * 64 + sw);
            }
        #pragma unroll
        for (int j = 0; j < NREP; ++j)
            #pragma unroll
            for (int kd = 0; kd < 2; ++kd) {
                const int sw = (((kd << 2) | qd) ^ l7) << 3;
                bfv[j][kd] = *(const bf16x8*)(Bs + (wn + j * 16 + l16) * 64 + sw);
            }
        #pragma unroll
        for (int i = 0; i < 4; ++i)
            #pragma unroll
            for (int j = 0; j < NREP; ++j)
                #pragma unroll
                for (int kd = 0; kd < 2; ++kd)
                    acc[i][j] = __builtin_amdgcn_mfma_f32_16x16x32_bf16(af[i][kd], bfv[j][kd], acc[i][j], 0, 0, 0);
    }

    // epilogue: C/D layout col=lane&15, row=(lane>>4)*4+reg
    #pragma unroll
    for (int i = 0; i < 4; ++i) {
        const int row0 = bm + wm + i * 16 + qd * 4;
        #pragma unroll
        for (int j = 0; j < NREP; ++j) {
            const int col = bn + wn + j * 16 + l16;
            const float bv = b2f(bias[col]);
            #pragma unroll
            for (int r = 0; r < 4; ++r) {
                float v = acc[i][j][r] + bv;
                if (act == 1) v = gelu_tanh(v);
                C[(size_t)(row0 + r) * N + col] = f2b(v);
            }
        }
    }
}

// ---------- flash attention: 64 queries/block, online softmax, MFMA QK^T and PV ----------
__global__ __launch_bounds__(256) void attn_kernel(
    const u16* __restrict__ QKV, const int* __restrict__ seg, u16* __restrict__ Cb) {
    __shared__ alignas(16) u16 Qs[64 * 72];     // [q][d]
    __shared__ alignas(16) u16 Ks[128 * 72];    // [key][d]
    __shared__ alignas(16) u16 Vt[64 * 136];    // [d][key] with 16B-block xor swizzle
    __shared__ alignas(16) u16 Ps[64 * 136];    // [q][key]
    __shared__ float biasv[512];
    const int tid = threadIdx.x;
    const int qt = blockIdx.x, h = blockIdx.y, b = blockIdx.z;
    const int wave = tid >> 6, lane = tid & 63;
    const int qd = lane >> 4, l16 = lane & 15;
    const u16* Qg = QKV + (size_t)b * S_ * STRQ + h * 64;
    const u16* Kg = Qg + 768;
    const u16* Vg = Qg + 1536;

    for (int i = tid; i < 512; i += 256)
        biasv[i] = (seg[b * S_ + i] > 0) ? 0.0f : -1e9f;

    {   // stage Q tile 64x64 = 512 uint4 items
        int c = tid;
        #pragma unroll
        for (int u = 0; u < 2; ++u, c += 256) {
            int r = c >> 3, c8 = (c & 7) * 8;
            uint4 v4 = *(const uint4*)(Qg + (size_t)(qt * 64 + r) * STRQ + c8);
            *(uint4*)(Qs + r * 72 + c8) = v4;
        }
    }

    float m_run[4], l_run[4];
    f32x4 accO[4];
    #pragma unroll
    for (int r = 0; r < 4; ++r) { m_run[r] = -3.0e38f; l_run[r] = 0.f; }
    #pragma unroll
    for (int dt = 0; dt < 4; ++dt) accO[dt] = {0.f, 0.f, 0.f, 0.f};

    for (int kt = 0; kt < 512; kt += 128) {
        __syncthreads();                       // prev iter's Ks/Vt reads complete
        {   // stage K tile 128x64 = 1024 uint4 items
            int c = tid;
            #pragma unroll
            for (int u = 0; u < 4; ++u, c += 256) {
                int r = c >> 3, c8 = (c & 7) * 8;
                uint4 v4 = *(const uint4*)(Kg + (size_t)(kt + r) * STRQ + c8);
                *(uint4*)(Ks + r * 72 + c8) = v4;
            }
        }
        {   // stage V tile transposed: Vt[d][key], key-block xor-swizzled (1024 items)
            int c = tid;
            #pragma unroll
            for (int u = 0; u < 4; ++u, c += 256) {
                int r = c >> 3, d8 = (c & 7) * 8;
                uint4 v4 = *(const uint4*)(Vg + (size_t)(kt + r) * STRQ + d8);
                u16 tmp[8]; *(uint4*)tmp = v4;
                #pragma unroll
                for (int j = 0; j < 8; ++j) {
                    int d = d8 + j;
                    int blk = (r >> 3) ^ (d >> 3);
                    Vt[d * 136 + blk * 8 + (r & 7)] = tmp[j];
                }
            }
        }
        __syncthreads();

        // ---- QK^T: wave owns q rows wave*16..+15, all 128 keys ----
        f32x4 s[8];
        {
            bf16x8 aq[2];
            #pragma unroll
            for (int kd = 0; kd < 2; ++kd)
                aq[kd] = *(const bf16x8*)(Qs + (wave * 16 + l16) * 72 + kd * 32 + qd * 8);
            #pragma unroll
            for (int nt = 0; nt < 8; ++nt) {
                s[nt] = {0.f, 0.f, 0.f, 0.f};
                #pragma unroll
                for (int kd = 0; kd < 2; ++kd) {
                    bf16x8 bk = *(const bf16x8*)(Ks + (nt * 16 + l16) * 72 + kd * 32 + qd * 8);
                    s[nt] = __builtin_amdgcn_mfma_f32_16x16x32_bf16(aq[kd], bk, s[nt], 0, 0, 0);
                }
            }
        }
        // scale + mask bias (bias depends on key = col = nt*16+l16)
        #pragma unroll
        for (int nt = 0; nt < 8; ++nt) {
            const float bv = biasv[kt + nt * 16 + l16];
            #pragma unroll
            for (int r = 0; r < 4; ++r) s[nt][r] = s[nt][r] * 0.125f + bv;
        }
        // online softmax: rows live in (qd, r); reduce across 16 l16 lanes
        float alpha[4], rsum[4];
        #pragma unroll
        for (int r = 0; r < 4; ++r) {
            float m = s[0][r];
            #pragma unroll
            for (int nt = 1; nt < 8; ++nt) m = fmaxf(m, s[nt][r]);
            #pragma unroll
            for (int msk = 8; msk >= 1; msk >>= 1) m = fmaxf(m, __shfl_xor(m, msk));
            float mn = fmaxf(m_run[r], m);
            alpha[r] = __expf(m_run[r] - mn);
            m_run[r] = mn;
            rsum[r] = 0.f;
        }
        #pragma unroll
        for (int nt = 0; nt < 8; ++nt)
            #pragma unroll
            for (int r = 0; r < 4; ++r) {
                float p = __expf(s[nt][r] - m_run[r]);
                rsum[r] += p;
                Ps[(wave * 16 + qd * 4 + r) * 136 + nt * 16 + l16] = f2b(p);
            }
        #pragma unroll
        for (int r = 0; r < 4; ++r) {
            float t = rsum[r];
            #pragma unroll
            for (int msk = 8; msk >= 1; msk >>= 1) t += __shfl_xor(t, msk);
            l_run[r] = l_run[r] * alpha[r] + t;
        }
        #pragma unroll
        for (int dt = 0; dt < 4; ++dt)
            #pragma unroll
            for (int r = 0; r < 4; ++r) accO[dt][r] *= alpha[r];
        __syncthreads();                       // Ps visible (and Vt already staged)

        // ---- PV: O(16x64) += P(16x128) @ V(128x64) ----
        #pragma unroll
        for (int kk = 0; kk < 4; ++kk) {
            bf16x8 ap = *(const bf16x8*)(Ps + (wave * 16 + l16) * 136 + kk * 32 + qd * 8);
            #pragma unroll
            for (int dt = 0; dt < 4; ++dt) {
                const int d = dt * 16 + l16;
                const int blk = (kk * 4 + qd) ^ (d >> 3);
                bf16x8 bv = *(const bf16x8*)(Vt + d * 136 + blk * 8);
                accO[dt] = __builtin_amdgcn_mfma_f32_16x16x32_bf16(ap, bv, accO[dt], 0, 0, 0);
            }
        }
    }

    // epilogue: normalize and write ctx [row][h*64+d]
    #pragma unroll
    for (int r = 0; r < 4; ++r) {
        const int row = qt * 64 + wave * 16 + qd * 4 + r;
        const float inv = 1.0f / l_run[r];
        const size_t obase = ((size_t)b * S_ + row) * H_ + h * 64;
        #pragma unroll
        for (int dt = 0; dt < 4; ++dt)
            Cb[obase + dt * 16 + l16] = f2b(accO[dt][r] * inv);
    }
}

// ---------- head1: hid = tanh(pooled @ Wp1 + bp1) via MFMA, one wave per 16x16 tile ----------
__global__ __launch_bounds__(256) void head1_kernel(
    const u16* __restrict__ xb, const u16* __restrict__ Wp1T,
    const void* __restrict__ bp1, u16* __restrict__ hidb, const int* __restrict__ fl) {
    __shared__ alignas(16) u16 Xs[16 * 776];     // stride 776 breaks 16-way bank alias
    const int bf = fl[0];
    const int tid = threadIdx.x, wave = tid >> 6, lane = tid & 63;
    const int qd = lane >> 4, l16 = lane & 15;
    for (int i = tid; i < 16 * 96; i += 256) {   // 96 uint4 per pooled row
        int b = i / 96, c = (i % 96) * 8;
        *(uint4*)(Xs + b * 776 + c) = *(const uint4*)(xb + ((size_t)b * S_) * H_ + c);
    }
    __syncthreads();
    const int n0 = (blockIdx.x * 4 + wave) * 16;
    f32x4 acc = {0.f, 0.f, 0.f, 0.f};
    for (int k0 = 0; k0 < H_; k0 += 32) {
        bf16x8 a  = *(const bf16x8*)(Xs + l16 * 776 + k0 + qd * 8);
        bf16x8 bb = *(const bf16x8*)(Wp1T + (size_t)(n0 + l16) * H_ + k0 + qd * 8);
        acc = __builtin_amdgcn_mfma_f32_16x16x32_bf16(a, bb, acc, 0, 0, 0);
    }
    // C/D: col=l16 (j), row=qd*4+r (batch)
    #pragma unroll
    for (int r = 0; r < 4; ++r) {
        const int b = qd * 4 + r, j = n0 + l16;
        hidb[b * H_ + j] = f2b(tanhf(acc[r] + lda(bp1, j, bf)));
    }
}

// ---------- head2: logits, wave per (batch, label) ----------
__global__ __launch_bounds__(640) void head2_kernel(
    const u16* __restrict__ hidb, const void* __restrict__ Wp2, const void* __restrict__ bp2,
    float* __restrict__ lg, const int* __restrict__ fl) {
    const int bf = fl[0];
    const int b = blockIdx.x, j = threadIdx.x >> 6, lane = threadIdx.x & 63;
    float s = 0.f;
    for (int k = lane; k < H_; k += 64)
        s += b2f(hidb[b * H_ + k]) * lda(Wp2, (size_t)k * LAB_ + j, bf);
    #pragma unroll
    for (int m = 32; m >= 1; m >>= 1) s += __shfl_xor(s, m);
    if (lane == 0) lg[b * LAB_ + j] = s + lda(bp2, j, bf);
}

// ---------- head3: log-softmax loss + dual-format output ----------
__global__ __launch_bounds__(192) void head3_kernel(
    const float* __restrict__ lg, const int* __restrict__ tgt,
    void* __restrict__ outv, const int* __restrict__ fl) {
    __shared__ float lse[B_];
    const int bf = fl[0], t = threadIdx.x;
    if (t < B_) {
        float mx = -1e30f;
        for (int j = 0; j < LAB_; ++j) mx = fmaxf(mx, lg[t * LAB_ + j]);
        float s = 0.f;
        for (int j = 0; j < LAB_; ++j) s += expf(lg[t * LAB_ + j] - mx);
        lse[t] = mx + logf(s);
    }
    __syncthreads();
    float loss = 0.f;
    if (t == 0) {
        for (int b = 0; b < B_; ++b) loss += lse[b] - lg[b * LAB_ + tgt[b]];
        loss /= (float)B_;
    }
    if (bf) {
        u16* o = (u16*)outv;
        if (t == 0) o[0] = f2b(loss);
        if (t < B_ * LAB_) o[1 + t] = f2b(lg[t]);
    } else {
        float* o = (float*)outv;
        if (t == 0) o[0] = loss;
        if (t < B_ * LAB_) o[1 + t] = lg[t];
    }
}

// ---------- launch ----------
extern "C" void kernel_launch(void* const* d_in, const int* in_sizes, int n_in,
                              void* d_out, int out_size, void* d_ws, size_t ws_size,
                              hipStream_t stream) {
    (void)in_sizes; (void)n_in; (void)out_size; (void)ws_size;
    const int* src = (const int*)d_in[0];
    const int* seg = (const int*)d_in[1];
    const int* tgt = (const int*)d_in[2];
    const int* tib = (const int*)d_in[3];
    const void* we  = d_in[4];
    const void* pe  = d_in[5];
    const void* se  = d_in[6];
    const void* elg = d_in[7];
    const void* elb = d_in[8];
    const void* Wq  = d_in[9];
    const void* bq  = d_in[10];
    const void* Wk  = d_in[11];
    const void* bk  = d_in[12];
    const void* Wv  = d_in[13];
    const void* bv  = d_in[14];
    const void* Wo  = d_in[15];
    const void* bo  = d_in[16];
    const void* l1g = d_in[17];
    const void* l1b = d_in[18];
    const void* Wf1 = d_in[19];
    const void* bf1 = d_in[20];
    const void* Wf2 = d_in[21];
    const void* bf2 = d_in[22];
    const void* l2g = d_in[23];
    const void* l2b = d_in[24];
    const void* Wp1 = d_in[25];
    const void* bp1 = d_in[26];
    const void* Wp2 = d_in[27];
    const void* bp2 = d_in[28];
    const void* sf  = d_in[29];

    const size_t HH   = (size_t)H_ * H_;        // 589824
    const size_t HFF  = (size_t)H_ * FF_;       // 2359296
    const size_t MH   = (size_t)M_ * H_;        // 6291456
    const size_t MQKV = (size_t)M_ * STRQ;      // 18874368
    const size_t MFF  = (size_t)M_ * FF_;       // 25165824
    const size_t QKVW = (size_t)STRQ * H_;      // 1769472 (per-layer merged weight)

    char* w = (char*)d_ws;
    int* dflag  = (int*)w;  w += 256;
    u16* bias_ws = (u16*)w; w += 41472 * 2;     // prep_bias layout
    u16* WqkvT = (u16*)w;  w += L_ * QKVW * 2;
    u16* WoT   = (u16*)w;  w += L_ * HH  * 2;
    u16* Wf1T  = (u16*)w;  w += L_ * HFF * 2;
    u16* Wf2T  = (u16*)w;  w += L_ * HFF * 2;
    u16* Wp1T  = (u16*)w;  w += HH * 2;
    float* x32 = (float*)w; w += MH * 4;
    u16* xb    = (u16*)w;  w += MH * 2;
    u16* qkvb  = (u16*)w;  w += MQKV * 2;
    u16* ctxb  = (u16*)w;  w += MH * 2;
    u16* tmpb  = (u16*)w;  w += MH * 2;
    u16* ffb   = (u16*)w;  w += MFF * 2;
    u16* hidb  = (u16*)w;  w += (size_t)B_ * H_ * 2;
    float* lg  = (float*)w; w += (size_t)B_ * LAB_ * 4;

    u16* bqkv = bias_ws;            // 6 x 2304
    u16* bo6  = bias_ws + 13824;    // 6 x 768
    u16* bf16_= bias_ws + 18432;    // 6 x 3072
    u16* bf26 = bias_ws + 36864;    // 6 x 768

    const dim3 tb(256);
    detect_kernel<<<1, 1, 0, stream>>>((const u32*)elg, dflag);
    prep_bias<<<162, tb, 0, stream>>>(bq, bk, bv, bo, bf1, bf2, bias_ws, dflag);

    // weight transposes+convert; Wq/Wk/Wv interleave into per-layer 2304x768 blocks
    transpose_k<<<dim3(12, 12, 6), tb, 0, stream>>>(Wq, WqkvT,                    H_, H_, (long)HH, (long)QKVW, dflag);
    transpose_k<<<dim3(12, 12, 6), tb, 0, stream>>>(Wk, WqkvT + (size_t)768*768,  H_, H_, (long)HH, (long)QKVW, dflag);
    transpose_k<<<dim3(12, 12, 6), tb, 0, stream>>>(Wv, WqkvT + (size_t)1536*768, H_, H_, (long)HH, (long)QKVW, dflag);
    transpose_k<<<dim3(12, 12, 6), tb, 0, stream>>>(Wo,  WoT,  H_, H_,  (long)HH,  (long)HH,  dflag);
    transpose_k<<<dim3(48, 12, 6), tb, 0, stream>>>(Wf1, Wf1T, H_, FF_, (long)HFF, (long)HFF, dflag);
    transpose_k<<<dim3(12, 48, 6), tb, 0, stream>>>(Wf2, Wf2T, FF_, H_, (long)HFF, (long)HFF, dflag);
    transpose_k<<<dim3(12, 12, 1), tb, 0, stream>>>(Wp1, Wp1T, H_, H_,  (long)HH,  (long)HH,  dflag);

    embed_kernel<<<M_, tb, 0, stream>>>(src, seg, tib, we, pe, se, elg, elb, sf, x32, xb, dflag);

    for (int l = 0; l < L_; ++l) {
        // QKV: M x 2304 x 768 (BN=128, 18x64=1152 blocks)
        gemm_bt<128><<<dim3(STRQ / 128, M_ / 128), tb, 0, stream>>>(xb, WqkvT + l * QKVW, bqkv + l * STRQ, qkvb, M_, STRQ, H_, 0);
        attn_kernel<<<dim3(S_ / 64, NH_, B_), tb, 0, stream>>>(qkvb, seg, ctxb);
        // Wo: M x 768 x 768 (BN=64, 12x64=768 blocks -> 3 blocks/CU)
        gemm_bt<64><<<dim3(H_ / 64, M_ / 128), tb, 0, stream>>>(ctxb, WoT + l * HH, bo6 + l * H_, tmpb, M_, H_, H_, 0);
        add_ln_kernel<<<M_, tb, 0, stream>>>(x32, tmpb, l1g, l1b, (long)l * H_, x32, xb, dflag);
        // FF1: M x 3072 x 768 + gelu (BN=128, 24x64=1536 blocks)
        gemm_bt<128><<<dim3(FF_ / 128, M_ / 128), tb, 0, stream>>>(xb, Wf1T + l * HFF, bf16_ + l * FF_, ffb, M_, FF_, H_, 1);
        // FF2: M x 768 x 3072 (BN=64, 768 blocks)
        gemm_bt<64><<<dim3(H_ / 64, M_ / 128), tb, 0, stream>>>(ffb, Wf2T + l * HFF, bf26 + l * H_, tmpb, M_, H_, FF_, 0);
        add_ln_kernel<<<M_, tb, 0, stream>>>(x32, tmpb, l2g, l2b, (long)l * H_, x32, xb, dflag);
    }

    head1_kernel<<<12, tb, 0, stream>>>(xb, Wp1T, bp1, hidb, dflag);
    head2_kernel<<<B_, dim3(640), 0, stream>>>(hidb, Wp2, bp2, lg, dflag);
    head3_kernel<<<1, dim3(192), 0, stream>>>(lg, tgt, d_out, dflag);
}

// Round 5
// 1964.365 us; speedup vs baseline: 1.3914x; 1.0602x over previous
//
#include <hip/hip_runtime.h>

typedef unsigned short u16;
typedef unsigned int   u32;
typedef __bf16  bf16x8 __attribute__((ext_vector_type(8)));
typedef float   f32x4  __attribute__((ext_vector_type(4)));

#define B_   16
#define S_   512
#define H_   768
#define NH_  12
#define L_   6
#define FF_  3072
#define M_   8192     // B_*S_
#define LAB_ 10
#define STRQ 2304     // merged qkv row stride

// ---------- bf16 helpers (storage = u16 bits) ----------
__device__ __forceinline__ float b2f(u16 x) {
    u32 u = ((u32)x) << 16; float f; __builtin_memcpy(&f, &u, 4); return f;
}
__device__ __forceinline__ u16 f2b(float f) {
    u32 u; __builtin_memcpy(&u, &f, 4);
    u32 r = u + 0x7FFFu + ((u >> 16) & 1u);
    return (u16)(r >> 16);
}
__device__ __forceinline__ float lda(const void* p, size_t i, int bf) {
    return bf ? b2f(((const u16*)p)[i]) : ((const float*)p)[i];
}
// gelu tanh-approx reformed as sigmoid: 0.5x(1+tanh(z)) = x/(1+exp(-2z)),
// 2z = 1.5957691216.. * x * (1 + 0.044715 x^2). v_exp + v_rcp (~9 VALU inst)
// vs libm tanhf (~30-50): round-4 counters showed FF1 at 66% VALUBusy from
// the tanhf epilogue. Saturation safe: exp->inf -> rcp->0 -> gelu=0.
__device__ __forceinline__ float gelu_tanh(float x) {
    float e = __expf(-1.5957691216057308f * x * fmaf(0.044715f, x * x, 1.0f));
    return x * __builtin_amdgcn_rcpf(1.0f + e);
}
// async global->LDS, 16B per lane; LDS dest must be wave-uniform base + lane*16
__device__ __forceinline__ void async_lds16(const u16* g, u16* l) {
    __builtin_amdgcn_global_load_lds(
        (const __attribute__((address_space(1))) u32*)(const void*)g,
        (__attribute__((address_space(3))) u32*)(void*)l, 16, 0, 0);
}

// ---------- dtype detect: emb_ln_g is all ones ----------
__global__ void detect_kernel(const u32* __restrict__ g, int* __restrict__ flag) {
    flag[0] = (g[0] == 0x3F803F80u) ? 1 : 0;   // bf16 ones pair vs fp32 one
}

// ---------- block reduce (sum of two values), 256 threads ----------
__device__ __forceinline__ void block_reduce2(float& s, float& s2, float* red, int tid) {
    int lane = tid & 63, wave = tid >> 6;
    #pragma unroll
    for (int m = 32; m >= 1; m >>= 1) { s += __shfl_xor(s, m); s2 += __shfl_xor(s2, m); }
    if (lane == 0) { red[wave] = s; red[4 + wave] = s2; }
    __syncthreads();
    s  = red[0] + red[1] + red[2] + red[3];
    s2 = red[4] + red[5] + red[6] + red[7];
}

// ---------- weight transpose+convert: in (K x N) -> out bf16 (N x K) ----------
__global__ __launch_bounds__(256) void transpose_k(const void* __restrict__ in,
                                                   u16* __restrict__ out, int K, int N,
                                                   long in_lstride, long out_lstride,
                                                   const int* __restrict__ fl) {
    __shared__ u16 tile[64][65];
    const int bf = fl[0];
    const size_t ioff = (size_t)blockIdx.z * (size_t)in_lstride;
    const size_t ooff = (size_t)blockIdx.z * (size_t)out_lstride;
    int k0 = blockIdx.y * 64, n0 = blockIdx.x * 64;
    int c = threadIdx.x & 63, r0 = threadIdx.x >> 6;
    #pragma unroll
    for (int r = r0; r < 64; r += 4) {
        size_t idx = ioff + (size_t)(k0 + r) * N + n0 + c;
        tile[r][c] = bf ? ((const u16*)in)[idx] : f2b(((const float*)in)[idx]);
    }
    __syncthreads();
    #pragma unroll
    for (int r = r0; r < 64; r += 4)
        out[ooff + (size_t)(n0 + r) * K + k0 + c] = tile[c][r];
}

// ---------- bias prep: convert all GEMM biases to bf16, qkv concatenated ----------
// layout: [0,13824) bqkv (6 x 2304) | [13824,18432) bo | [18432,36864) bf1 | [36864,41472) bf2
__global__ __launch_bounds__(256) void prep_bias(
    const void* __restrict__ bq, const void* __restrict__ bk, const void* __restrict__ bv,
    const void* __restrict__ bo, const void* __restrict__ bf1, const void* __restrict__ bf2,
    u16* __restrict__ out, const int* __restrict__ fl) {
    const int bf = fl[0];
    int i = blockIdx.x * 256 + threadIdx.x;
    if (i >= 41472) return;
    float v;
    if (i < 13824) {
        int l = i / 2304, c = i % 2304;
        v = (c < 768) ? lda(bq, (size_t)l * 768 + c, bf)
          : (c < 1536) ? lda(bk, (size_t)l * 768 + c - 768, bf)
                       : lda(bv, (size_t)l * 768 + c - 1536, bf);
    } else if (i < 18432) v = lda(bo,  i - 13824, bf);
    else if (i < 36864)   v = lda(bf1, i - 18432, bf);
    else                  v = lda(bf2, i - 36864, bf);
    out[i] = f2b(v);
}

// ---------- embedding + LN + selection scale ----------
__global__ __launch_bounds__(256) void embed_kernel(
    const int* __restrict__ src, const int* __restrict__ seg, const int* __restrict__ tib,
    const void* __restrict__ we, const void* __restrict__ pe, const void* __restrict__ se,
    const void* __restrict__ g, const void* __restrict__ bb, const void* __restrict__ sf,
    float* __restrict__ x32, u16* __restrict__ xb, const int* __restrict__ fl) {
    __shared__ float red[8];
    const int bf = fl[0];
    const int r = blockIdx.x, tid = threadIdx.x;
    const int s = r & (S_ - 1);
    const int w = src[r], sg = seg[r];
    const float scale = lda(sf, tib[r], bf);
    float v[3]; int col[3];
    #pragma unroll
    for (int i = 0; i < 3; ++i) {
        col[i] = tid + i * 256;
        v[i] = lda(we, (size_t)w * H_ + col[i], bf) + lda(pe, (size_t)s * H_ + col[i], bf)
             + lda(se, (size_t)sg * H_ + col[i], bf);
    }
    float su = v[0] + v[1] + v[2];
    float sq = v[0]*v[0] + v[1]*v[1] + v[2]*v[2];
    block_reduce2(su, sq, red, tid);
    const float mean = su * (1.0f / H_);
    const float var  = sq * (1.0f / H_) - mean * mean;
    const float inv  = rsqrtf(var + 1e-5f);
    #pragma unroll
    for (int i = 0; i < 3; ++i) {
        float y = ((v[i] - mean) * inv * lda(g, col[i], bf) + lda(bb, col[i], bf)) * scale;
        x32[(size_t)r * H_ + col[i]] = y;
        xb [(size_t)r * H_ + col[i]] = f2b(y);
    }
}

// ---------- residual add + LN (x32 master, bf16 shadow out) ----------
__global__ __launch_bounds__(256) void add_ln_kernel(
    const float* __restrict__ xin, const u16* __restrict__ t,
    const void* __restrict__ g, const void* __restrict__ bb, long goff,
    float* __restrict__ xout, u16* __restrict__ xb, const int* __restrict__ fl) {
    __shared__ float red[8];
    const int bf = fl[0];
    const int r = blockIdx.x, tid = threadIdx.x;
    const size_t rb = (size_t)r * H_;
    float v[3]; int col[3];
    #pragma unroll
    for (int i = 0; i < 3; ++i) {
        col[i] = tid + i * 256;
        v[i] = xin[rb + col[i]] + b2f(t[rb + col[i]]);
    }
    float su = v[0] + v[1] + v[2];
    float sq = v[0]*v[0] + v[1]*v[1] + v[2]*v[2];
    block_reduce2(su, sq, red, tid);
    const float mean = su * (1.0f / H_);
    const float var  = sq * (1.0f / H_) - mean * mean;
    const float inv  = rsqrtf(var + 1e-5f);
    #pragma unroll
    for (int i = 0; i < 3; ++i) {
        float y = (v[i] - mean) * inv * lda(g, goff + col[i], bf) + lda(bb, goff + col[i], bf);
        xout[rb + col[i]] = y;
        xb  [rb + col[i]] = f2b(y);
    }
}

// =====================================================================
// MFMA GEMM (m97-style, 128xBNT tile, 256 thr): BK=64, XOR chunk swizzle.
// BNT=128: QKV/FF1 (large-N grids). BNT=64: Wo/FF2 (N=768, 3 blocks/CU).
// K-accumulation order per output element unchanged -> bit-identical.
// =====================================================================
template<int BNT>
__global__ __launch_bounds__(256) void gemm_bt(
    const u16* __restrict__ A, const u16* __restrict__ Bt, const u16* __restrict__ bias,
    u16* __restrict__ C, int M, int N, int K, int act) {
    constexpr int NREP = BNT / 32;          // n-frags per wave: 4 or 2
    constexpr int BCH  = BNT / 32;          // B staging chunks per thread: 4 or 2
    __shared__ alignas(16) u16 As[128 * 64];
    __shared__ alignas(16) u16 Bs[BNT * 64];
    const int tid = threadIdx.x;
    const int bm = blockIdx.y * 128, bn = blockIdx.x * BNT;
    const int wave = tid >> 6, lane = tid & 63;
    const int wm = (wave >> 1) * 64, wn = (wave & 1) * (BNT / 2);
    const int qd = lane >> 4, l16 = lane & 15;
    const int l7 = l16 & 7;

    const f32x4 fz = {0.f, 0.f, 0.f, 0.f};
    f32x4 acc[4][NREP];
    #pragma unroll
    for (int i = 0; i < 4; ++i)
        #pragma unroll
        for (int j = 0; j < NREP; ++j) acc[i][j] = fz;

    // staging: tile rows x 64 cols; thread covers chunks tid+u*256.
    // LDS dest linear (chunk c at base+c*8); global source chunk = (c&7)^(row&7).
    const u16* Ag[4]; int dofsA[4];
    #pragma unroll
    for (int u = 0; u < 4; ++u) {
        const int c = tid + u * 256;
        const int r = c >> 3;
        const int cs = ((c & 7) ^ (r & 7)) * 8;
        Ag[u] = A + (size_t)(bm + r) * K + cs;
        dofsA[u] = c * 8;
    }
    const u16* Bg[BCH]; int dofsB[BCH];
    #pragma unroll
    for (int u = 0; u < BCH; ++u) {
        const int c = tid + u * 256;
        const int r = c >> 3;
        const int cs = ((c & 7) ^ (r & 7)) * 8;
        Bg[u] = Bt + (size_t)(bn + r) * K + cs;
        dofsB[u] = c * 8;
    }

    for (int k0 = 0; k0 < K; k0 += 64) {
        __syncthreads();               // prev iter's LDS reads complete
        #pragma unroll
        for (int u = 0; u < 4; ++u) async_lds16(Ag[u] + k0, As + dofsA[u]);
        #pragma unroll
        for (int u = 0; u < BCH; ++u) async_lds16(Bg[u] + k0, Bs + dofsB[u]);
        __syncthreads();               // vmcnt drained by barrier semantics
        bf16x8 af[4][2], bfv[NREP][2];
        #pragma unroll
        for (int i = 0; i < 4; ++i)
            #pragma unroll
            for (int kd = 0; kd < 2; ++kd) {
                const int sw = (((kd << 2) | qd) ^ l7) << 3;   // swizzled 16B chunk
                af[i][kd] = *(const bf16x8*)(As + (wm + i * 16 + l16) * 64 + sw);
            }
        #pragma unroll
        for (int j = 0; j < NREP; ++j)
            #pragma unroll
            for (int kd = 0; kd < 2; ++kd) {
                const int sw = (((kd << 2) | qd) ^ l7) << 3;
                bfv[j][kd] = *(const bf16x8*)(Bs + (wn + j * 16 + l16) * 64 + sw);
            }
        #pragma unroll
        for (int i = 0; i < 4; ++i)
            #pragma unroll
            for (int j = 0; j < NREP; ++j)
                #pragma unroll
                for (int kd = 0; kd < 2; ++kd)
                    acc[i][j] = __builtin_amdgcn_mfma_f32_16x16x32_bf16(af[i][kd], bfv[j][kd], acc[i][j], 0, 0, 0);
    }

    // epilogue: C/D layout col=lane&15, row=(lane>>4)*4+reg
    #pragma unroll
    for (int i = 0; i < 4; ++i) {
        const int row0 = bm + wm + i * 16 + qd * 4;
        #pragma unroll
        for (int j = 0; j < NREP; ++j) {
            const int col = bn + wn + j * 16 + l16;
            const float bv = b2f(bias[col]);
            #pragma unroll
            for (int r = 0; r < 4; ++r) {
                float v = acc[i][j][r] + bv;
                if (act == 1) v = gelu_tanh(v);
                C[(size_t)(row0 + r) * N + col] = f2b(v);
            }
        }
    }
}

// ---------- flash attention: 64 queries/block, online softmax, MFMA QK^T and PV ----------
__global__ __launch_bounds__(256) void attn_kernel(
    const u16* __restrict__ QKV, const int* __restrict__ seg, u16* __restrict__ Cb) {
    __shared__ alignas(16) u16 Qs[64 * 72];     // [q][d]
    __shared__ alignas(16) u16 Ks[128 * 72];    // [key][d]
    __shared__ alignas(16) u16 Vt[64 * 136];    // [d][key] with 16B-block xor swizzle
    __shared__ alignas(16) u16 Ps[64 * 136];    // [q][key]
    __shared__ float biasv[512];
    const int tid = threadIdx.x;
    const int qt = blockIdx.x, h = blockIdx.y, b = blockIdx.z;
    const int wave = tid >> 6, lane = tid & 63;
    const int qd = lane >> 4, l16 = lane & 15;
    const u16* Qg = QKV + (size_t)b * S_ * STRQ + h * 64;
    const u16* Kg = Qg + 768;
    const u16* Vg = Qg + 1536;

    for (int i = tid; i < 512; i += 256)
        biasv[i] = (seg[b * S_ + i] > 0) ? 0.0f : -1e9f;

    {   // stage Q tile 64x64 = 512 uint4 items
        int c = tid;
        #pragma unroll
        for (int u = 0; u < 2; ++u, c += 256) {
            int r = c >> 3, c8 = (c & 7) * 8;
            uint4 v4 = *(const uint4*)(Qg + (size_t)(qt * 64 + r) * STRQ + c8);
            *(uint4*)(Qs + r * 72 + c8) = v4;
        }
    }

    float m_run[4], l_run[4];
    f32x4 accO[4];
    #pragma unroll
    for (int r = 0; r < 4; ++r) { m_run[r] = -3.0e38f; l_run[r] = 0.f; }
    #pragma unroll
    for (int dt = 0; dt < 4; ++dt) accO[dt] = {0.f, 0.f, 0.f, 0.f};

    for (int kt = 0; kt < 512; kt += 128) {
        __syncthreads();                       // prev iter's Ks/Vt reads complete
        {   // stage K tile 128x64 = 1024 uint4 items
            int c = tid;
            #pragma unroll
            for (int u = 0; u < 4; ++u, c += 256) {
                int r = c >> 3, c8 = (c & 7) * 8;
                uint4 v4 = *(const uint4*)(Kg + (size_t)(kt + r) * STRQ + c8);
                *(uint4*)(Ks + r * 72 + c8) = v4;
            }
        }
        {   // stage V tile transposed: Vt[d][key], key-block xor-swizzled (1024 items)
            int c = tid;
            #pragma unroll
            for (int u = 0; u < 4; ++u, c += 256) {
                int r = c >> 3, d8 = (c & 7) * 8;
                uint4 v4 = *(const uint4*)(Vg + (size_t)(kt + r) * STRQ + d8);
                u16 tmp[8]; *(uint4*)tmp = v4;
                #pragma unroll
                for (int j = 0; j < 8; ++j) {
                    int d = d8 + j;
                    int blk = (r >> 3) ^ (d >> 3);
                    Vt[d * 136 + blk * 8 + (r & 7)] = tmp[j];
                }
            }
        }
        __syncthreads();

        // ---- QK^T: wave owns q rows wave*16..+15, all 128 keys ----
        f32x4 s[8];
        {
            bf16x8 aq[2];
            #pragma unroll
            for (int kd = 0; kd < 2; ++kd)
                aq[kd] = *(const bf16x8*)(Qs + (wave * 16 + l16) * 72 + kd * 32 + qd * 8);
            #pragma unroll
            for (int nt = 0; nt < 8; ++nt) {
                s[nt] = {0.f, 0.f, 0.f, 0.f};
                #pragma unroll
                for (int kd = 0; kd < 2; ++kd) {
                    bf16x8 bk = *(const bf16x8*)(Ks + (nt * 16 + l16) * 72 + kd * 32 + qd * 8);
                    s[nt] = __builtin_amdgcn_mfma_f32_16x16x32_bf16(aq[kd], bk, s[nt], 0, 0, 0);
                }
            }
        }
        // scale + mask bias (bias depends on key = col = nt*16+l16)
        #pragma unroll
        for (int nt = 0; nt < 8; ++nt) {
            const float bv = biasv[kt + nt * 16 + l16];
            #pragma unroll
            for (int r = 0; r < 4; ++r) s[nt][r] = s[nt][r] * 0.125f + bv;
        }
        // online softmax: rows live in (qd, r); reduce across 16 l16 lanes
        float alpha[4], rsum[4];
        #pragma unroll
        for (int r = 0; r < 4; ++r) {
            float m = s[0][r];
            #pragma unroll
            for (int nt = 1; nt < 8; ++nt) m = fmaxf(m, s[nt][r]);
            #pragma unroll
            for (int msk = 8; msk >= 1; msk >>= 1) m = fmaxf(m, __shfl_xor(m, msk));
            float mn = fmaxf(m_run[r], m);
            alpha[r] = __expf(m_run[r] - mn);
            m_run[r] = mn;
            rsum[r] = 0.f;
        }
        #pragma unroll
        for (int nt = 0; nt < 8; ++nt)
            #pragma unroll
            for (int r = 0; r < 4; ++r) {
                float p = __expf(s[nt][r] - m_run[r]);
                rsum[r] += p;
                Ps[(wave * 16 + qd * 4 + r) * 136 + nt * 16 + l16] = f2b(p);
            }
        #pragma unroll
        for (int r = 0; r < 4; ++r) {
            float t = rsum[r];
            #pragma unroll
            for (int msk = 8; msk >= 1; msk >>= 1) t += __shfl_xor(t, msk);
            l_run[r] = l_run[r] * alpha[r] + t;
        }
        #pragma unroll
        for (int dt = 0; dt < 4; ++dt)
            #pragma unroll
            for (int r = 0; r < 4; ++r) accO[dt][r] *= alpha[r];
        __syncthreads();                       // Ps visible (and Vt already staged)

        // ---- PV: O(16x64) += P(16x128) @ V(128x64) ----
        #pragma unroll
        for (int kk = 0; kk < 4; ++kk) {
            bf16x8 ap = *(const bf16x8*)(Ps + (wave * 16 + l16) * 136 + kk * 32 + qd * 8);
            #pragma unroll
            for (int dt = 0; dt < 4; ++dt) {
                const int d = dt * 16 + l16;
                const int blk = (kk * 4 + qd) ^ (d >> 3);
                bf16x8 bv = *(const bf16x8*)(Vt + d * 136 + blk * 8);
                accO[dt] = __builtin_amdgcn_mfma_f32_16x16x32_bf16(ap, bv, accO[dt], 0, 0, 0);
            }
        }
    }

    // epilogue: normalize and write ctx [row][h*64+d]
    #pragma unroll
    for (int r = 0; r < 4; ++r) {
        const int row = qt * 64 + wave * 16 + qd * 4 + r;
        const float inv = 1.0f / l_run[r];
        const size_t obase = ((size_t)b * S_ + row) * H_ + h * 64;
        #pragma unroll
        for (int dt = 0; dt < 4; ++dt)
            Cb[obase + dt * 16 + l16] = f2b(accO[dt][r] * inv);
    }
}

// ---------- head1: hid = tanh(pooled @ Wp1 + bp1) via MFMA, one wave per 16x16 tile ----------
__global__ __launch_bounds__(256) void head1_kernel(
    const u16* __restrict__ xb, const u16* __restrict__ Wp1T,
    const void* __restrict__ bp1, u16* __restrict__ hidb, const int* __restrict__ fl) {
    __shared__ alignas(16) u16 Xs[16 * 776];     // stride 776 breaks 16-way bank alias
    const int bf = fl[0];
    const int tid = threadIdx.x, wave = tid >> 6, lane = tid & 63;
    const int qd = lane >> 4, l16 = lane & 15;
    for (int i = tid; i < 16 * 96; i += 256) {   // 96 uint4 per pooled row
        int b = i / 96, c = (i % 96) * 8;
        *(uint4*)(Xs + b * 776 + c) = *(const uint4*)(xb + ((size_t)b * S_) * H_ + c);
    }
    __syncthreads();
    const int n0 = (blockIdx.x * 4 + wave) * 16;
    f32x4 acc = {0.f, 0.f, 0.f, 0.f};
    for (int k0 = 0; k0 < H_; k0 += 32) {
        bf16x8 a  = *(const bf16x8*)(Xs + l16 * 776 + k0 + qd * 8);
        bf16x8 bb = *(const bf16x8*)(Wp1T + (size_t)(n0 + l16) * H_ + k0 + qd * 8);
        acc = __builtin_amdgcn_mfma_f32_16x16x32_bf16(a, bb, acc, 0, 0, 0);
    }
    // C/D: col=l16 (j), row=qd*4+r (batch)
    #pragma unroll
    for (int r = 0; r < 4; ++r) {
        const int b = qd * 4 + r, j = n0 + l16;
        hidb[b * H_ + j] = f2b(tanhf(acc[r] + lda(bp1, j, bf)));
    }
}

// ---------- head2: logits, wave per (batch, label) ----------
__global__ __launch_bounds__(640) void head2_kernel(
    const u16* __restrict__ hidb, const void* __restrict__ Wp2, const void* __restrict__ bp2,
    float* __restrict__ lg, const int* __restrict__ fl) {
    const int bf = fl[0];
    const int b = blockIdx.x, j = threadIdx.x >> 6, lane = threadIdx.x & 63;
    float s = 0.f;
    for (int k = lane; k < H_; k += 64)
        s += b2f(hidb[b * H_ + k]) * lda(Wp2, (size_t)k * LAB_ + j, bf);
    #pragma unroll
    for (int m = 32; m >= 1; m >>= 1) s += __shfl_xor(s, m);
    if (lane == 0) lg[b * LAB_ + j] = s + lda(bp2, j, bf);
}

// ---------- head3: log-softmax loss + dual-format output ----------
__global__ __launch_bounds__(192) void head3_kernel(
    const float* __restrict__ lg, const int* __restrict__ tgt,
    void* __restrict__ outv, const int* __restrict__ fl) {
    __shared__ float lse[B_];
    const int bf = fl[0], t = threadIdx.x;
    if (t < B_) {
        float mx = -1e30f;
        for (int j = 0; j < LAB_; ++j) mx = fmaxf(mx, lg[t * LAB_ + j]);
        float s = 0.f;
        for (int j = 0; j < LAB_; ++j) s += expf(lg[t * LAB_ + j] - mx);
        lse[t] = mx + logf(s);
    }
    __syncthreads();
    float loss = 0.f;
    if (t == 0) {
        for (int b = 0; b < B_; ++b) loss += lse[b] - lg[b * LAB_ + tgt[b]];
        loss /= (float)B_;
    }
    if (bf) {
        u16* o = (u16*)outv;
        if (t == 0) o[0] = f2b(loss);
        if (t < B_ * LAB_) o[1 + t] = f2b(lg[t]);
    } else {
        float* o = (float*)outv;
        if (t == 0) o[0] = loss;
        if (t < B_ * LAB_) o[1 + t] = lg[t];
    }
}

// ---------- launch ----------
extern "C" void kernel_launch(void* const* d_in, const int* in_sizes, int n_in,
                              void* d_out, int out_size, void* d_ws, size_t ws_size,
                              hipStream_t stream) {
    (void)in_sizes; (void)n_in; (void)out_size; (void)ws_size;
    const int* src = (const int*)d_in[0];
    const int* seg = (const int*)d_in[1];
    const int* tgt = (const int*)d_in[2];
    const int* tib = (const int*)d_in[3];
    const void* we  = d_in[4];
    const void* pe  = d_in[5];
    const void* se  = d_in[6];
    const void* elg = d_in[7];
    const void* elb = d_in[8];
    const void* Wq  = d_in[9];
    const void* bq  = d_in[10];
    const void* Wk  = d_in[11];
    const void* bk  = d_in[12];
    const void* Wv  = d_in[13];
    const void* bv  = d_in[14];
    const void* Wo  = d_in[15];
    const void* bo  = d_in[16];
    const void* l1g = d_in[17];
    const void* l1b = d_in[18];
    const void* Wf1 = d_in[19];
    const void* bf1 = d_in[20];
    const void* Wf2 = d_in[21];
    const void* bf2 = d_in[22];
    const void* l2g = d_in[23];
    const void* l2b = d_in[24];
    const void* Wp1 = d_in[25];
    const void* bp1 = d_in[26];
    const void* Wp2 = d_in[27];
    const void* bp2 = d_in[28];
    const void* sf  = d_in[29];

    const size_t HH   = (size_t)H_ * H_;        // 589824
    const size_t HFF  = (size_t)H_ * FF_;       // 2359296
    const size_t MH   = (size_t)M_ * H_;        // 6291456
    const size_t MQKV = (size_t)M_ * STRQ;      // 18874368
    const size_t MFF  = (size_t)M_ * FF_;       // 25165824
    const size_t QKVW = (size_t)STRQ * H_;      // 1769472 (per-layer merged weight)

    char* w = (char*)d_ws;
    int* dflag  = (int*)w;  w += 256;
    u16* bias_ws = (u16*)w; w += 41472 * 2;     // prep_bias layout
    u16* WqkvT = (u16*)w;  w += L_ * QKVW * 2;
    u16* WoT   = (u16*)w;  w += L_ * HH  * 2;
    u16* Wf1T  = (u16*)w;  w += L_ * HFF * 2;
    u16* Wf2T  = (u16*)w;  w += L_ * HFF * 2;
    u16* Wp1T  = (u16*)w;  w += HH * 2;
    float* x32 = (float*)w; w += MH * 4;
    u16* xb    = (u16*)w;  w += MH * 2;
    u16* qkvb  = (u16*)w;  w += MQKV * 2;
    u16* ctxb  = (u16*)w;  w += MH * 2;
    u16* tmpb  = (u16*)w;  w += MH * 2;
    u16* ffb   = (u16*)w;  w += MFF * 2;
    u16* hidb  = (u16*)w;  w += (size_t)B_ * H_ * 2;
    float* lg  = (float*)w; w += (size_t)B_ * LAB_ * 4;

    u16* bqkv = bias_ws;            // 6 x 2304
    u16* bo6  = bias_ws + 13824;    // 6 x 768
    u16* bf16_= bias_ws + 18432;    // 6 x 3072
    u16* bf26 = bias_ws + 36864;    // 6 x 768

    const dim3 tb(256);
    detect_kernel<<<1, 1, 0, stream>>>((const u32*)elg, dflag);
    prep_bias<<<162, tb, 0, stream>>>(bq, bk, bv, bo, bf1, bf2, bias_ws, dflag);

    // weight transposes+convert; Wq/Wk/Wv interleave into per-layer 2304x768 blocks
    transpose_k<<<dim3(12, 12, 6), tb, 0, stream>>>(Wq, WqkvT,                    H_, H_, (long)HH, (long)QKVW, dflag);
    transpose_k<<<dim3(12, 12, 6), tb, 0, stream>>>(Wk, WqkvT + (size_t)768*768,  H_, H_, (long)HH, (long)QKVW, dflag);
    transpose_k<<<dim3(12, 12, 6), tb, 0, stream>>>(Wv, WqkvT + (size_t)1536*768, H_, H_, (long)HH, (long)QKVW, dflag);
    transpose_k<<<dim3(12, 12, 6), tb, 0, stream>>>(Wo,  WoT,  H_, H_,  (long)HH,  (long)HH,  dflag);
    transpose_k<<<dim3(48, 12, 6), tb, 0, stream>>>(Wf1, Wf1T, H_, FF_, (long)HFF, (long)HFF, dflag);
    transpose_k<<<dim3(12, 48, 6), tb, 0, stream>>>(Wf2, Wf2T, FF_, H_, (long)HFF, (long)HFF, dflag);
    transpose_k<<<dim3(12, 12, 1), tb, 0, stream>>>(Wp1, Wp1T, H_, H_,  (long)HH,  (long)HH,  dflag);

    embed_kernel<<<M_, tb, 0, stream>>>(src, seg, tib, we, pe, se, elg, elb, sf, x32, xb, dflag);

    for (int l = 0; l < L_; ++l) {
        // QKV: M x 2304 x 768 (BN=128, 18x64=1152 blocks)
        gemm_bt<128><<<dim3(STRQ / 128, M_ / 128), tb, 0, stream>>>(xb, WqkvT + l * QKVW, bqkv + l * STRQ, qkvb, M_, STRQ, H_, 0);
        attn_kernel<<<dim3(S_ / 64, NH_, B_), tb, 0, stream>>>(qkvb, seg, ctxb);
        // Wo: M x 768 x 768 (BN=64, 12x64=768 blocks -> 3 blocks/CU)
        gemm_bt<64><<<dim3(H_ / 64, M_ / 128), tb, 0, stream>>>(ctxb, WoT + l * HH, bo6 + l * H_, tmpb, M_, H_, H_, 0);
        add_ln_kernel<<<M_, tb, 0, stream>>>(x32, tmpb, l1g, l1b, (long)l * H_, x32, xb, dflag);
        // FF1: M x 3072 x 768 + gelu (BN=128, 24x64=1536 blocks)
        gemm_bt<128><<<dim3(FF_ / 128, M_ / 128), tb, 0, stream>>>(xb, Wf1T + l * HFF, bf16_ + l * FF_, ffb, M_, FF_, H_, 1);
        // FF2: M x 768 x 3072 (BN=64, 768 blocks)
        gemm_bt<64><<<dim3(H_ / 64, M_ / 128), tb, 0, stream>>>(ffb, Wf2T + l * HFF, bf26 + l * H_, tmpb, M_, H_, FF_, 0);
        add_ln_kernel<<<M_, tb, 0, stream>>>(x32, tmpb, l2g, l2b, (long)l * H_, x32, xb, dflag);
    }

    head1_kernel<<<12, tb, 0, stream>>>(xb, Wp1T, bp1, hidb, dflag);
    head2_kernel<<<B_, dim3(640), 0, stream>>>(hidb, Wp2, bp2, lg, dflag);
    head3_kernel<<<1, dim3(192), 0, stream>>>(lg, tgt, d_out, dflag);
}

// Round 6
// 1913.551 us; speedup vs baseline: 1.4284x; 1.0266x over previous
//
#include <hip/hip_runtime.h>

typedef unsigned short u16;
typedef unsigned int   u32;
typedef __bf16  bf16x8 __attribute__((ext_vector_type(8)));
typedef float   f32x4  __attribute__((ext_vector_type(4)));

#define B_   16
#define S_   512
#define H_   768
#define NH_  12
#define L_   6
#define FF_  3072
#define M_   8192     // B_*S_
#define LAB_ 10
#define STRQ 2304     // merged qkv row stride

// ---------- bf16 helpers (storage = u16 bits) ----------
__device__ __forceinline__ float b2f(u16 x) {
    u32 u = ((u32)x) << 16; float f; __builtin_memcpy(&f, &u, 4); return f;
}
__device__ __forceinline__ u16 f2b(float f) {
    u32 u; __builtin_memcpy(&u, &f, 4);
    u32 r = u + 0x7FFFu + ((u >> 16) & 1u);
    return (u16)(r >> 16);
}
__device__ __forceinline__ float lda(const void* p, size_t i, int bf) {
    return bf ? b2f(((const u16*)p)[i]) : ((const float*)p)[i];
}
// gelu tanh-approx reformed as sigmoid: 0.5x(1+tanh(z)) = x/(1+exp(-2z)),
// 2z = 1.5957691216.. * x * (1 + 0.044715 x^2). v_exp + v_rcp (~9 VALU inst)
// vs libm tanhf (~30-50): round-4 counters showed FF1 at 66% VALUBusy from
// the tanhf epilogue. Saturation safe: exp->inf -> rcp->0 -> gelu=0.
__device__ __forceinline__ float gelu_tanh(float x) {
    float e = __expf(-1.5957691216057308f * x * fmaf(0.044715f, x * x, 1.0f));
    return x * __builtin_amdgcn_rcpf(1.0f + e);
}
// async global->LDS, 16B per lane; LDS dest must be wave-uniform base + lane*16
__device__ __forceinline__ void async_lds16(const u16* g, u16* l) {
    __builtin_amdgcn_global_load_lds(
        (const __attribute__((address_space(1))) u32*)(const void*)g,
        (__attribute__((address_space(3))) u32*)(void*)l, 16, 0, 0);
}

// ---------- dtype detect: emb_ln_g is all ones ----------
__global__ void detect_kernel(const u32* __restrict__ g, int* __restrict__ flag) {
    flag[0] = (g[0] == 0x3F803F80u) ? 1 : 0;   // bf16 ones pair vs fp32 one
}

// ---------- block reduce (sum of two values), 256 threads ----------
__device__ __forceinline__ void block_reduce2(float& s, float& s2, float* red, int tid) {
    int lane = tid & 63, wave = tid >> 6;
    #pragma unroll
    for (int m = 32; m >= 1; m >>= 1) { s += __shfl_xor(s, m); s2 += __shfl_xor(s2, m); }
    if (lane == 0) { red[wave] = s; red[4 + wave] = s2; }
    __syncthreads();
    s  = red[0] + red[1] + red[2] + red[3];
    s2 = red[4] + red[5] + red[6] + red[7];
}

// ---------- weight transpose+convert: in (K x N) -> out bf16 (N x K) ----------
__global__ __launch_bounds__(256) void transpose_k(const void* __restrict__ in,
                                                   u16* __restrict__ out, int K, int N,
                                                   long in_lstride, long out_lstride,
                                                   const int* __restrict__ fl) {
    __shared__ u16 tile[64][65];
    const int bf = fl[0];
    const size_t ioff = (size_t)blockIdx.z * (size_t)in_lstride;
    const size_t ooff = (size_t)blockIdx.z * (size_t)out_lstride;
    int k0 = blockIdx.y * 64, n0 = blockIdx.x * 64;
    int c = threadIdx.x & 63, r0 = threadIdx.x >> 6;
    #pragma unroll
    for (int r = r0; r < 64; r += 4) {
        size_t idx = ioff + (size_t)(k0 + r) * N + n0 + c;
        tile[r][c] = bf ? ((const u16*)in)[idx] : f2b(((const float*)in)[idx]);
    }
    __syncthreads();
    #pragma unroll
    for (int r = r0; r < 64; r += 4)
        out[ooff + (size_t)(n0 + r) * K + k0 + c] = tile[c][r];
}

// ---------- bias prep: convert all GEMM biases to bf16, qkv concatenated ----------
// layout: [0,13824) bqkv (6 x 2304) | [13824,18432) bo | [18432,36864) bf1 | [36864,41472) bf2
__global__ __launch_bounds__(256) void prep_bias(
    const void* __restrict__ bq, const void* __restrict__ bk, const void* __restrict__ bv,
    const void* __restrict__ bo, const void* __restrict__ bf1, const void* __restrict__ bf2,
    u16* __restrict__ out, const int* __restrict__ fl) {
    const int bf = fl[0];
    int i = blockIdx.x * 256 + threadIdx.x;
    if (i >= 41472) return;
    float v;
    if (i < 13824) {
        int l = i / 2304, c = i % 2304;
        v = (c < 768) ? lda(bq, (size_t)l * 768 + c, bf)
          : (c < 1536) ? lda(bk, (size_t)l * 768 + c - 768, bf)
                       : lda(bv, (size_t)l * 768 + c - 1536, bf);
    } else if (i < 18432) v = lda(bo,  i - 13824, bf);
    else if (i < 36864)   v = lda(bf1, i - 18432, bf);
    else                  v = lda(bf2, i - 36864, bf);
    out[i] = f2b(v);
}

// ---------- embedding + LN + selection scale ----------
__global__ __launch_bounds__(256) void embed_kernel(
    const int* __restrict__ src, const int* __restrict__ seg, const int* __restrict__ tib,
    const void* __restrict__ we, const void* __restrict__ pe, const void* __restrict__ se,
    const void* __restrict__ g, const void* __restrict__ bb, const void* __restrict__ sf,
    float* __restrict__ x32, u16* __restrict__ xb, const int* __restrict__ fl) {
    __shared__ float red[8];
    const int bf = fl[0];
    const int r = blockIdx.x, tid = threadIdx.x;
    const int s = r & (S_ - 1);
    const int w = src[r], sg = seg[r];
    const float scale = lda(sf, tib[r], bf);
    float v[3]; int col[3];
    #pragma unroll
    for (int i = 0; i < 3; ++i) {
        col[i] = tid + i * 256;
        v[i] = lda(we, (size_t)w * H_ + col[i], bf) + lda(pe, (size_t)s * H_ + col[i], bf)
             + lda(se, (size_t)sg * H_ + col[i], bf);
    }
    float su = v[0] + v[1] + v[2];
    float sq = v[0]*v[0] + v[1]*v[1] + v[2]*v[2];
    block_reduce2(su, sq, red, tid);
    const float mean = su * (1.0f / H_);
    const float var  = sq * (1.0f / H_) - mean * mean;
    const float inv  = rsqrtf(var + 1e-5f);
    #pragma unroll
    for (int i = 0; i < 3; ++i) {
        float y = ((v[i] - mean) * inv * lda(g, col[i], bf) + lda(bb, col[i], bf)) * scale;
        x32[(size_t)r * H_ + col[i]] = y;
        xb [(size_t)r * H_ + col[i]] = f2b(y);
    }
}

// ---------- residual add + LN (x32 master, bf16 shadow out) ----------
__global__ __launch_bounds__(256) void add_ln_kernel(
    const float* __restrict__ xin, const u16* __restrict__ t,
    const void* __restrict__ g, const void* __restrict__ bb, long goff,
    float* __restrict__ xout, u16* __restrict__ xb, const int* __restrict__ fl) {
    __shared__ float red[8];
    const int bf = fl[0];
    const int r = blockIdx.x, tid = threadIdx.x;
    const size_t rb = (size_t)r * H_;
    float v[3]; int col[3];
    #pragma unroll
    for (int i = 0; i < 3; ++i) {
        col[i] = tid + i * 256;
        v[i] = xin[rb + col[i]] + b2f(t[rb + col[i]]);
    }
    float su = v[0] + v[1] + v[2];
    float sq = v[0]*v[0] + v[1]*v[1] + v[2]*v[2];
    block_reduce2(su, sq, red, tid);
    const float mean = su * (1.0f / H_);
    const float var  = sq * (1.0f / H_) - mean * mean;
    const float inv  = rsqrtf(var + 1e-5f);
    #pragma unroll
    for (int i = 0; i < 3; ++i) {
        float y = (v[i] - mean) * inv * lda(g, goff + col[i], bf) + lda(bb, goff + col[i], bf);
        xout[rb + col[i]] = y;
        xb  [rb + col[i]] = f2b(y);
    }
}

// =====================================================================
// MFMA GEMM (m97-style, 128xBNT tile, 256 thr): BK=64, XOR chunk swizzle.
// BNT=128: QKV/FF1 (large-N grids). BNT=64: Wo/FF2 (N=768, 3 blocks/CU).
// Round-6: XCD-aware chunked block swizzle (T1). Round-5 counters: FF2
// FETCH 201MB vs ~55MB ideal (4x over-fetch) -- the 12 blocks sharing an
// A-row-strip were round-robined across the 8 XCD L2s. Chunked bijective
// remap (all grids %8==0) makes same-XCD blocks adjacent in tile space:
// each A strip is fetched by one XCD only. Pure block reorder ->
// bit-identical output.
// =====================================================================
template<int BNT>
__global__ __launch_bounds__(256) void gemm_bt(
    const u16* __restrict__ A, const u16* __restrict__ Bt, const u16* __restrict__ bias,
    u16* __restrict__ C, int M, int N, int K, int act) {
    constexpr int NREP = BNT / 32;          // n-frags per wave: 4 or 2
    constexpr int BCH  = BNT / 32;          // B staging chunks per thread: 4 or 2
    __shared__ alignas(16) u16 As[128 * 64];
    __shared__ alignas(16) u16 Bs[BNT * 64];
    const int tid = threadIdx.x;
    // XCD-aware chunked bijective swizzle: ids congruent mod 8 (same XCD)
    // become adjacent tiles; nwg % 8 == 0 for all our grids.
    const int nbx = (int)gridDim.x;
    const int nwg = nbx * (int)gridDim.y;
    const int lin = (int)blockIdx.y * nbx + (int)blockIdx.x;
    const int wg  = (lin & 7) * (nwg >> 3) + (lin >> 3);
    const int bm = (wg / nbx) * 128, bn = (wg % nbx) * BNT;
    const int wave = tid >> 6, lane = tid & 63;
    const int wm = (wave >> 1) * 64, wn = (wave & 1) * (BNT / 2);
    const int qd = lane >> 4, l16 = lane & 15;
    const int l7 = l16 & 7;

    const f32x4 fz = {0.f, 0.f, 0.f, 0.f};
    f32x4 acc[4][NREP];
    #pragma unroll
    for (int i = 0; i < 4; ++i)
        #pragma unroll
        for (int j = 0; j < NREP; ++j) acc[i][j] = fz;

    // staging: tile rows x 64 cols; thread covers chunks tid+u*256.
    // LDS dest linear (chunk c at base+c*8); global source chunk = (c&7)^(row&7).
    const u16* Ag[4]; int dofsA[4];
    #pragma unroll
    for (int u = 0; u < 4; ++u) {
        const int c = tid + u * 256;
        const int r = c >> 3;
        const int cs = ((c & 7) ^ (r & 7)) * 8;
        Ag[u] = A + (size_t)(bm + r) * K + cs;
        dofsA[u] = c * 8;
    }
    const u16* Bg[BCH]; int dofsB[BCH];
    #pragma unroll
    for (int u = 0; u < BCH; ++u) {
        const int c = tid + u * 256;
        const int r = c >> 3;
        const int cs = ((c & 7) ^ (r & 7)) * 8;
        Bg[u] = Bt + (size_t)(bn + r) * K + cs;
        dofsB[u] = c * 8;
    }

    for (int k0 = 0; k0 < K; k0 += 64) {
        __syncthreads();               // prev iter's LDS reads complete
        #pragma unroll
        for (int u = 0; u < 4; ++u) async_lds16(Ag[u] + k0, As + dofsA[u]);
        #pragma unroll
        for (int u = 0; u < BCH; ++u) async_lds16(Bg[u] + k0, Bs + dofsB[u]);
        __syncthreads();               // vmcnt drained by barrier semantics
        bf16x8 af[4][2], bfv[NREP][2];
        #pragma unroll
        for (int i = 0; i < 4; ++i)
            #pragma unroll
            for (int kd = 0; kd < 2; ++kd) {
                const int sw = (((kd << 2) | qd) ^ l7) << 3;   // swizzled 16B chunk
                af[i][kd] = *(const bf16x8*)(As + (wm + i * 16 + l16) * 64 + sw);
            }
        #pragma unroll
        for (int j = 0; j < NREP; ++j)
            #pragma unroll
            for (int kd = 0; kd < 2; ++kd) {
                const int sw = (((kd << 2) | qd) ^ l7) << 3;
                bfv[j][kd] = *(const bf16x8*)(Bs + (wn + j * 16 + l16) * 64 + sw);
            }
        #pragma unroll
        for (int i = 0; i < 4; ++i)
            #pragma unroll
            for (int j = 0; j < NREP; ++j)
                #pragma unroll
                for (int kd = 0; kd < 2; ++kd)
                    acc[i][j] = __builtin_amdgcn_mfma_f32_16x16x32_bf16(af[i][kd], bfv[j][kd], acc[i][j], 0, 0, 0);
    }

    // epilogue: C/D layout col=lane&15, row=(lane>>4)*4+reg
    #pragma unroll
    for (int i = 0; i < 4; ++i) {
        const int row0 = bm + wm + i * 16 + qd * 4;
        #pragma unroll
        for (int j = 0; j < NREP; ++j) {
            const int col = bn + wn + j * 16 + l16;
            const float bv = b2f(bias[col]);
            #pragma unroll
            for (int r = 0; r < 4; ++r) {
                float v = acc[i][j][r] + bv;
                if (act == 1) v = gelu_tanh(v);
                C[(size_t)(row0 + r) * N + col] = f2b(v);
            }
        }
    }
}

// ---------- flash attention: 64 queries/block, online softmax, MFMA QK^T and PV ----------
__global__ __launch_bounds__(256) void attn_kernel(
    const u16* __restrict__ QKV, const int* __restrict__ seg, u16* __restrict__ Cb) {
    __shared__ alignas(16) u16 Qs[64 * 72];     // [q][d]
    __shared__ alignas(16) u16 Ks[128 * 72];    // [key][d]
    __shared__ alignas(16) u16 Vt[64 * 136];    // [d][key] with 16B-block xor swizzle
    __shared__ alignas(16) u16 Ps[64 * 136];    // [q][key]
    __shared__ float biasv[512];
    const int tid = threadIdx.x;
    const int qt = blockIdx.x, h = blockIdx.y, b = blockIdx.z;
    const int wave = tid >> 6, lane = tid & 63;
    const int qd = lane >> 4, l16 = lane & 15;
    const u16* Qg = QKV + (size_t)b * S_ * STRQ + h * 64;
    const u16* Kg = Qg + 768;
    const u16* Vg = Qg + 1536;

    for (int i = tid; i < 512; i += 256)
        biasv[i] = (seg[b * S_ + i] > 0) ? 0.0f : -1e9f;

    {   // stage Q tile 64x64 = 512 uint4 items
        int c = tid;
        #pragma unroll
        for (int u = 0; u < 2; ++u, c += 256) {
            int r = c >> 3, c8 = (c & 7) * 8;
            uint4 v4 = *(const uint4*)(Qg + (size_t)(qt * 64 + r) * STRQ + c8);
            *(uint4*)(Qs + r * 72 + c8) = v4;
        }
    }

    float m_run[4], l_run[4];
    f32x4 accO[4];
    #pragma unroll
    for (int r = 0; r < 4; ++r) { m_run[r] = -3.0e38f; l_run[r] = 0.f; }
    #pragma unroll
    for (int dt = 0; dt < 4; ++dt) accO[dt] = {0.f, 0.f, 0.f, 0.f};

    for (int kt = 0; kt < 512; kt += 128) {
        __syncthreads();                       // prev iter's Ks/Vt reads complete
        {   // stage K tile 128x64 = 1024 uint4 items
            int c = tid;
            #pragma unroll
            for (int u = 0; u < 4; ++u, c += 256) {
                int r = c >> 3, c8 = (c & 7) * 8;
                uint4 v4 = *(const uint4*)(Kg + (size_t)(kt + r) * STRQ + c8);
                *(uint4*)(Ks + r * 72 + c8) = v4;
            }
        }
        {   // stage V tile transposed: Vt[d][key], key-block xor-swizzled (1024 items)
            int c = tid;
            #pragma unroll
            for (int u = 0; u < 4; ++u, c += 256) {
                int r = c >> 3, d8 = (c & 7) * 8;
                uint4 v4 = *(const uint4*)(Vg + (size_t)(kt + r) * STRQ + d8);
                u16 tmp[8]; *(uint4*)tmp = v4;
                #pragma unroll
                for (int j = 0; j < 8; ++j) {
                    int d = d8 + j;
                    int blk = (r >> 3) ^ (d >> 3);
                    Vt[d * 136 + blk * 8 + (r & 7)] = tmp[j];
                }
            }
        }
        __syncthreads();

        // ---- QK^T: wave owns q rows wave*16..+15, all 128 keys ----
        f32x4 s[8];
        {
            bf16x8 aq[2];
            #pragma unroll
            for (int kd = 0; kd < 2; ++kd)
                aq[kd] = *(const bf16x8*)(Qs + (wave * 16 + l16) * 72 + kd * 32 + qd * 8);
            #pragma unroll
            for (int nt = 0; nt < 8; ++nt) {
                s[nt] = {0.f, 0.f, 0.f, 0.f};
                #pragma unroll
                for (int kd = 0; kd < 2; ++kd) {
                    bf16x8 bk = *(const bf16x8*)(Ks + (nt * 16 + l16) * 72 + kd * 32 + qd * 8);
                    s[nt] = __builtin_amdgcn_mfma_f32_16x16x32_bf16(aq[kd], bk, s[nt], 0, 0, 0);
                }
            }
        }
        // scale + mask bias (bias depends on key = col = nt*16+l16)
        #pragma unroll
        for (int nt = 0; nt < 8; ++nt) {
            const float bv = biasv[kt + nt * 16 + l16];
            #pragma unroll
            for (int r = 0; r < 4; ++r) s[nt][r] = s[nt][r] * 0.125f + bv;
        }
        // online softmax: rows live in (qd, r); reduce across 16 l16 lanes
        float alpha[4], rsum[4];
        #pragma unroll
        for (int r = 0; r < 4; ++r) {
            float m = s[0][r];
            #pragma unroll
            for (int nt = 1; nt < 8; ++nt) m = fmaxf(m, s[nt][r]);
            #pragma unroll
            for (int msk = 8; msk >= 1; msk >>= 1) m = fmaxf(m, __shfl_xor(m, msk));
            float mn = fmaxf(m_run[r], m);
            alpha[r] = __expf(m_run[r] - mn);
            m_run[r] = mn;
            rsum[r] = 0.f;
        }
        #pragma unroll
        for (int nt = 0; nt < 8; ++nt)
            #pragma unroll
            for (int r = 0; r < 4; ++r) {
                float p = __expf(s[nt][r] - m_run[r]);
                rsum[r] += p;
                Ps[(wave * 16 + qd * 4 + r) * 136 + nt * 16 + l16] = f2b(p);
            }
        #pragma unroll
        for (int r = 0; r < 4; ++r) {
            float t = rsum[r];
            #pragma unroll
            for (int msk = 8; msk >= 1; msk >>= 1) t += __shfl_xor(t, msk);
            l_run[r] = l_run[r] * alpha[r] + t;
        }
        #pragma unroll
        for (int dt = 0; dt < 4; ++dt)
            #pragma unroll
            for (int r = 0; r < 4; ++r) accO[dt][r] *= alpha[r];
        __syncthreads();                       // Ps visible (and Vt already staged)

        // ---- PV: O(16x64) += P(16x128) @ V(128x64) ----
        #pragma unroll
        for (int kk = 0; kk < 4; ++kk) {
            bf16x8 ap = *(const bf16x8*)(Ps + (wave * 16 + l16) * 136 + kk * 32 + qd * 8);
            #pragma unroll
            for (int dt = 0; dt < 4; ++dt) {
                const int d = dt * 16 + l16;
                const int blk = (kk * 4 + qd) ^ (d >> 3);
                bf16x8 bv = *(const bf16x8*)(Vt + d * 136 + blk * 8);
                accO[dt] = __builtin_amdgcn_mfma_f32_16x16x32_bf16(ap, bv, accO[dt], 0, 0, 0);
            }
        }
    }

    // epilogue: normalize and write ctx [row][h*64+d]
    #pragma unroll
    for (int r = 0; r < 4; ++r) {
        const int row = qt * 64 + wave * 16 + qd * 4 + r;
        const float inv = 1.0f / l_run[r];
        const size_t obase = ((size_t)b * S_ + row) * H_ + h * 64;
        #pragma unroll
        for (int dt = 0; dt < 4; ++dt)
            Cb[obase + dt * 16 + l16] = f2b(accO[dt][r] * inv);
    }
}

// ---------- head1: hid = tanh(pooled @ Wp1 + bp1) via MFMA, one wave per 16x16 tile ----------
__global__ __launch_bounds__(256) void head1_kernel(
    const u16* __restrict__ xb, const u16* __restrict__ Wp1T,
    const void* __restrict__ bp1, u16* __restrict__ hidb, const int* __restrict__ fl) {
    __shared__ alignas(16) u16 Xs[16 * 776];     // stride 776 breaks 16-way bank alias
    const int bf = fl[0];
    const int tid = threadIdx.x, wave = tid >> 6, lane = tid & 63;
    const int qd = lane >> 4, l16 = lane & 15;
    for (int i = tid; i < 16 * 96; i += 256) {   // 96 uint4 per pooled row
        int b = i / 96, c = (i % 96) * 8;
        *(uint4*)(Xs + b * 776 + c) = *(const uint4*)(xb + ((size_t)b * S_) * H_ + c);
    }
    __syncthreads();
    const int n0 = (blockIdx.x * 4 + wave) * 16;
    f32x4 acc = {0.f, 0.f, 0.f, 0.f};
    for (int k0 = 0; k0 < H_; k0 += 32) {
        bf16x8 a  = *(const bf16x8*)(Xs + l16 * 776 + k0 + qd * 8);
        bf16x8 bb = *(const bf16x8*)(Wp1T + (size_t)(n0 + l16) * H_ + k0 + qd * 8);
        acc = __builtin_amdgcn_mfma_f32_16x16x32_bf16(a, bb, acc, 0, 0, 0);
    }
    // C/D: col=l16 (j), row=qd*4+r (batch)
    #pragma unroll
    for (int r = 0; r < 4; ++r) {
        const int b = qd * 4 + r, j = n0 + l16;
        hidb[b * H_ + j] = f2b(tanhf(acc[r] + lda(bp1, j, bf)));
    }
}

// ---------- head2: logits, wave per (batch, label) ----------
__global__ __launch_bounds__(640) void head2_kernel(
    const u16* __restrict__ hidb, const void* __restrict__ Wp2, const void* __restrict__ bp2,
    float* __restrict__ lg, const int* __restrict__ fl) {
    const int bf = fl[0];
    const int b = blockIdx.x, j = threadIdx.x >> 6, lane = threadIdx.x & 63;
    float s = 0.f;
    for (int k = lane; k < H_; k += 64)
        s += b2f(hidb[b * H_ + k]) * lda(Wp2, (size_t)k * LAB_ + j, bf);
    #pragma unroll
    for (int m = 32; m >= 1; m >>= 1) s += __shfl_xor(s, m);
    if (lane == 0) lg[b * LAB_ + j] = s + lda(bp2, j, bf);
}

// ---------- head3: log-softmax loss + dual-format output ----------
__global__ __launch_bounds__(192) void head3_kernel(
    const float* __restrict__ lg, const int* __restrict__ tgt,
    void* __restrict__ outv, const int* __restrict__ fl) {
    __shared__ float lse[B_];
    const int bf = fl[0], t = threadIdx.x;
    if (t < B_) {
        float mx = -1e30f;
        for (int j = 0; j < LAB_; ++j) mx = fmaxf(mx, lg[t * LAB_ + j]);
        float s = 0.f;
        for (int j = 0; j < LAB_; ++j) s += expf(lg[t * LAB_ + j] - mx);
        lse[t] = mx + logf(s);
    }
    __syncthreads();
    float loss = 0.f;
    if (t == 0) {
        for (int b = 0; b < B_; ++b) loss += lse[b] - lg[b * LAB_ + tgt[b]];
        loss /= (float)B_;
    }
    if (bf) {
        u16* o = (u16*)outv;
        if (t == 0) o[0] = f2b(loss);
        if (t < B_ * LAB_) o[1 + t] = f2b(lg[t]);
    } else {
        float* o = (float*)outv;
        if (t == 0) o[0] = loss;
        if (t < B_ * LAB_) o[1 + t] = lg[t];
    }
}

// ---------- launch ----------
extern "C" void kernel_launch(void* const* d_in, const int* in_sizes, int n_in,
                              void* d_out, int out_size, void* d_ws, size_t ws_size,
                              hipStream_t stream) {
    (void)in_sizes; (void)n_in; (void)out_size; (void)ws_size;
    const int* src = (const int*)d_in[0];
    const int* seg = (const int*)d_in[1];
    const int* tgt = (const int*)d_in[2];
    const int* tib = (const int*)d_in[3];
    const void* we  = d_in[4];
    const void* pe  = d_in[5];
    const void* se  = d_in[6];
    const void* elg = d_in[7];
    const void* elb = d_in[8];
    const void* Wq  = d_in[9];
    const void* bq  = d_in[10];
    const void* Wk  = d_in[11];
    const void* bk  = d_in[12];
    const void* Wv  = d_in[13];
    const void* bv  = d_in[14];
    const void* Wo  = d_in[15];
    const void* bo  = d_in[16];
    const void* l1g = d_in[17];
    const void* l1b = d_in[18];
    const void* Wf1 = d_in[19];
    const void* bf1 = d_in[20];
    const void* Wf2 = d_in[21];
    const void* bf2 = d_in[22];
    const void* l2g = d_in[23];
    const void* l2b = d_in[24];
    const void* Wp1 = d_in[25];
    const void* bp1 = d_in[26];
    const void* Wp2 = d_in[27];
    const void* bp2 = d_in[28];
    const void* sf  = d_in[29];

    const size_t HH   = (size_t)H_ * H_;        // 589824
    const size_t HFF  = (size_t)H_ * FF_;       // 2359296
    const size_t MH   = (size_t)M_ * H_;        // 6291456
    const size_t MQKV = (size_t)M_ * STRQ;      // 18874368
    const size_t MFF  = (size_t)M_ * FF_;       // 25165824
    const size_t QKVW = (size_t)STRQ * H_;      // 1769472 (per-layer merged weight)

    char* w = (char*)d_ws;
    int* dflag  = (int*)w;  w += 256;
    u16* bias_ws = (u16*)w; w += 41472 * 2;     // prep_bias layout
    u16* WqkvT = (u16*)w;  w += L_ * QKVW * 2;
    u16* WoT   = (u16*)w;  w += L_ * HH  * 2;
    u16* Wf1T  = (u16*)w;  w += L_ * HFF * 2;
    u16* Wf2T  = (u16*)w;  w += L_ * HFF * 2;
    u16* Wp1T  = (u16*)w;  w += HH * 2;
    float* x32 = (float*)w; w += MH * 4;
    u16* xb    = (u16*)w;  w += MH * 2;
    u16* qkvb  = (u16*)w;  w += MQKV * 2;
    u16* ctxb  = (u16*)w;  w += MH * 2;
    u16* tmpb  = (u16*)w;  w += MH * 2;
    u16* ffb   = (u16*)w;  w += MFF * 2;
    u16* hidb  = (u16*)w;  w += (size_t)B_ * H_ * 2;
    float* lg  = (float*)w; w += (size_t)B_ * LAB_ * 4;

    u16* bqkv = bias_ws;            // 6 x 2304
    u16* bo6  = bias_ws + 13824;    // 6 x 768
    u16* bf16_= bias_ws + 18432;    // 6 x 3072
    u16* bf26 = bias_ws + 36864;    // 6 x 768

    const dim3 tb(256);
    detect_kernel<<<1, 1, 0, stream>>>((const u32*)elg, dflag);
    prep_bias<<<162, tb, 0, stream>>>(bq, bk, bv, bo, bf1, bf2, bias_ws, dflag);

    // weight transposes+convert; Wq/Wk/Wv interleave into per-layer 2304x768 blocks
    transpose_k<<<dim3(12, 12, 6), tb, 0, stream>>>(Wq, WqkvT,                    H_, H_, (long)HH, (long)QKVW, dflag);
    transpose_k<<<dim3(12, 12, 6), tb, 0, stream>>>(Wk, WqkvT + (size_t)768*768,  H_, H_, (long)HH, (long)QKVW, dflag);
    transpose_k<<<dim3(12, 12, 6), tb, 0, stream>>>(Wv, WqkvT + (size_t)1536*768, H_, H_, (long)HH, (long)QKVW, dflag);
    transpose_k<<<dim3(12, 12, 6), tb, 0, stream>>>(Wo,  WoT,  H_, H_,  (long)HH,  (long)HH,  dflag);
    transpose_k<<<dim3(48, 12, 6), tb, 0, stream>>>(Wf1, Wf1T, H_, FF_, (long)HFF, (long)HFF, dflag);
    transpose_k<<<dim3(12, 48, 6), tb, 0, stream>>>(Wf2, Wf2T, FF_, H_, (long)HFF, (long)HFF, dflag);
    transpose_k<<<dim3(12, 12, 1), tb, 0, stream>>>(Wp1, Wp1T, H_, H_,  (long)HH,  (long)HH,  dflag);

    embed_kernel<<<M_, tb, 0, stream>>>(src, seg, tib, we, pe, se, elg, elb, sf, x32, xb, dflag);

    for (int l = 0; l < L_; ++l) {
        // QKV: M x 2304 x 768 (BN=128, 18x64=1152 blocks)
        gemm_bt<128><<<dim3(STRQ / 128, M_ / 128), tb, 0, stream>>>(xb, WqkvT + l * QKVW, bqkv + l * STRQ, qkvb, M_, STRQ, H_, 0);
        attn_kernel<<<dim3(S_ / 64, NH_, B_), tb, 0, stream>>>(qkvb, seg, ctxb);
        // Wo: M x 768 x 768 (BN=64, 12x64=768 blocks -> 3 blocks/CU)
        gemm_bt<64><<<dim3(H_ / 64, M_ / 128), tb, 0, stream>>>(ctxb, WoT + l * HH, bo6 + l * H_, tmpb, M_, H_, H_, 0);
        add_ln_kernel<<<M_, tb, 0, stream>>>(x32, tmpb, l1g, l1b, (long)l * H_, x32, xb, dflag);
        // FF1: M x 3072 x 768 + gelu (BN=128, 24x64=1536 blocks)
        gemm_bt<128><<<dim3(FF_ / 128, M_ / 128), tb, 0, stream>>>(xb, Wf1T + l * HFF, bf16_ + l * FF_, ffb, M_, FF_, H_, 1);
        // FF2: M x 768 x 3072 (BN=64, 768 blocks)
        gemm_bt<64><<<dim3(H_ / 64, M_ / 128), tb, 0, stream>>>(ffb, Wf2T + l * HFF, bf26 + l * H_, tmpb, M_, H_, FF_, 0);
        add_ln_kernel<<<M_, tb, 0, stream>>>(x32, tmpb, l2g, l2b, (long)l * H_, x32, xb, dflag);
    }

    head1_kernel<<<12, tb, 0, stream>>>(xb, Wp1T, bp1, hidb, dflag);
    head2_kernel<<<B_, dim3(640), 0, stream>>>(hidb, Wp2, bp2, lg, dflag);
    head3_kernel<<<1, dim3(192), 0, stream>>>(lg, tgt, d_out, dflag);
}

// Round 7
// 1853.715 us; speedup vs baseline: 1.4745x; 1.0323x over previous
//
#include <hip/hip_runtime.h>

typedef unsigned short u16;
typedef unsigned int   u32;
typedef __bf16  bf16x8 __attribute__((ext_vector_type(8)));
typedef float   f32x4  __attribute__((ext_vector_type(4)));

#define B_   16
#define S_   512
#define H_   768
#define NH_  12
#define L_   6
#define FF_  3072
#define M_   8192     // B_*S_
#define LAB_ 10
#define STRQ 2304     // merged qkv row stride

// ---------- bf16 helpers (storage = u16 bits) ----------
__device__ __forceinline__ float b2f(u16 x) {
    u32 u = ((u32)x) << 16; float f; __builtin_memcpy(&f, &u, 4); return f;
}
__device__ __forceinline__ u16 f2b(float f) {
    u32 u; __builtin_memcpy(&u, &f, 4);
    u32 r = u + 0x7FFFu + ((u >> 16) & 1u);
    return (u16)(r >> 16);
}
__device__ __forceinline__ float lda(const void* p, size_t i, int bf) {
    return bf ? b2f(((const u16*)p)[i]) : ((const float*)p)[i];
}
// gelu tanh-approx reformed as sigmoid: 0.5x(1+tanh(z)) = x/(1+exp(-2z)),
// 2z = 1.5957691216.. * x * (1 + 0.044715 x^2). v_exp + v_rcp (~9 VALU inst)
// vs libm tanhf (~30-50). Saturation safe: exp->inf -> rcp->0 -> gelu=0.
__device__ __forceinline__ float gelu_tanh(float x) {
    float e = __expf(-1.5957691216057308f * x * fmaf(0.044715f, x * x, 1.0f));
    return x * __builtin_amdgcn_rcpf(1.0f + e);
}
// async global->LDS, 16B per lane; LDS dest must be wave-uniform base + lane*16
__device__ __forceinline__ void async_lds16(const u16* g, u16* l) {
    __builtin_amdgcn_global_load_lds(
        (const __attribute__((address_space(1))) u32*)(const void*)g,
        (__attribute__((address_space(3))) u32*)(void*)l, 16, 0, 0);
}

// ---------- dtype detect: emb_ln_g is all ones ----------
__global__ void detect_kernel(const u32* __restrict__ g, int* __restrict__ flag) {
    flag[0] = (g[0] == 0x3F803F80u) ? 1 : 0;   // bf16 ones pair vs fp32 one
}

// ---------- block reduce (sum of two values), 256 threads ----------
__device__ __forceinline__ void block_reduce2(float& s, float& s2, float* red, int tid) {
    int lane = tid & 63, wave = tid >> 6;
    #pragma unroll
    for (int m = 32; m >= 1; m >>= 1) { s += __shfl_xor(s, m); s2 += __shfl_xor(s2, m); }
    if (lane == 0) { red[wave] = s; red[4 + wave] = s2; }
    __syncthreads();
    s  = red[0] + red[1] + red[2] + red[3];
    s2 = red[4] + red[5] + red[6] + red[7];
}

// ---------- weight transpose+convert: in (K x N) -> out bf16 (N x K) ----------
__global__ __launch_bounds__(256) void transpose_k(const void* __restrict__ in,
                                                   u16* __restrict__ out, int K, int N,
                                                   long in_lstride, long out_lstride,
                                                   const int* __restrict__ fl) {
    __shared__ u16 tile[64][65];
    const int bf = fl[0];
    const size_t ioff = (size_t)blockIdx.z * (size_t)in_lstride;
    const size_t ooff = (size_t)blockIdx.z * (size_t)out_lstride;
    int k0 = blockIdx.y * 64, n0 = blockIdx.x * 64;
    int c = threadIdx.x & 63, r0 = threadIdx.x >> 6;
    #pragma unroll
    for (int r = r0; r < 64; r += 4) {
        size_t idx = ioff + (size_t)(k0 + r) * N + n0 + c;
        tile[r][c] = bf ? ((const u16*)in)[idx] : f2b(((const float*)in)[idx]);
    }
    __syncthreads();
    #pragma unroll
    for (int r = r0; r < 64; r += 4)
        out[ooff + (size_t)(n0 + r) * K + k0 + c] = tile[c][r];
}

// ---------- bias prep: convert all GEMM biases to bf16, qkv concatenated ----------
// layout: [0,13824) bqkv (6 x 2304) | [13824,18432) bo | [18432,36864) bf1 | [36864,41472) bf2
__global__ __launch_bounds__(256) void prep_bias(
    const void* __restrict__ bq, const void* __restrict__ bk, const void* __restrict__ bv,
    const void* __restrict__ bo, const void* __restrict__ bf1, const void* __restrict__ bf2,
    u16* __restrict__ out, const int* __restrict__ fl) {
    const int bf = fl[0];
    int i = blockIdx.x * 256 + threadIdx.x;
    if (i >= 41472) return;
    float v;
    if (i < 13824) {
        int l = i / 2304, c = i % 2304;
        v = (c < 768) ? lda(bq, (size_t)l * 768 + c, bf)
          : (c < 1536) ? lda(bk, (size_t)l * 768 + c - 768, bf)
                       : lda(bv, (size_t)l * 768 + c - 1536, bf);
    } else if (i < 18432) v = lda(bo,  i - 13824, bf);
    else if (i < 36864)   v = lda(bf1, i - 18432, bf);
    else                  v = lda(bf2, i - 36864, bf);
    out[i] = f2b(v);
}

// ---------- embedding + LN + selection scale ----------
__global__ __launch_bounds__(256) void embed_kernel(
    const int* __restrict__ src, const int* __restrict__ seg, const int* __restrict__ tib,
    const void* __restrict__ we, const void* __restrict__ pe, const void* __restrict__ se,
    const void* __restrict__ g, const void* __restrict__ bb, const void* __restrict__ sf,
    float* __restrict__ x32, u16* __restrict__ xb, const int* __restrict__ fl) {
    __shared__ float red[8];
    const int bf = fl[0];
    const int r = blockIdx.x, tid = threadIdx.x;
    const int s = r & (S_ - 1);
    const int w = src[r], sg = seg[r];
    const float scale = lda(sf, tib[r], bf);
    float v[3]; int col[3];
    #pragma unroll
    for (int i = 0; i < 3; ++i) {
        col[i] = tid + i * 256;
        v[i] = lda(we, (size_t)w * H_ + col[i], bf) + lda(pe, (size_t)s * H_ + col[i], bf)
             + lda(se, (size_t)sg * H_ + col[i], bf);
    }
    float su = v[0] + v[1] + v[2];
    float sq = v[0]*v[0] + v[1]*v[1] + v[2]*v[2];
    block_reduce2(su, sq, red, tid);
    const float mean = su * (1.0f / H_);
    const float var  = sq * (1.0f / H_) - mean * mean;
    const float inv  = rsqrtf(var + 1e-5f);
    #pragma unroll
    for (int i = 0; i < 3; ++i) {
        float y = ((v[i] - mean) * inv * lda(g, col[i], bf) + lda(bb, col[i], bf)) * scale;
        x32[(size_t)r * H_ + col[i]] = y;
        xb [(size_t)r * H_ + col[i]] = f2b(y);
    }
}

// ---------- residual add + LN (x32 master, bf16 shadow out) ----------
__global__ __launch_bounds__(256) void add_ln_kernel(
    const float* __restrict__ xin, const u16* __restrict__ t,
    const void* __restrict__ g, const void* __restrict__ bb, long goff,
    float* __restrict__ xout, u16* __restrict__ xb, const int* __restrict__ fl) {
    __shared__ float red[8];
    const int bf = fl[0];
    const int r = blockIdx.x, tid = threadIdx.x;
    const size_t rb = (size_t)r * H_;
    float v[3]; int col[3];
    #pragma unroll
    for (int i = 0; i < 3; ++i) {
        col[i] = tid + i * 256;
        v[i] = xin[rb + col[i]] + b2f(t[rb + col[i]]);
    }
    float su = v[0] + v[1] + v[2];
    float sq = v[0]*v[0] + v[1]*v[1] + v[2]*v[2];
    block_reduce2(su, sq, red, tid);
    const float mean = su * (1.0f / H_);
    const float var  = sq * (1.0f / H_) - mean * mean;
    const float inv  = rsqrtf(var + 1e-5f);
    #pragma unroll
    for (int i = 0; i < 3; ++i) {
        float y = (v[i] - mean) * inv * lda(g, goff + col[i], bf) + lda(bb, goff + col[i], bf);
        xout[rb + col[i]] = y;
        xb  [rb + col[i]] = f2b(y);
    }
}

// =====================================================================
// MFMA GEMM (m97-style, 128xBNT tile, 256 thr): BK=64, XOR chunk swizzle,
// XCD-aware chunked block swizzle (T1, round-6: FF2 FETCH 201->43MB).
// Round-7: LDS-bounce epilogue -- 64 scalar global_store_short/thread
// repacked via per-wave LDS scratch into 8 coalesced dwordx4 stores.
// Values bit-identical (same f2b(acc+bias[+gelu]) per element).
// =====================================================================
template<int BNT>
__global__ __launch_bounds__(256) void gemm_bt(
    const u16* __restrict__ A, const u16* __restrict__ Bt, const u16* __restrict__ bias,
    u16* __restrict__ C, int M, int N, int K, int act) {
    constexpr int NREP = BNT / 32;          // n-frags per wave: 4 or 2
    constexpr int BCH  = BNT / 32;          // B staging chunks per thread: 4 or 2
    constexpr int WNE  = BNT / 2;           // wave col span: 64 or 32
    __shared__ alignas(16) u16 As[128 * 64];
    __shared__ alignas(16) u16 Bs[BNT * 64];
    const int tid = threadIdx.x;
    // XCD-aware chunked bijective swizzle: ids congruent mod 8 (same XCD)
    // become adjacent tiles; nwg % 8 == 0 for all our grids.
    const int nbx = (int)gridDim.x;
    const int nwg = nbx * (int)gridDim.y;
    const int lin = (int)blockIdx.y * nbx + (int)blockIdx.x;
    const int wg  = (lin & 7) * (nwg >> 3) + (lin >> 3);
    const int bm = (wg / nbx) * 128, bn = (wg % nbx) * BNT;
    const int wave = tid >> 6, lane = tid & 63;
    const int wm = (wave >> 1) * 64, wn = (wave & 1) * WNE;
    const int qd = lane >> 4, l16 = lane & 15;
    const int l7 = l16 & 7;

    const f32x4 fz = {0.f, 0.f, 0.f, 0.f};
    f32x4 acc[4][NREP];
    #pragma unroll
    for (int i = 0; i < 4; ++i)
        #pragma unroll
        for (int j = 0; j < NREP; ++j) acc[i][j] = fz;

    // staging: tile rows x 64 cols; thread covers chunks tid+u*256.
    // LDS dest linear (chunk c at base+c*8); global source chunk = (c&7)^(row&7).
    const u16* Ag[4]; int dofsA[4];
    #pragma unroll
    for (int u = 0; u < 4; ++u) {
        const int c = tid + u * 256;
        const int r = c >> 3;
        const int cs = ((c & 7) ^ (r & 7)) * 8;
        Ag[u] = A + (size_t)(bm + r) * K + cs;
        dofsA[u] = c * 8;
    }
    const u16* Bg[BCH]; int dofsB[BCH];
    #pragma unroll
    for (int u = 0; u < BCH; ++u) {
        const int c = tid + u * 256;
        const int r = c >> 3;
        const int cs = ((c & 7) ^ (r & 7)) * 8;
        Bg[u] = Bt + (size_t)(bn + r) * K + cs;
        dofsB[u] = c * 8;
    }

    for (int k0 = 0; k0 < K; k0 += 64) {
        __syncthreads();               // prev iter's LDS reads complete
        #pragma unroll
        for (int u = 0; u < 4; ++u) async_lds16(Ag[u] + k0, As + dofsA[u]);
        #pragma unroll
        for (int u = 0; u < BCH; ++u) async_lds16(Bg[u] + k0, Bs + dofsB[u]);
        __syncthreads();               // vmcnt drained by barrier semantics
        bf16x8 af[4][2], bfv[NREP][2];
        #pragma unroll
        for (int i = 0; i < 4; ++i)
            #pragma unroll
            for (int kd = 0; kd < 2; ++kd) {
                const int sw = (((kd << 2) | qd) ^ l7) << 3;   // swizzled 16B chunk
                af[i][kd] = *(const bf16x8*)(As + (wm + i * 16 + l16) * 64 + sw);
            }
        #pragma unroll
        for (int j = 0; j < NREP; ++j)
            #pragma unroll
            for (int kd = 0; kd < 2; ++kd) {
                const int sw = (((kd << 2) | qd) ^ l7) << 3;
                bfv[j][kd] = *(const bf16x8*)(Bs + (wn + j * 16 + l16) * 64 + sw);
            }
        #pragma unroll
        for (int i = 0; i < 4; ++i)
            #pragma unroll
            for (int j = 0; j < NREP; ++j)
                #pragma unroll
                for (int kd = 0; kd < 2; ++kd)
                    acc[i][j] = __builtin_amdgcn_mfma_f32_16x16x32_bf16(af[i][kd], bfv[j][kd], acc[i][j], 0, 0, 0);
    }

    // epilogue: C/D layout col=lane&15, row=(lane>>4)*4+reg.
    // LDS-bounce: scatter fragments to per-wave scratch, read back
    // row-contiguous, store dwordx4 (2 or 1 per i vs 16 scalar).
    float bvj[NREP];
    #pragma unroll
    for (int j = 0; j < NREP; ++j) bvj[j] = b2f(bias[bn + wn + j * 16 + l16]);
    __syncthreads();                       // all waves' K-loop LDS reads done (WAR)
    u16* eb = As + wave * (16 * WNE);      // per-wave scratch (<= 8KB total)
    const int er  = lane >> 2;             // 0..15 local row
    const int ecb = (lane & 3) * (WNE / 4);// u16 col base for read-back
    #pragma unroll
    for (int i = 0; i < 4; ++i) {
        #pragma unroll
        for (int j = 0; j < NREP; ++j)
            #pragma unroll
            for (int r = 0; r < 4; ++r) {
                float v = acc[i][j][r] + bvj[j];
                if (act == 1) v = gelu_tanh(v);
                eb[(qd * 4 + r) * WNE + j * 16 + l16] = f2b(v);
            }
        asm volatile("s_waitcnt lgkmcnt(0)" ::: "memory");   // writes visible (in-wave)
        u16* cp = C + (size_t)(bm + wm + i * 16 + er) * N + bn + wn + ecb;
        if constexpr (BNT == 128) {
            uint4 v0 = *(const uint4*)(eb + er * 64 + ecb);
            uint4 v1 = *(const uint4*)(eb + er * 64 + ecb + 8);
            *(uint4*)cp = v0;
            *(uint4*)(cp + 8) = v1;
        } else {
            uint4 v0 = *(const uint4*)(eb + er * 32 + ecb);
            *(uint4*)cp = v0;
        }
        asm volatile("s_waitcnt lgkmcnt(0)" ::: "memory");   // reads done before next i writes
    }
}

// ---------- flash attention: 64 queries/block, online softmax, MFMA QK^T and PV ----------
// Round-7: Q/K staged via global_load_lds (XOR chunk swizzle, gemm-verified
// pair: linear dest + pre-swizzled source + swizzled read) -- removes the
// VGPR round-trip; s_setprio(1) around MFMA clusters (T5, +4-7% in the
// independent-block attn regime, m191).
__global__ __launch_bounds__(256) void attn_kernel(
    const u16* __restrict__ QKV, const int* __restrict__ seg, u16* __restrict__ Cb) {
    __shared__ alignas(16) u16 Qs[64 * 64];     // [q][d] chunk-swizzled
    __shared__ alignas(16) u16 Ks[128 * 64];    // [key][d] chunk-swizzled
    __shared__ alignas(16) u16 Vt[64 * 136];    // [d][key] with 16B-block xor swizzle
    __shared__ alignas(16) u16 Ps[64 * 136];    // [q][key]
    __shared__ float biasv[512];
    const int tid = threadIdx.x;
    const int qt = blockIdx.x, h = blockIdx.y, b = blockIdx.z;
    const int wave = tid >> 6, lane = tid & 63;
    const int qd = lane >> 4, l16 = lane & 15;
    const int l7 = l16 & 7;
    const u16* Qg = QKV + (size_t)b * S_ * STRQ + h * 64;
    const u16* Kg = Qg + 768;
    const u16* Vg = Qg + 1536;

    // async-stage Q tile 64x64 (2 chunks/thread, source pre-XOR-swizzled)
    #pragma unroll
    for (int u = 0; u < 2; ++u) {
        const int c = tid + u * 256, r = c >> 3;
        const int cs = ((c & 7) ^ (r & 7)) * 8;
        async_lds16(Qg + (size_t)(qt * 64 + r) * STRQ + cs, Qs + c * 8);
    }

    for (int i = tid; i < 512; i += 256)
        biasv[i] = (seg[b * S_ + i] > 0) ? 0.0f : -1e9f;

    float m_run[4], l_run[4];
    f32x4 accO[4];
    #pragma unroll
    for (int r = 0; r < 4; ++r) { m_run[r] = -3.0e38f; l_run[r] = 0.f; }
    #pragma unroll
    for (int dt = 0; dt < 4; ++dt) accO[dt] = {0.f, 0.f, 0.f, 0.f};

    for (int kt = 0; kt < 512; kt += 128) {
        __syncthreads();                       // prev iter's Ks/Vt reads complete
        {   // async-stage K tile 128x64 (4 chunks/thread)
            #pragma unroll
            for (int u = 0; u < 4; ++u) {
                const int c = tid + u * 256, r = c >> 3;
                const int cs = ((c & 7) ^ (r & 7)) * 8;
                async_lds16(Kg + (size_t)(kt + r) * STRQ + cs, Ks + c * 8);
            }
        }
        {   // stage V tile transposed: Vt[d][key], key-block xor-swizzled (1024 items)
            int c = tid;
            #pragma unroll
            for (int u = 0; u < 4; ++u, c += 256) {
                int r = c >> 3, d8 = (c & 7) * 8;
                uint4 v4 = *(const uint4*)(Vg + (size_t)(kt + r) * STRQ + d8);
                u16 tmp[8]; *(uint4*)tmp = v4;
                #pragma unroll
                for (int j = 0; j < 8; ++j) {
                    int d = d8 + j;
                    int blk = (r >> 3) ^ (d >> 3);
                    Vt[d * 136 + blk * 8 + (r & 7)] = tmp[j];
                }
            }
        }
        __syncthreads();

        // ---- QK^T: wave owns q rows wave*16..+15, all 128 keys ----
        f32x4 s[8];
        {
            bf16x8 aq[2];
            #pragma unroll
            for (int kd = 0; kd < 2; ++kd)
                aq[kd] = *(const bf16x8*)(Qs + (wave * 16 + l16) * 64 + ((((kd << 2) | qd) ^ l7) << 3));
            __builtin_amdgcn_s_setprio(1);
            #pragma unroll
            for (int nt = 0; nt < 8; ++nt) {
                s[nt] = {0.f, 0.f, 0.f, 0.f};
                #pragma unroll
                for (int kd = 0; kd < 2; ++kd) {
                    bf16x8 bk = *(const bf16x8*)(Ks + (nt * 16 + l16) * 64 + ((((kd << 2) | qd) ^ l7) << 3));
                    s[nt] = __builtin_amdgcn_mfma_f32_16x16x32_bf16(aq[kd], bk, s[nt], 0, 0, 0);
                }
            }
            __builtin_amdgcn_s_setprio(0);
        }
        // scale + mask bias (bias depends on key = col = nt*16+l16)
        #pragma unroll
        for (int nt = 0; nt < 8; ++nt) {
            const float bv = biasv[kt + nt * 16 + l16];
            #pragma unroll
            for (int r = 0; r < 4; ++r) s[nt][r] = s[nt][r] * 0.125f + bv;
        }
        // online softmax: rows live in (qd, r); reduce across 16 l16 lanes
        float alpha[4], rsum[4];
        #pragma unroll
        for (int r = 0; r < 4; ++r) {
            float m = s[0][r];
            #pragma unroll
            for (int nt = 1; nt < 8; ++nt) m = fmaxf(m, s[nt][r]);
            #pragma unroll
            for (int msk = 8; msk >= 1; msk >>= 1) m = fmaxf(m, __shfl_xor(m, msk));
            float mn = fmaxf(m_run[r], m);
            alpha[r] = __expf(m_run[r] - mn);
            m_run[r] = mn;
            rsum[r] = 0.f;
        }
        #pragma unroll
        for (int nt = 0; nt < 8; ++nt)
            #pragma unroll
            for (int r = 0; r < 4; ++r) {
                float p = __expf(s[nt][r] - m_run[r]);
                rsum[r] += p;
                Ps[(wave * 16 + qd * 4 + r) * 136 + nt * 16 + l16] = f2b(p);
            }
        #pragma unroll
        for (int r = 0; r < 4; ++r) {
            float t = rsum[r];
            #pragma unroll
            for (int msk = 8; msk >= 1; msk >>= 1) t += __shfl_xor(t, msk);
            l_run[r] = l_run[r] * alpha[r] + t;
        }
        #pragma unroll
        for (int dt = 0; dt < 4; ++dt)
            #pragma unroll
            for (int r = 0; r < 4; ++r) accO[dt][r] *= alpha[r];
        __syncthreads();                       // Ps visible (and Vt already staged)

        // ---- PV: O(16x64) += P(16x128) @ V(128x64) ----
        __builtin_amdgcn_s_setprio(1);
        #pragma unroll
        for (int kk = 0; kk < 4; ++kk) {
            bf16x8 ap = *(const bf16x8*)(Ps + (wave * 16 + l16) * 136 + kk * 32 + qd * 8);
            #pragma unroll
            for (int dt = 0; dt < 4; ++dt) {
                const int d = dt * 16 + l16;
                const int blk = (kk * 4 + qd) ^ (d >> 3);
                bf16x8 bv = *(const bf16x8*)(Vt + d * 136 + blk * 8);
                accO[dt] = __builtin_amdgcn_mfma_f32_16x16x32_bf16(ap, bv, accO[dt], 0, 0, 0);
            }
        }
        __builtin_amdgcn_s_setprio(0);
    }

    // epilogue: normalize and write ctx [row][h*64+d]
    #pragma unroll
    for (int r = 0; r < 4; ++r) {
        const int row = qt * 64 + wave * 16 + qd * 4 + r;
        const float inv = 1.0f / l_run[r];
        const size_t obase = ((size_t)b * S_ + row) * H_ + h * 64;
        #pragma unroll
        for (int dt = 0; dt < 4; ++dt)
            Cb[obase + dt * 16 + l16] = f2b(accO[dt][r] * inv);
    }
}

// ---------- head1: hid = tanh(pooled @ Wp1 + bp1) via MFMA, one wave per 16x16 tile ----------
__global__ __launch_bounds__(256) void head1_kernel(
    const u16* __restrict__ xb, const u16* __restrict__ Wp1T,
    const void* __restrict__ bp1, u16* __restrict__ hidb, const int* __restrict__ fl) {
    __shared__ alignas(16) u16 Xs[16 * 776];     // stride 776 breaks 16-way bank alias
    const int bf = fl[0];
    const int tid = threadIdx.x, wave = tid >> 6, lane = tid & 63;
    const int qd = lane >> 4, l16 = lane & 15;
    for (int i = tid; i < 16 * 96; i += 256) {   // 96 uint4 per pooled row
        int b = i / 96, c = (i % 96) * 8;
        *(uint4*)(Xs + b * 776 + c) = *(const uint4*)(xb + ((size_t)b * S_) * H_ + c);
    }
    __syncthreads();
    const int n0 = (blockIdx.x * 4 + wave) * 16;
    f32x4 acc = {0.f, 0.f, 0.f, 0.f};
    for (int k0 = 0; k0 < H_; k0 += 32) {
        bf16x8 a  = *(const bf16x8*)(Xs + l16 * 776 + k0 + qd * 8);
        bf16x8 bb = *(const bf16x8*)(Wp1T + (size_t)(n0 + l16) * H_ + k0 + qd * 8);
        acc = __builtin_amdgcn_mfma_f32_16x16x32_bf16(a, bb, acc, 0, 0, 0);
    }
    // C/D: col=l16 (j), row=qd*4+r (batch)
    #pragma unroll
    for (int r = 0; r < 4; ++r) {
        const int b = qd * 4 + r, j = n0 + l16;
        hidb[b * H_ + j] = f2b(tanhf(acc[r] + lda(bp1, j, bf)));
    }
}

// ---------- head2: logits, wave per (batch, label) ----------
__global__ __launch_bounds__(640) void head2_kernel(
    const u16* __restrict__ hidb, const void* __restrict__ Wp2, const void* __restrict__ bp2,
    float* __restrict__ lg, const int* __restrict__ fl) {
    const int bf = fl[0];
    const int b = blockIdx.x, j = threadIdx.x >> 6, lane = threadIdx.x & 63;
    float s = 0.f;
    for (int k = lane; k < H_; k += 64)
        s += b2f(hidb[b * H_ + k]) * lda(Wp2, (size_t)k * LAB_ + j, bf);
    #pragma unroll
    for (int m = 32; m >= 1; m >>= 1) s += __shfl_xor(s, m);
    if (lane == 0) lg[b * LAB_ + j] = s + lda(bp2, j, bf);
}

// ---------- head3: log-softmax loss + dual-format output ----------
__global__ __launch_bounds__(192) void head3_kernel(
    const float* __restrict__ lg, const int* __restrict__ tgt,
    void* __restrict__ outv, const int* __restrict__ fl) {
    __shared__ float lse[B_];
    const int bf = fl[0], t = threadIdx.x;
    if (t < B_) {
        float mx = -1e30f;
        for (int j = 0; j < LAB_; ++j) mx = fmaxf(mx, lg[t * LAB_ + j]);
        float s = 0.f;
        for (int j = 0; j < LAB_; ++j) s += expf(lg[t * LAB_ + j] - mx);
        lse[t] = mx + logf(s);
    }
    __syncthreads();
    float loss = 0.f;
    if (t == 0) {
        for (int b = 0; b < B_; ++b) loss += lse[b] - lg[b * LAB_ + tgt[b]];
        loss /= (float)B_;
    }
    if (bf) {
        u16* o = (u16*)outv;
        if (t == 0) o[0] = f2b(loss);
        if (t < B_ * LAB_) o[1 + t] = f2b(lg[t]);
    } else {
        float* o = (float*)outv;
        if (t == 0) o[0] = loss;
        if (t < B_ * LAB_) o[1 + t] = lg[t];
    }
}

// ---------- launch ----------
extern "C" void kernel_launch(void* const* d_in, const int* in_sizes, int n_in,
                              void* d_out, int out_size, void* d_ws, size_t ws_size,
                              hipStream_t stream) {
    (void)in_sizes; (void)n_in; (void)out_size; (void)ws_size;
    const int* src = (const int*)d_in[0];
    const int* seg = (const int*)d_in[1];
    const int* tgt = (const int*)d_in[2];
    const int* tib = (const int*)d_in[3];
    const void* we  = d_in[4];
    const void* pe  = d_in[5];
    const void* se  = d_in[6];
    const void* elg = d_in[7];
    const void* elb = d_in[8];
    const void* Wq  = d_in[9];
    const void* bq  = d_in[10];
    const void* Wk  = d_in[11];
    const void* bk  = d_in[12];
    const void* Wv  = d_in[13];
    const void* bv  = d_in[14];
    const void* Wo  = d_in[15];
    const void* bo  = d_in[16];
    const void* l1g = d_in[17];
    const void* l1b = d_in[18];
    const void* Wf1 = d_in[19];
    const void* bf1 = d_in[20];
    const void* Wf2 = d_in[21];
    const void* bf2 = d_in[22];
    const void* l2g = d_in[23];
    const void* l2b = d_in[24];
    const void* Wp1 = d_in[25];
    const void* bp1 = d_in[26];
    const void* Wp2 = d_in[27];
    const void* bp2 = d_in[28];
    const void* sf  = d_in[29];

    const size_t HH   = (size_t)H_ * H_;        // 589824
    const size_t HFF  = (size_t)H_ * FF_;       // 2359296
    const size_t MH   = (size_t)M_ * H_;        // 6291456
    const size_t MQKV = (size_t)M_ * STRQ;      // 18874368
    const size_t MFF  = (size_t)M_ * FF_;       // 25165824
    const size_t QKVW = (size_t)STRQ * H_;      // 1769472 (per-layer merged weight)

    char* w = (char*)d_ws;
    int* dflag  = (int*)w;  w += 256;
    u16* bias_ws = (u16*)w; w += 41472 * 2;     // prep_bias layout
    u16* WqkvT = (u16*)w;  w += L_ * QKVW * 2;
    u16* WoT   = (u16*)w;  w += L_ * HH  * 2;
    u16* Wf1T  = (u16*)w;  w += L_ * HFF * 2;
    u16* Wf2T  = (u16*)w;  w += L_ * HFF * 2;
    u16* Wp1T  = (u16*)w;  w += HH * 2;
    float* x32 = (float*)w; w += MH * 4;
    u16* xb    = (u16*)w;  w += MH * 2;
    u16* qkvb  = (u16*)w;  w += MQKV * 2;
    u16* ctxb  = (u16*)w;  w += MH * 2;
    u16* tmpb  = (u16*)w;  w += MH * 2;
    u16* ffb   = (u16*)w;  w += MFF * 2;
    u16* hidb  = (u16*)w;  w += (size_t)B_ * H_ * 2;
    float* lg  = (float*)w; w += (size_t)B_ * LAB_ * 4;

    u16* bqkv = bias_ws;            // 6 x 2304
    u16* bo6  = bias_ws + 13824;    // 6 x 768
    u16* bf16_= bias_ws + 18432;    // 6 x 3072
    u16* bf26 = bias_ws + 36864;    // 6 x 768

    const dim3 tb(256);
    detect_kernel<<<1, 1, 0, stream>>>((const u32*)elg, dflag);
    prep_bias<<<162, tb, 0, stream>>>(bq, bk, bv, bo, bf1, bf2, bias_ws, dflag);

    // weight transposes+convert; Wq/Wk/Wv interleave into per-layer 2304x768 blocks
    transpose_k<<<dim3(12, 12, 6), tb, 0, stream>>>(Wq, WqkvT,                    H_, H_, (long)HH, (long)QKVW, dflag);
    transpose_k<<<dim3(12, 12, 6), tb, 0, stream>>>(Wk, WqkvT + (size_t)768*768,  H_, H_, (long)HH, (long)QKVW, dflag);
    transpose_k<<<dim3(12, 12, 6), tb, 0, stream>>>(Wv, WqkvT + (size_t)1536*768, H_, H_, (long)HH, (long)QKVW, dflag);
    transpose_k<<<dim3(12, 12, 6), tb, 0, stream>>>(Wo,  WoT,  H_, H_,  (long)HH,  (long)HH,  dflag);
    transpose_k<<<dim3(48, 12, 6), tb, 0, stream>>>(Wf1, Wf1T, H_, FF_, (long)HFF, (long)HFF, dflag);
    transpose_k<<<dim3(12, 48, 6), tb, 0, stream>>>(Wf2, Wf2T, FF_, H_, (long)HFF, (long)HFF, dflag);
    transpose_k<<<dim3(12, 12, 1), tb, 0, stream>>>(Wp1, Wp1T, H_, H_,  (long)HH,  (long)HH,  dflag);

    embed_kernel<<<M_, tb, 0, stream>>>(src, seg, tib, we, pe, se, elg, elb, sf, x32, xb, dflag);

    for (int l = 0; l < L_; ++l) {
        // QKV: M x 2304 x 768 (BN=128, 18x64=1152 blocks)
        gemm_bt<128><<<dim3(STRQ / 128, M_ / 128), tb, 0, stream>>>(xb, WqkvT + l * QKVW, bqkv + l * STRQ, qkvb, M_, STRQ, H_, 0);
        attn_kernel<<<dim3(S_ / 64, NH_, B_), tb, 0, stream>>>(qkvb, seg, ctxb);
        // Wo: M x 768 x 768 (BN=64, 12x64=768 blocks -> 3 blocks/CU)
        gemm_bt<64><<<dim3(H_ / 64, M_ / 128), tb, 0, stream>>>(ctxb, WoT + l * HH, bo6 + l * H_, tmpb, M_, H_, H_, 0);
        add_ln_kernel<<<M_, tb, 0, stream>>>(x32, tmpb, l1g, l1b, (long)l * H_, x32, xb, dflag);
        // FF1: M x 3072 x 768 + gelu (BN=128, 24x64=1536 blocks)
        gemm_bt<128><<<dim3(FF_ / 128, M_ / 128), tb, 0, stream>>>(xb, Wf1T + l * HFF, bf16_ + l * FF_, ffb, M_, FF_, H_, 1);
        // FF2: M x 768 x 3072 (BN=64, 768 blocks)
        gemm_bt<64><<<dim3(H_ / 64, M_ / 128), tb, 0, stream>>>(ffb, Wf2T + l * HFF, bf26 + l * H_, tmpb, M_, H_, FF_, 0);
        add_ln_kernel<<<M_, tb, 0, stream>>>(x32, tmpb, l2g, l2b, (long)l * H_, x32, xb, dflag);
    }

    head1_kernel<<<12, tb, 0, stream>>>(xb, Wp1T, bp1, hidb, dflag);
    head2_kernel<<<B_, dim3(640), 0, stream>>>(hidb, Wp2, bp2, lg, dflag);
    head3_kernel<<<1, dim3(192), 0, stream>>>(lg, tgt, d_out, dflag);
}

// Round 8
// 1786.506 us; speedup vs baseline: 1.5300x; 1.0376x over previous
//
#include <hip/hip_runtime.h>

typedef unsigned short u16;
typedef unsigned int   u32;
typedef __bf16  bf16x8 __attribute__((ext_vector_type(8)));
typedef float   f32x4  __attribute__((ext_vector_type(4)));

#define B_   16
#define S_   512
#define H_   768
#define NH_  12
#define L_   6
#define FF_  3072
#define M_   8192     // B_*S_
#define LAB_ 10
#define STRQ 2304     // merged qkv row stride

// ---------- bf16 helpers (storage = u16 bits) ----------
__device__ __forceinline__ float b2f(u16 x) {
    u32 u = ((u32)x) << 16; float f; __builtin_memcpy(&f, &u, 4); return f;
}
__device__ __forceinline__ u16 f2b(float f) {
    u32 u; __builtin_memcpy(&u, &f, 4);
    u32 r = u + 0x7FFFu + ((u >> 16) & 1u);
    return (u16)(r >> 16);
}
__device__ __forceinline__ float lda(const void* p, size_t i, int bf) {
    return bf ? b2f(((const u16*)p)[i]) : ((const float*)p)[i];
}
// gelu tanh-approx reformed as sigmoid: 0.5x(1+tanh(z)) = x/(1+exp(-2z)),
// 2z = 1.5957691216.. * x * (1 + 0.044715 x^2). v_exp + v_rcp (~9 VALU inst)
// vs libm tanhf (~30-50). Saturation safe: exp->inf -> rcp->0 -> gelu=0.
__device__ __forceinline__ float gelu_tanh(float x) {
    float e = __expf(-1.5957691216057308f * x * fmaf(0.044715f, x * x, 1.0f));
    return x * __builtin_amdgcn_rcpf(1.0f + e);
}
// async global->LDS, 16B per lane; LDS dest must be wave-uniform base + lane*16
__device__ __forceinline__ void async_lds16(const u16* g, u16* l) {
    __builtin_amdgcn_global_load_lds(
        (const __attribute__((address_space(1))) u32*)(const void*)g,
        (__attribute__((address_space(3))) u32*)(void*)l, 16, 0, 0);
}

// ---------- dtype detect: emb_ln_g is all ones ----------
__global__ void detect_kernel(const u32* __restrict__ g, int* __restrict__ flag) {
    flag[0] = (g[0] == 0x3F803F80u) ? 1 : 0;   // bf16 ones pair vs fp32 one
}

// ---------- block reduce (sum of two values), 256 threads ----------
__device__ __forceinline__ void block_reduce2(float& s, float& s2, float* red, int tid) {
    int lane = tid & 63, wave = tid >> 6;
    #pragma unroll
    for (int m = 32; m >= 1; m >>= 1) { s += __shfl_xor(s, m); s2 += __shfl_xor(s2, m); }
    if (lane == 0) { red[wave] = s; red[4 + wave] = s2; }
    __syncthreads();
    s  = red[0] + red[1] + red[2] + red[3];
    s2 = red[4] + red[5] + red[6] + red[7];
}

// ---------- weight transpose+convert: in (K x N) -> out bf16 (N x K) ----------
__global__ __launch_bounds__(256) void transpose_k(const void* __restrict__ in,
                                                   u16* __restrict__ out, int K, int N,
                                                   long in_lstride, long out_lstride,
                                                   const int* __restrict__ fl) {
    __shared__ u16 tile[64][65];
    const int bf = fl[0];
    const size_t ioff = (size_t)blockIdx.z * (size_t)in_lstride;
    const size_t ooff = (size_t)blockIdx.z * (size_t)out_lstride;
    int k0 = blockIdx.y * 64, n0 = blockIdx.x * 64;
    int c = threadIdx.x & 63, r0 = threadIdx.x >> 6;
    #pragma unroll
    for (int r = r0; r < 64; r += 4) {
        size_t idx = ioff + (size_t)(k0 + r) * N + n0 + c;
        tile[r][c] = bf ? ((const u16*)in)[idx] : f2b(((const float*)in)[idx]);
    }
    __syncthreads();
    #pragma unroll
    for (int r = r0; r < 64; r += 4)
        out[ooff + (size_t)(n0 + r) * K + k0 + c] = tile[c][r];
}

// ---------- bias prep: convert all GEMM biases to bf16, qkv concatenated ----------
// layout: [0,13824) bqkv (6 x 2304) | [13824,18432) bo | [18432,36864) bf1 | [36864,41472) bf2
__global__ __launch_bounds__(256) void prep_bias(
    const void* __restrict__ bq, const void* __restrict__ bk, const void* __restrict__ bv,
    const void* __restrict__ bo, const void* __restrict__ bf1, const void* __restrict__ bf2,
    u16* __restrict__ out, const int* __restrict__ fl) {
    const int bf = fl[0];
    int i = blockIdx.x * 256 + threadIdx.x;
    if (i >= 41472) return;
    float v;
    if (i < 13824) {
        int l = i / 2304, c = i % 2304;
        v = (c < 768) ? lda(bq, (size_t)l * 768 + c, bf)
          : (c < 1536) ? lda(bk, (size_t)l * 768 + c - 768, bf)
                       : lda(bv, (size_t)l * 768 + c - 1536, bf);
    } else if (i < 18432) v = lda(bo,  i - 13824, bf);
    else if (i < 36864)   v = lda(bf1, i - 18432, bf);
    else                  v = lda(bf2, i - 36864, bf);
    out[i] = f2b(v);
}

// ---------- embedding + LN + selection scale ----------
__global__ __launch_bounds__(256) void embed_kernel(
    const int* __restrict__ src, const int* __restrict__ seg, const int* __restrict__ tib,
    const void* __restrict__ we, const void* __restrict__ pe, const void* __restrict__ se,
    const void* __restrict__ g, const void* __restrict__ bb, const void* __restrict__ sf,
    float* __restrict__ x32, u16* __restrict__ xb, const int* __restrict__ fl) {
    __shared__ float red[8];
    const int bf = fl[0];
    const int r = blockIdx.x, tid = threadIdx.x;
    const int s = r & (S_ - 1);
    const int w = src[r], sg = seg[r];
    const float scale = lda(sf, tib[r], bf);
    float v[3]; int col[3];
    #pragma unroll
    for (int i = 0; i < 3; ++i) {
        col[i] = tid + i * 256;
        v[i] = lda(we, (size_t)w * H_ + col[i], bf) + lda(pe, (size_t)s * H_ + col[i], bf)
             + lda(se, (size_t)sg * H_ + col[i], bf);
    }
    float su = v[0] + v[1] + v[2];
    float sq = v[0]*v[0] + v[1]*v[1] + v[2]*v[2];
    block_reduce2(su, sq, red, tid);
    const float mean = su * (1.0f / H_);
    const float var  = sq * (1.0f / H_) - mean * mean;
    const float inv  = rsqrtf(var + 1e-5f);
    #pragma unroll
    for (int i = 0; i < 3; ++i) {
        float y = ((v[i] - mean) * inv * lda(g, col[i], bf) + lda(bb, col[i], bf)) * scale;
        x32[(size_t)r * H_ + col[i]] = y;
        xb [(size_t)r * H_ + col[i]] = f2b(y);
    }
}

// ---------- residual add + LN (x32 master, bf16 shadow out) ----------
__global__ __launch_bounds__(256) void add_ln_kernel(
    const float* __restrict__ xin, const u16* __restrict__ t,
    const void* __restrict__ g, const void* __restrict__ bb, long goff,
    float* __restrict__ xout, u16* __restrict__ xb, const int* __restrict__ fl) {
    __shared__ float red[8];
    const int bf = fl[0];
    const int r = blockIdx.x, tid = threadIdx.x;
    const size_t rb = (size_t)r * H_;
    float v[3]; int col[3];
    #pragma unroll
    for (int i = 0; i < 3; ++i) {
        col[i] = tid + i * 256;
        v[i] = xin[rb + col[i]] + b2f(t[rb + col[i]]);
    }
    float su = v[0] + v[1] + v[2];
    float sq = v[0]*v[0] + v[1]*v[1] + v[2]*v[2];
    block_reduce2(su, sq, red, tid);
    const float mean = su * (1.0f / H_);
    const float var  = sq * (1.0f / H_) - mean * mean;
    const float inv  = rsqrtf(var + 1e-5f);
    #pragma unroll
    for (int i = 0; i < 3; ++i) {
        float y = (v[i] - mean) * inv * lda(g, goff + col[i], bf) + lda(bb, goff + col[i], bf);
        xout[rb + col[i]] = y;
        xb  [rb + col[i]] = f2b(y);
    }
}

// =====================================================================
// MFMA GEMM (m97-style, 128xBNT tile, BKx per K-step, 256 thr):
// XOR chunk swizzle, XCD-aware chunked block swizzle (T1), LDS-bounce
// coalesced epilogue. Round-8: BK=128 for the BN=64 (Wo/FF2) path --
// round-7 counters showed FF2 barrier-drain-bound (Mfma 25/VALU 29/HBM 11,
// 48 K-steps x fixed drain cost). BK=128 halves barrier events; LDS
// 48KB keeps 3 blocks/CU (m132's 64KB cliff doesn't apply);
// launch_bounds(256,3) caps VGPR at 168 to protect occupancy.
// K-accumulation order per output element unchanged -> bit-identical.
// =====================================================================
template<int BNT, int BK>
__global__ __launch_bounds__(256, 3) void gemm_bt(
    const u16* __restrict__ A, const u16* __restrict__ Bt, const u16* __restrict__ bias,
    u16* __restrict__ C, int M, int N, int K, int act) {
    constexpr int NREP = BNT / 32;          // n-frags per wave: 4 or 2
    constexpr int WNE  = BNT / 2;           // wave col span: 64 or 32
    constexpr int CPR  = BK / 8;            // 16B chunks per row: 8 or 16
    constexpr int CSH  = (BK == 128) ? 4 : 3;
    constexpr int KMSK = CPR - 1;
    constexpr int KD   = BK / 32;           // mfma k-frags per step: 2 or 4
    constexpr int ACH  = 128 * CPR / 256;   // A chunks/thread: 4 or 8
    constexpr int BCH  = BNT * CPR / 256;   // B chunks/thread: 4
    __shared__ alignas(16) u16 As[128 * BK];
    __shared__ alignas(16) u16 Bs[BNT * BK];
    const int tid = threadIdx.x;
    // XCD-aware chunked bijective swizzle: ids congruent mod 8 (same XCD)
    // become adjacent tiles; nwg % 8 == 0 for all our grids.
    const int nbx = (int)gridDim.x;
    const int nwg = nbx * (int)gridDim.y;
    const int lin = (int)blockIdx.y * nbx + (int)blockIdx.x;
    const int wg  = (lin & 7) * (nwg >> 3) + (lin >> 3);
    const int bm = (wg / nbx) * 128, bn = (wg % nbx) * BNT;
    const int wave = tid >> 6, lane = tid & 63;
    const int wm = (wave >> 1) * 64, wn = (wave & 1) * WNE;
    const int qd = lane >> 4, l16 = lane & 15;
    const int lk = l16 & KMSK;

    const f32x4 fz = {0.f, 0.f, 0.f, 0.f};
    f32x4 acc[4][NREP];
    #pragma unroll
    for (int i = 0; i < 4; ++i)
        #pragma unroll
        for (int j = 0; j < NREP; ++j) acc[i][j] = fz;

    // staging: tile rows x BK cols; thread covers chunks tid+u*256.
    // LDS dest linear (chunk c at base+c*8); global source chunk = (c&KMSK)^(row&KMSK).
    const u16* Ag[ACH]; int dofsA[ACH];
    #pragma unroll
    for (int u = 0; u < ACH; ++u) {
        const int c = tid + u * 256;
        const int r = c >> CSH;
        const int cs = ((c & KMSK) ^ (r & KMSK)) * 8;
        Ag[u] = A + (size_t)(bm + r) * K + cs;
        dofsA[u] = c * 8;
    }
    const u16* Bg[BCH]; int dofsB[BCH];
    #pragma unroll
    for (int u = 0; u < BCH; ++u) {
        const int c = tid + u * 256;
        const int r = c >> CSH;
        const int cs = ((c & KMSK) ^ (r & KMSK)) * 8;
        Bg[u] = Bt + (size_t)(bn + r) * K + cs;
        dofsB[u] = c * 8;
    }

    for (int k0 = 0; k0 < K; k0 += BK) {
        __syncthreads();               // prev iter's LDS reads complete
        #pragma unroll
        for (int u = 0; u < ACH; ++u) async_lds16(Ag[u] + k0, As + dofsA[u]);
        #pragma unroll
        for (int u = 0; u < BCH; ++u) async_lds16(Bg[u] + k0, Bs + dofsB[u]);
        __syncthreads();               // vmcnt drained by barrier semantics
        bf16x8 af[4][KD], bfv[NREP][KD];
        #pragma unroll
        for (int i = 0; i < 4; ++i)
            #pragma unroll
            for (int kd = 0; kd < KD; ++kd) {
                const int sw = (((kd << 2) | qd) ^ lk) << 3;   // swizzled 16B chunk
                af[i][kd] = *(const bf16x8*)(As + (wm + i * 16 + l16) * BK + sw);
            }
        #pragma unroll
        for (int j = 0; j < NREP; ++j)
            #pragma unroll
            for (int kd = 0; kd < KD; ++kd) {
                const int sw = (((kd << 2) | qd) ^ lk) << 3;
                bfv[j][kd] = *(const bf16x8*)(Bs + (wn + j * 16 + l16) * BK + sw);
            }
        #pragma unroll
        for (int i = 0; i < 4; ++i)
            #pragma unroll
            for (int j = 0; j < NREP; ++j)
                #pragma unroll
                for (int kd = 0; kd < KD; ++kd)
                    acc[i][j] = __builtin_amdgcn_mfma_f32_16x16x32_bf16(af[i][kd], bfv[j][kd], acc[i][j], 0, 0, 0);
    }

    // epilogue: C/D layout col=lane&15, row=(lane>>4)*4+reg.
    // LDS-bounce: scatter fragments to per-wave scratch, read back
    // row-contiguous, store dwordx4 (2 or 1 per i vs 16 scalar).
    float bvj[NREP];
    #pragma unroll
    for (int j = 0; j < NREP; ++j) bvj[j] = b2f(bias[bn + wn + j * 16 + l16]);
    __syncthreads();                       // all waves' K-loop LDS reads done (WAR)
    u16* eb = As + wave * (16 * WNE);      // per-wave scratch (<= 8KB total)
    const int er  = lane >> 2;             // 0..15 local row
    const int ecb = (lane & 3) * (WNE / 4);// u16 col base for read-back
    #pragma unroll
    for (int i = 0; i < 4; ++i) {
        #pragma unroll
        for (int j = 0; j < NREP; ++j)
            #pragma unroll
            for (int r = 0; r < 4; ++r) {
                float v = acc[i][j][r] + bvj[j];
                if (act == 1) v = gelu_tanh(v);
                eb[(qd * 4 + r) * WNE + j * 16 + l16] = f2b(v);
            }
        asm volatile("s_waitcnt lgkmcnt(0)" ::: "memory");   // writes visible (in-wave)
        u16* cp = C + (size_t)(bm + wm + i * 16 + er) * N + bn + wn + ecb;
        if constexpr (BNT == 128) {
            uint4 v0 = *(const uint4*)(eb + er * 64 + ecb);
            uint4 v1 = *(const uint4*)(eb + er * 64 + ecb + 8);
            *(uint4*)cp = v0;
            *(uint4*)(cp + 8) = v1;
        } else {
            uint4 v0 = *(const uint4*)(eb + er * 32 + ecb);
            *(uint4*)cp = v0;
        }
        asm volatile("s_waitcnt lgkmcnt(0)" ::: "memory");   // reads done before next i writes
    }
}

// ---------- flash attention: 64 queries/block, online softmax, MFMA QK^T and PV ----------
// Q/K staged via global_load_lds (XOR chunk swizzle, gemm-verified pair:
// linear dest + pre-swizzled source + swizzled read); s_setprio(1) around
// MFMA clusters (T5, independent-block attn regime, m191).
__global__ __launch_bounds__(256) void attn_kernel(
    const u16* __restrict__ QKV, const int* __restrict__ seg, u16* __restrict__ Cb) {
    __shared__ alignas(16) u16 Qs[64 * 64];     // [q][d] chunk-swizzled
    __shared__ alignas(16) u16 Ks[128 * 64];    // [key][d] chunk-swizzled
    __shared__ alignas(16) u16 Vt[64 * 136];    // [d][key] with 16B-block xor swizzle
    __shared__ alignas(16) u16 Ps[64 * 136];    // [q][key]
    __shared__ float biasv[512];
    const int tid = threadIdx.x;
    const int qt = blockIdx.x, h = blockIdx.y, b = blockIdx.z;
    const int wave = tid >> 6, lane = tid & 63;
    const int qd = lane >> 4, l16 = lane & 15;
    const int l7 = l16 & 7;
    const u16* Qg = QKV + (size_t)b * S_ * STRQ + h * 64;
    const u16* Kg = Qg + 768;
    const u16* Vg = Qg + 1536;

    // async-stage Q tile 64x64 (2 chunks/thread, source pre-XOR-swizzled)
    #pragma unroll
    for (int u = 0; u < 2; ++u) {
        const int c = tid + u * 256, r = c >> 3;
        const int cs = ((c & 7) ^ (r & 7)) * 8;
        async_lds16(Qg + (size_t)(qt * 64 + r) * STRQ + cs, Qs + c * 8);
    }

    for (int i = tid; i < 512; i += 256)
        biasv[i] = (seg[b * S_ + i] > 0) ? 0.0f : -1e9f;

    float m_run[4], l_run[4];
    f32x4 accO[4];
    #pragma unroll
    for (int r = 0; r < 4; ++r) { m_run[r] = -3.0e38f; l_run[r] = 0.f; }
    #pragma unroll
    for (int dt = 0; dt < 4; ++dt) accO[dt] = {0.f, 0.f, 0.f, 0.f};

    for (int kt = 0; kt < 512; kt += 128) {
        __syncthreads();                       // prev iter's Ks/Vt reads complete
        {   // async-stage K tile 128x64 (4 chunks/thread)
            #pragma unroll
            for (int u = 0; u < 4; ++u) {
                const int c = tid + u * 256, r = c >> 3;
                const int cs = ((c & 7) ^ (r & 7)) * 8;
                async_lds16(Kg + (size_t)(kt + r) * STRQ + cs, Ks + c * 8);
            }
        }
        {   // stage V tile transposed: Vt[d][key], key-block xor-swizzled (1024 items)
            int c = tid;
            #pragma unroll
            for (int u = 0; u < 4; ++u, c += 256) {
                int r = c >> 3, d8 = (c & 7) * 8;
                uint4 v4 = *(const uint4*)(Vg + (size_t)(kt + r) * STRQ + d8);
                u16 tmp[8]; *(uint4*)tmp = v4;
                #pragma unroll
                for (int j = 0; j < 8; ++j) {
                    int d = d8 + j;
                    int blk = (r >> 3) ^ (d >> 3);
                    Vt[d * 136 + blk * 8 + (r & 7)] = tmp[j];
                }
            }
        }
        __syncthreads();

        // ---- QK^T: wave owns q rows wave*16..+15, all 128 keys ----
        f32x4 s[8];
        {
            bf16x8 aq[2];
            #pragma unroll
            for (int kd = 0; kd < 2; ++kd)
                aq[kd] = *(const bf16x8*)(Qs + (wave * 16 + l16) * 64 + ((((kd << 2) | qd) ^ l7) << 3));
            __builtin_amdgcn_s_setprio(1);
            #pragma unroll
            for (int nt = 0; nt < 8; ++nt) {
                s[nt] = {0.f, 0.f, 0.f, 0.f};
                #pragma unroll
                for (int kd = 0; kd < 2; ++kd) {
                    bf16x8 bk = *(const bf16x8*)(Ks + (nt * 16 + l16) * 64 + ((((kd << 2) | qd) ^ l7) << 3));
                    s[nt] = __builtin_amdgcn_mfma_f32_16x16x32_bf16(aq[kd], bk, s[nt], 0, 0, 0);
                }
            }
            __builtin_amdgcn_s_setprio(0);
        }
        // scale + mask bias (bias depends on key = col = nt*16+l16)
        #pragma unroll
        for (int nt = 0; nt < 8; ++nt) {
            const float bv = biasv[kt + nt * 16 + l16];
            #pragma unroll
            for (int r = 0; r < 4; ++r) s[nt][r] = s[nt][r] * 0.125f + bv;
        }
        // online softmax: rows live in (qd, r); reduce across 16 l16 lanes
        float alpha[4], rsum[4];
        #pragma unroll
        for (int r = 0; r < 4; ++r) {
            float m = s[0][r];
            #pragma unroll
            for (int nt = 1; nt < 8; ++nt) m = fmaxf(m, s[nt][r]);
            #pragma unroll
            for (int msk = 8; msk >= 1; msk >>= 1) m = fmaxf(m, __shfl_xor(m, msk));
            float mn = fmaxf(m_run[r], m);
            alpha[r] = __expf(m_run[r] - mn);
            m_run[r] = mn;
            rsum[r] = 0.f;
        }
        #pragma unroll
        for (int nt = 0; nt < 8; ++nt)
            #pragma unroll
            for (int r = 0; r < 4; ++r) {
                float p = __expf(s[nt][r] - m_run[r]);
                rsum[r] += p;
                Ps[(wave * 16 + qd * 4 + r) * 136 + nt * 16 + l16] = f2b(p);
            }
        #pragma unroll
        for (int r = 0; r < 4; ++r) {
            float t = rsum[r];
            #pragma unroll
            for (int msk = 8; msk >= 1; msk >>= 1) t += __shfl_xor(t, msk);
            l_run[r] = l_run[r] * alpha[r] + t;
        }
        #pragma unroll
        for (int dt = 0; dt < 4; ++dt)
            #pragma unroll
            for (int r = 0; r < 4; ++r) accO[dt][r] *= alpha[r];
        __syncthreads();                       // Ps visible (and Vt already staged)

        // ---- PV: O(16x64) += P(16x128) @ V(128x64) ----
        __builtin_amdgcn_s_setprio(1);
        #pragma unroll
        for (int kk = 0; kk < 4; ++kk) {
            bf16x8 ap = *(const bf16x8*)(Ps + (wave * 16 + l16) * 136 + kk * 32 + qd * 8);
            #pragma unroll
            for (int dt = 0; dt < 4; ++dt) {
                const int d = dt * 16 + l16;
                const int blk = (kk * 4 + qd) ^ (d >> 3);
                bf16x8 bv = *(const bf16x8*)(Vt + d * 136 + blk * 8);
                accO[dt] = __builtin_amdgcn_mfma_f32_16x16x32_bf16(ap, bv, accO[dt], 0, 0, 0);
            }
        }
        __builtin_amdgcn_s_setprio(0);
    }

    // epilogue: normalize and write ctx [row][h*64+d]
    #pragma unroll
    for (int r = 0; r < 4; ++r) {
        const int row = qt * 64 + wave * 16 + qd * 4 + r;
        const float inv = 1.0f / l_run[r];
        const size_t obase = ((size_t)b * S_ + row) * H_ + h * 64;
        #pragma unroll
        for (int dt = 0; dt < 4; ++dt)
            Cb[obase + dt * 16 + l16] = f2b(accO[dt][r] * inv);
    }
}

// ---------- head1: hid = tanh(pooled @ Wp1 + bp1) via MFMA, one wave per 16x16 tile ----------
__global__ __launch_bounds__(256) void head1_kernel(
    const u16* __restrict__ xb, const u16* __restrict__ Wp1T,
    const void* __restrict__ bp1, u16* __restrict__ hidb, const int* __restrict__ fl) {
    __shared__ alignas(16) u16 Xs[16 * 776];     // stride 776 breaks 16-way bank alias
    const int bf = fl[0];
    const int tid = threadIdx.x, wave = tid >> 6, lane = tid & 63;
    const int qd = lane >> 4, l16 = lane & 15;
    for (int i = tid; i < 16 * 96; i += 256) {   // 96 uint4 per pooled row
        int b = i / 96, c = (i % 96) * 8;
        *(uint4*)(Xs + b * 776 + c) = *(const uint4*)(xb + ((size_t)b * S_) * H_ + c);
    }
    __syncthreads();
    const int n0 = (blockIdx.x * 4 + wave) * 16;
    f32x4 acc = {0.f, 0.f, 0.f, 0.f};
    for (int k0 = 0; k0 < H_; k0 += 32) {
        bf16x8 a  = *(const bf16x8*)(Xs + l16 * 776 + k0 + qd * 8);
        bf16x8 bb = *(const bf16x8*)(Wp1T + (size_t)(n0 + l16) * H_ + k0 + qd * 8);
        acc = __builtin_amdgcn_mfma_f32_16x16x32_bf16(a, bb, acc, 0, 0, 0);
    }
    // C/D: col=l16 (j), row=qd*4+r (batch)
    #pragma unroll
    for (int r = 0; r < 4; ++r) {
        const int b = qd * 4 + r, j = n0 + l16;
        hidb[b * H_ + j] = f2b(tanhf(acc[r] + lda(bp1, j, bf)));
    }
}

// ---------- head2: logits, wave per (batch, label) ----------
__global__ __launch_bounds__(640) void head2_kernel(
    const u16* __restrict__ hidb, const void* __restrict__ Wp2, const void* __restrict__ bp2,
    float* __restrict__ lg, const int* __restrict__ fl) {
    const int bf = fl[0];
    const int b = blockIdx.x, j = threadIdx.x >> 6, lane = threadIdx.x & 63;
    float s = 0.f;
    for (int k = lane; k < H_; k += 64)
        s += b2f(hidb[b * H_ + k]) * lda(Wp2, (size_t)k * LAB_ + j, bf);
    #pragma unroll
    for (int m = 32; m >= 1; m >>= 1) s += __shfl_xor(s, m);
    if (lane == 0) lg[b * LAB_ + j] = s + lda(bp2, j, bf);
}

// ---------- head3: log-softmax loss + dual-format output ----------
__global__ __launch_bounds__(192) void head3_kernel(
    const float* __restrict__ lg, const int* __restrict__ tgt,
    void* __restrict__ outv, const int* __restrict__ fl) {
    __shared__ float lse[B_];
    const int bf = fl[0], t = threadIdx.x;
    if (t < B_) {
        float mx = -1e30f;
        for (int j = 0; j < LAB_; ++j) mx = fmaxf(mx, lg[t * LAB_ + j]);
        float s = 0.f;
        for (int j = 0; j < LAB_; ++j) s += expf(lg[t * LAB_ + j] - mx);
        lse[t] = mx + logf(s);
    }
    __syncthreads();
    float loss = 0.f;
    if (t == 0) {
        for (int b = 0; b < B_; ++b) loss += lse[b] - lg[b * LAB_ + tgt[b]];
        loss /= (float)B_;
    }
    if (bf) {
        u16* o = (u16*)outv;
        if (t == 0) o[0] = f2b(loss);
        if (t < B_ * LAB_) o[1 + t] = f2b(lg[t]);
    } else {
        float* o = (float*)outv;
        if (t == 0) o[0] = loss;
        if (t < B_ * LAB_) o[1 + t] = lg[t];
    }
}

// ---------- launch ----------
extern "C" void kernel_launch(void* const* d_in, const int* in_sizes, int n_in,
                              void* d_out, int out_size, void* d_ws, size_t ws_size,
                              hipStream_t stream) {
    (void)in_sizes; (void)n_in; (void)out_size; (void)ws_size;
    const int* src = (const int*)d_in[0];
    const int* seg = (const int*)d_in[1];
    const int* tgt = (const int*)d_in[2];
    const int* tib = (const int*)d_in[3];
    const void* we  = d_in[4];
    const void* pe  = d_in[5];
    const void* se  = d_in[6];
    const void* elg = d_in[7];
    const void* elb = d_in[8];
    const void* Wq  = d_in[9];
    const void* bq  = d_in[10];
    const void* Wk  = d_in[11];
    const void* bk  = d_in[12];
    const void* Wv  = d_in[13];
    const void* bv  = d_in[14];
    const void* Wo  = d_in[15];
    const void* bo  = d_in[16];
    const void* l1g = d_in[17];
    const void* l1b = d_in[18];
    const void* Wf1 = d_in[19];
    const void* bf1 = d_in[20];
    const void* Wf2 = d_in[21];
    const void* bf2 = d_in[22];
    const void* l2g = d_in[23];
    const void* l2b = d_in[24];
    const void* Wp1 = d_in[25];
    const void* bp1 = d_in[26];
    const void* Wp2 = d_in[27];
    const void* bp2 = d_in[28];
    const void* sf  = d_in[29];

    const size_t HH   = (size_t)H_ * H_;        // 589824
    const size_t HFF  = (size_t)H_ * FF_;       // 2359296
    const size_t MH   = (size_t)M_ * H_;        // 6291456
    const size_t MQKV = (size_t)M_ * STRQ;      // 18874368
    const size_t MFF  = (size_t)M_ * FF_;       // 25165824
    const size_t QKVW = (size_t)STRQ * H_;      // 1769472 (per-layer merged weight)

    char* w = (char*)d_ws;
    int* dflag  = (int*)w;  w += 256;
    u16* bias_ws = (u16*)w; w += 41472 * 2;     // prep_bias layout
    u16* WqkvT = (u16*)w;  w += L_ * QKVW * 2;
    u16* WoT   = (u16*)w;  w += L_ * HH  * 2;
    u16* Wf1T  = (u16*)w;  w += L_ * HFF * 2;
    u16* Wf2T  = (u16*)w;  w += L_ * HFF * 2;
    u16* Wp1T  = (u16*)w;  w += HH * 2;
    float* x32 = (float*)w; w += MH * 4;
    u16* xb    = (u16*)w;  w += MH * 2;
    u16* qkvb  = (u16*)w;  w += MQKV * 2;
    u16* ctxb  = (u16*)w;  w += MH * 2;
    u16* tmpb  = (u16*)w;  w += MH * 2;
    u16* ffb   = (u16*)w;  w += MFF * 2;
    u16* hidb  = (u16*)w;  w += (size_t)B_ * H_ * 2;
    float* lg  = (float*)w; w += (size_t)B_ * LAB_ * 4;

    u16* bqkv = bias_ws;            // 6 x 2304
    u16* bo6  = bias_ws + 13824;    // 6 x 768
    u16* bf16_= bias_ws + 18432;    // 6 x 3072
    u16* bf26 = bias_ws + 36864;    // 6 x 768

    const dim3 tb(256);
    detect_kernel<<<1, 1, 0, stream>>>((const u32*)elg, dflag);
    prep_bias<<<162, tb, 0, stream>>>(bq, bk, bv, bo, bf1, bf2, bias_ws, dflag);

    // weight transposes+convert; Wq/Wk/Wv interleave into per-layer 2304x768 blocks
    transpose_k<<<dim3(12, 12, 6), tb, 0, stream>>>(Wq, WqkvT,                    H_, H_, (long)HH, (long)QKVW, dflag);
    transpose_k<<<dim3(12, 12, 6), tb, 0, stream>>>(Wk, WqkvT + (size_t)768*768,  H_, H_, (long)HH, (long)QKVW, dflag);
    transpose_k<<<dim3(12, 12, 6), tb, 0, stream>>>(Wv, WqkvT + (size_t)1536*768, H_, H_, (long)HH, (long)QKVW, dflag);
    transpose_k<<<dim3(12, 12, 6), tb, 0, stream>>>(Wo,  WoT,  H_, H_,  (long)HH,  (long)HH,  dflag);
    transpose_k<<<dim3(48, 12, 6), tb, 0, stream>>>(Wf1, Wf1T, H_, FF_, (long)HFF, (long)HFF, dflag);
    transpose_k<<<dim3(12, 48, 6), tb, 0, stream>>>(Wf2, Wf2T, FF_, H_, (long)HFF, (long)HFF, dflag);
    transpose_k<<<dim3(12, 12, 1), tb, 0, stream>>>(Wp1, Wp1T, H_, H_,  (long)HH,  (long)HH,  dflag);

    embed_kernel<<<M_, tb, 0, stream>>>(src, seg, tib, we, pe, se, elg, elb, sf, x32, xb, dflag);

    for (int l = 0; l < L_; ++l) {
        // QKV: M x 2304 x 768 (BN=128, BK=64, 18x64=1152 blocks)
        gemm_bt<128, 64><<<dim3(STRQ / 128, M_ / 128), tb, 0, stream>>>(xb, WqkvT + l * QKVW, bqkv + l * STRQ, qkvb, M_, STRQ, H_, 0);
        attn_kernel<<<dim3(S_ / 64, NH_, B_), tb, 0, stream>>>(qkvb, seg, ctxb);
        // Wo: M x 768 x 768 (BN=64, BK=128, 12x64=768 blocks -> 3 blocks/CU)
        gemm_bt<64, 128><<<dim3(H_ / 64, M_ / 128), tb, 0, stream>>>(ctxb, WoT + l * HH, bo6 + l * H_, tmpb, M_, H_, H_, 0);
        add_ln_kernel<<<M_, tb, 0, stream>>>(x32, tmpb, l1g, l1b, (long)l * H_, x32, xb, dflag);
        // FF1: M x 3072 x 768 + gelu (BN=128, BK=64, 24x64=1536 blocks)
        gemm_bt<128, 64><<<dim3(FF_ / 128, M_ / 128), tb, 0, stream>>>(xb, Wf1T + l * HFF, bf16_ + l * FF_, ffb, M_, FF_, H_, 1);
        // FF2: M x 768 x 3072 (BN=64, BK=128, 768 blocks, 24 K-steps)
        gemm_bt<64, 128><<<dim3(H_ / 64, M_ / 128), tb, 0, stream>>>(ffb, Wf2T + l * HFF, bf26 + l * H_, tmpb, M_, H_, FF_, 0);
        add_ln_kernel<<<M_, tb, 0, stream>>>(x32, tmpb, l2g, l2b, (long)l * H_, x32, xb, dflag);
    }

    head1_kernel<<<12, tb, 0, stream>>>(xb, Wp1T, bp1, hidb, dflag);
    head2_kernel<<<B_, dim3(640), 0, stream>>>(hidb, Wp2, bp2, lg, dflag);
    head3_kernel<<<1, dim3(192), 0, stream>>>(lg, tgt, d_out, dflag);
}

// Round 9
// 1750.824 us; speedup vs baseline: 1.5612x; 1.0204x over previous
//
#include <hip/hip_runtime.h>

typedef unsigned short u16;
typedef unsigned int   u32;
typedef __bf16  bf16x8 __attribute__((ext_vector_type(8)));
typedef float   f32x4  __attribute__((ext_vector_type(4)));

#define B_   16
#define S_   512
#define H_   768
#define NH_  12
#define L_   6
#define FF_  3072
#define M_   8192     // B_*S_
#define LAB_ 10
#define STRQ 2304     // merged qkv row stride

// ---------- bf16 helpers (storage = u16 bits) ----------
__device__ __forceinline__ float b2f(u16 x) {
    u32 u = ((u32)x) << 16; float f; __builtin_memcpy(&f, &u, 4); return f;
}
__device__ __forceinline__ u16 f2b(float f) {
    u32 u; __builtin_memcpy(&u, &f, 4);
    u32 r = u + 0x7FFFu + ((u >> 16) & 1u);
    return (u16)(r >> 16);
}
__device__ __forceinline__ float lda(const void* p, size_t i, int bf) {
    return bf ? b2f(((const u16*)p)[i]) : ((const float*)p)[i];
}
// gelu tanh-approx reformed as sigmoid: 0.5x(1+tanh(z)) = x/(1+exp(-2z)),
// 2z = 1.5957691216.. * x * (1 + 0.044715 x^2). v_exp + v_rcp (~9 VALU inst)
// vs libm tanhf (~30-50). Saturation safe: exp->inf -> rcp->0 -> gelu=0.
__device__ __forceinline__ float gelu_tanh(float x) {
    float e = __expf(-1.5957691216057308f * x * fmaf(0.044715f, x * x, 1.0f));
    return x * __builtin_amdgcn_rcpf(1.0f + e);
}
// async global->LDS, 16B per lane; LDS dest must be wave-uniform base + lane*16
__device__ __forceinline__ void async_lds16(const u16* g, u16* l) {
    __builtin_amdgcn_global_load_lds(
        (const __attribute__((address_space(1))) u32*)(const void*)g,
        (__attribute__((address_space(3))) u32*)(void*)l, 16, 0, 0);
}

// ---------- dtype detect: emb_ln_g is all ones ----------
__global__ void detect_kernel(const u32* __restrict__ g, int* __restrict__ flag) {
    flag[0] = (g[0] == 0x3F803F80u) ? 1 : 0;   // bf16 ones pair vs fp32 one
}

// ---------- block reduce (sum of two values), 256 threads ----------
__device__ __forceinline__ void block_reduce2(float& s, float& s2, float* red, int tid) {
    int lane = tid & 63, wave = tid >> 6;
    #pragma unroll
    for (int m = 32; m >= 1; m >>= 1) { s += __shfl_xor(s, m); s2 += __shfl_xor(s2, m); }
    if (lane == 0) { red[wave] = s; red[4 + wave] = s2; }
    __syncthreads();
    s  = red[0] + red[1] + red[2] + red[3];
    s2 = red[4] + red[5] + red[6] + red[7];
}

// ---------- weight transpose+convert: in (K x N) -> out bf16 (N x K) ----------
__global__ __launch_bounds__(256) void transpose_k(const void* __restrict__ in,
                                                   u16* __restrict__ out, int K, int N,
                                                   long in_lstride, long out_lstride,
                                                   const int* __restrict__ fl) {
    __shared__ u16 tile[64][65];
    const int bf = fl[0];
    const size_t ioff = (size_t)blockIdx.z * (size_t)in_lstride;
    const size_t ooff = (size_t)blockIdx.z * (size_t)out_lstride;
    int k0 = blockIdx.y * 64, n0 = blockIdx.x * 64;
    int c = threadIdx.x & 63, r0 = threadIdx.x >> 6;
    #pragma unroll
    for (int r = r0; r < 64; r += 4) {
        size_t idx = ioff + (size_t)(k0 + r) * N + n0 + c;
        tile[r][c] = bf ? ((const u16*)in)[idx] : f2b(((const float*)in)[idx]);
    }
    __syncthreads();
    #pragma unroll
    for (int r = r0; r < 64; r += 4)
        out[ooff + (size_t)(n0 + r) * K + k0 + c] = tile[c][r];
}

// ---------- bias prep: convert all GEMM biases to bf16, qkv concatenated ----------
// layout: [0,13824) bqkv (6 x 2304) | [13824,18432) bo | [18432,36864) bf1 | [36864,41472) bf2
__global__ __launch_bounds__(256) void prep_bias(
    const void* __restrict__ bq, const void* __restrict__ bk, const void* __restrict__ bv,
    const void* __restrict__ bo, const void* __restrict__ bf1, const void* __restrict__ bf2,
    u16* __restrict__ out, const int* __restrict__ fl) {
    const int bf = fl[0];
    int i = blockIdx.x * 256 + threadIdx.x;
    if (i >= 41472) return;
    float v;
    if (i < 13824) {
        int l = i / 2304, c = i % 2304;
        v = (c < 768) ? lda(bq, (size_t)l * 768 + c, bf)
          : (c < 1536) ? lda(bk, (size_t)l * 768 + c - 768, bf)
                       : lda(bv, (size_t)l * 768 + c - 1536, bf);
    } else if (i < 18432) v = lda(bo,  i - 13824, bf);
    else if (i < 36864)   v = lda(bf1, i - 18432, bf);
    else                  v = lda(bf2, i - 36864, bf);
    out[i] = f2b(v);
}

// ---------- embedding + LN + selection scale ----------
__global__ __launch_bounds__(256) void embed_kernel(
    const int* __restrict__ src, const int* __restrict__ seg, const int* __restrict__ tib,
    const void* __restrict__ we, const void* __restrict__ pe, const void* __restrict__ se,
    const void* __restrict__ g, const void* __restrict__ bb, const void* __restrict__ sf,
    float* __restrict__ x32, u16* __restrict__ xb, const int* __restrict__ fl) {
    __shared__ float red[8];
    const int bf = fl[0];
    const int r = blockIdx.x, tid = threadIdx.x;
    const int s = r & (S_ - 1);
    const int w = src[r], sg = seg[r];
    const float scale = lda(sf, tib[r], bf);
    float v[3]; int col[3];
    #pragma unroll
    for (int i = 0; i < 3; ++i) {
        col[i] = tid + i * 256;
        v[i] = lda(we, (size_t)w * H_ + col[i], bf) + lda(pe, (size_t)s * H_ + col[i], bf)
             + lda(se, (size_t)sg * H_ + col[i], bf);
    }
    float su = v[0] + v[1] + v[2];
    float sq = v[0]*v[0] + v[1]*v[1] + v[2]*v[2];
    block_reduce2(su, sq, red, tid);
    const float mean = su * (1.0f / H_);
    const float var  = sq * (1.0f / H_) - mean * mean;
    const float inv  = rsqrtf(var + 1e-5f);
    #pragma unroll
    for (int i = 0; i < 3; ++i) {
        float y = ((v[i] - mean) * inv * lda(g, col[i], bf) + lda(bb, col[i], bf)) * scale;
        x32[(size_t)r * H_ + col[i]] = y;
        xb [(size_t)r * H_ + col[i]] = f2b(y);
    }
}

// ---------- residual add + LN (x32 master, bf16 shadow out) ----------
__global__ __launch_bounds__(256) void add_ln_kernel(
    const float* __restrict__ xin, const u16* __restrict__ t,
    const void* __restrict__ g, const void* __restrict__ bb, long goff,
    float* __restrict__ xout, u16* __restrict__ xb, const int* __restrict__ fl) {
    __shared__ float red[8];
    const int bf = fl[0];
    const int r = blockIdx.x, tid = threadIdx.x;
    const size_t rb = (size_t)r * H_;
    float v[3]; int col[3];
    #pragma unroll
    for (int i = 0; i < 3; ++i) {
        col[i] = tid + i * 256;
        v[i] = xin[rb + col[i]] + b2f(t[rb + col[i]]);
    }
    float su = v[0] + v[1] + v[2];
    float sq = v[0]*v[0] + v[1]*v[1] + v[2]*v[2];
    block_reduce2(su, sq, red, tid);
    const float mean = su * (1.0f / H_);
    const float var  = sq * (1.0f / H_) - mean * mean;
    const float inv  = rsqrtf(var + 1e-5f);
    #pragma unroll
    for (int i = 0; i < 3; ++i) {
        float y = (v[i] - mean) * inv * lda(g, goff + col[i], bf) + lda(bb, goff + col[i], bf);
        xout[rb + col[i]] = y;
        xb  [rb + col[i]] = f2b(y);
    }
}

// =====================================================================
// MFMA GEMM (m97-style, 128xBNT tile, BKx per K-step, 256 thr):
// XOR chunk swizzle, XCD-aware chunked block swizzle (T1), LDS-bounce
// coalesced epilogue. BK=128 for the BN=64 (Wo/FF2) path (round-8:
// halves barrier-drain events; 48KB LDS keeps 3 blocks/CU).
// K-accumulation order per output element unchanged -> bit-identical.
// =====================================================================
template<int BNT, int BK>
__global__ __launch_bounds__(256, 3) void gemm_bt(
    const u16* __restrict__ A, const u16* __restrict__ Bt, const u16* __restrict__ bias,
    u16* __restrict__ C, int M, int N, int K, int act) {
    constexpr int NREP = BNT / 32;          // n-frags per wave: 4 or 2
    constexpr int WNE  = BNT / 2;           // wave col span: 64 or 32
    constexpr int CPR  = BK / 8;            // 16B chunks per row: 8 or 16
    constexpr int CSH  = (BK == 128) ? 4 : 3;
    constexpr int KMSK = CPR - 1;
    constexpr int KD   = BK / 32;           // mfma k-frags per step: 2 or 4
    constexpr int ACH  = 128 * CPR / 256;   // A chunks/thread: 4 or 8
    constexpr int BCH  = BNT * CPR / 256;   // B chunks/thread: 4
    __shared__ alignas(16) u16 As[128 * BK];
    __shared__ alignas(16) u16 Bs[BNT * BK];
    const int tid = threadIdx.x;
    // XCD-aware chunked bijective swizzle: ids congruent mod 8 (same XCD)
    // become adjacent tiles; nwg % 8 == 0 for all our grids.
    const int nbx = (int)gridDim.x;
    const int nwg = nbx * (int)gridDim.y;
    const int lin = (int)blockIdx.y * nbx + (int)blockIdx.x;
    const int wg  = (lin & 7) * (nwg >> 3) + (lin >> 3);
    const int bm = (wg / nbx) * 128, bn = (wg % nbx) * BNT;
    const int wave = tid >> 6, lane = tid & 63;
    const int wm = (wave >> 1) * 64, wn = (wave & 1) * WNE;
    const int qd = lane >> 4, l16 = lane & 15;
    const int lk = l16 & KMSK;

    const f32x4 fz = {0.f, 0.f, 0.f, 0.f};
    f32x4 acc[4][NREP];
    #pragma unroll
    for (int i = 0; i < 4; ++i)
        #pragma unroll
        for (int j = 0; j < NREP; ++j) acc[i][j] = fz;

    // staging: tile rows x BK cols; thread covers chunks tid+u*256.
    // LDS dest linear (chunk c at base+c*8); global source chunk = (c&KMSK)^(row&KMSK).
    const u16* Ag[ACH]; int dofsA[ACH];
    #pragma unroll
    for (int u = 0; u < ACH; ++u) {
        const int c = tid + u * 256;
        const int r = c >> CSH;
        const int cs = ((c & KMSK) ^ (r & KMSK)) * 8;
        Ag[u] = A + (size_t)(bm + r) * K + cs;
        dofsA[u] = c * 8;
    }
    const u16* Bg[BCH]; int dofsB[BCH];
    #pragma unroll
    for (int u = 0; u < BCH; ++u) {
        const int c = tid + u * 256;
        const int r = c >> CSH;
        const int cs = ((c & KMSK) ^ (r & KMSK)) * 8;
        Bg[u] = Bt + (size_t)(bn + r) * K + cs;
        dofsB[u] = c * 8;
    }

    for (int k0 = 0; k0 < K; k0 += BK) {
        __syncthreads();               // prev iter's LDS reads complete
        #pragma unroll
        for (int u = 0; u < ACH; ++u) async_lds16(Ag[u] + k0, As + dofsA[u]);
        #pragma unroll
        for (int u = 0; u < BCH; ++u) async_lds16(Bg[u] + k0, Bs + dofsB[u]);
        __syncthreads();               // vmcnt drained by barrier semantics
        bf16x8 af[4][KD], bfv[NREP][KD];
        #pragma unroll
        for (int i = 0; i < 4; ++i)
            #pragma unroll
            for (int kd = 0; kd < KD; ++kd) {
                const int sw = (((kd << 2) | qd) ^ lk) << 3;   // swizzled 16B chunk
                af[i][kd] = *(const bf16x8*)(As + (wm + i * 16 + l16) * BK + sw);
            }
        #pragma unroll
        for (int j = 0; j < NREP; ++j)
            #pragma unroll
            for (int kd = 0; kd < KD; ++kd) {
                const int sw = (((kd << 2) | qd) ^ lk) << 3;
                bfv[j][kd] = *(const bf16x8*)(Bs + (wn + j * 16 + l16) * BK + sw);
            }
        #pragma unroll
        for (int i = 0; i < 4; ++i)
            #pragma unroll
            for (int j = 0; j < NREP; ++j)
                #pragma unroll
                for (int kd = 0; kd < KD; ++kd)
                    acc[i][j] = __builtin_amdgcn_mfma_f32_16x16x32_bf16(af[i][kd], bfv[j][kd], acc[i][j], 0, 0, 0);
    }

    // epilogue: C/D layout col=lane&15, row=(lane>>4)*4+reg.
    // LDS-bounce: scatter fragments to per-wave scratch, read back
    // row-contiguous, store dwordx4 (2 or 1 per i vs 16 scalar).
    float bvj[NREP];
    #pragma unroll
    for (int j = 0; j < NREP; ++j) bvj[j] = b2f(bias[bn + wn + j * 16 + l16]);
    __syncthreads();                       // all waves' K-loop LDS reads done (WAR)
    u16* eb = As + wave * (16 * WNE);      // per-wave scratch (<= 8KB total)
    const int er  = lane >> 2;             // 0..15 local row
    const int ecb = (lane & 3) * (WNE / 4);// u16 col base for read-back
    #pragma unroll
    for (int i = 0; i < 4; ++i) {
        #pragma unroll
        for (int j = 0; j < NREP; ++j)
            #pragma unroll
            for (int r = 0; r < 4; ++r) {
                float v = acc[i][j][r] + bvj[j];
                if (act == 1) v = gelu_tanh(v);
                eb[(qd * 4 + r) * WNE + j * 16 + l16] = f2b(v);
            }
        asm volatile("s_waitcnt lgkmcnt(0)" ::: "memory");   // writes visible (in-wave)
        u16* cp = C + (size_t)(bm + wm + i * 16 + er) * N + bn + wn + ecb;
        if constexpr (BNT == 128) {
            uint4 v0 = *(const uint4*)(eb + er * 64 + ecb);
            uint4 v1 = *(const uint4*)(eb + er * 64 + ecb + 8);
            *(uint4*)cp = v0;
            *(uint4*)(cp + 8) = v1;
        } else {
            uint4 v0 = *(const uint4*)(eb + er * 32 + ecb);
            *(uint4*)cp = v0;
        }
        asm volatile("s_waitcnt lgkmcnt(0)" ::: "memory");   // reads done before next i writes
    }
}

// ---------- flash attention: 64 queries/block, online softmax, MFMA QK^T and PV ----------
// Round-9: (1) XCD-group swizzle -- 1D grid, lin = (g%8) + 8*qt + 64*(g/8),
// g = h + 12*b: all 8 qt-blocks sharing one (b,h) K/V panel land on the
// SAME XCD (round-8 counters: FETCH 104MB vs 38MB unique = 2.8x over-fetch
// from K/V panels round-robined across 8 XCD L2s). Pure reorder.
// (2) 3rd barrier removed: Ps rows [wave*16, wave*16+16) are wave-private
// (written and read by the same wave only); explicit lgkmcnt(0) orders the
// in-wave ds_write->ds_read. Vt/Ks safety carried by top-of-loop barrier.
__global__ __launch_bounds__(256) void attn_kernel(
    const u16* __restrict__ QKV, const int* __restrict__ seg, u16* __restrict__ Cb) {
    __shared__ alignas(16) u16 Qs[64 * 64];     // [q][d] chunk-swizzled
    __shared__ alignas(16) u16 Ks[128 * 64];    // [key][d] chunk-swizzled
    __shared__ alignas(16) u16 Vt[64 * 136];    // [d][key] with 16B-block xor swizzle
    __shared__ alignas(16) u16 Ps[64 * 136];    // [q][key] (wave-private 16-row bands)
    __shared__ float biasv[512];
    const int tid = threadIdx.x;
    // XCD-group decode: lin = (g%8) + 8*qt + 64*(g/8), g = h + 12*b
    const int lin = (int)blockIdx.x;
    const int qt  = (lin >> 3) & 7;
    const int g   = (lin >> 6) * 8 + (lin & 7);
    const int h   = g % 12, b = g / 12;
    const int wave = tid >> 6, lane = tid & 63;
    const int qd = lane >> 4, l16 = lane & 15;
    const int l7 = l16 & 7;
    const u16* Qg = QKV + (size_t)b * S_ * STRQ + h * 64;
    const u16* Kg = Qg + 768;
    const u16* Vg = Qg + 1536;

    // async-stage Q tile 64x64 (2 chunks/thread, source pre-XOR-swizzled)
    #pragma unroll
    for (int u = 0; u < 2; ++u) {
        const int c = tid + u * 256, r = c >> 3;
        const int cs = ((c & 7) ^ (r & 7)) * 8;
        async_lds16(Qg + (size_t)(qt * 64 + r) * STRQ + cs, Qs + c * 8);
    }

    for (int i = tid; i < 512; i += 256)
        biasv[i] = (seg[b * S_ + i] > 0) ? 0.0f : -1e9f;

    float m_run[4], l_run[4];
    f32x4 accO[4];
    #pragma unroll
    for (int r = 0; r < 4; ++r) { m_run[r] = -3.0e38f; l_run[r] = 0.f; }
    #pragma unroll
    for (int dt = 0; dt < 4; ++dt) accO[dt] = {0.f, 0.f, 0.f, 0.f};

    for (int kt = 0; kt < 512; kt += 128) {
        __syncthreads();                       // prev iter's Ks/Vt/Ps reads complete
        {   // async-stage K tile 128x64 (4 chunks/thread)
            #pragma unroll
            for (int u = 0; u < 4; ++u) {
                const int c = tid + u * 256, r = c >> 3;
                const int cs = ((c & 7) ^ (r & 7)) * 8;
                async_lds16(Kg + (size_t)(kt + r) * STRQ + cs, Ks + c * 8);
            }
        }
        {   // stage V tile transposed: Vt[d][key], key-block xor-swizzled (1024 items)
            int c = tid;
            #pragma unroll
            for (int u = 0; u < 4; ++u, c += 256) {
                int r = c >> 3, d8 = (c & 7) * 8;
                uint4 v4 = *(const uint4*)(Vg + (size_t)(kt + r) * STRQ + d8);
                u16 tmp[8]; *(uint4*)tmp = v4;
                #pragma unroll
                for (int j = 0; j < 8; ++j) {
                    int d = d8 + j;
                    int blk = (r >> 3) ^ (d >> 3);
                    Vt[d * 136 + blk * 8 + (r & 7)] = tmp[j];
                }
            }
        }
        __syncthreads();

        // ---- QK^T: wave owns q rows wave*16..+15, all 128 keys ----
        f32x4 s[8];
        {
            bf16x8 aq[2];
            #pragma unroll
            for (int kd = 0; kd < 2; ++kd)
                aq[kd] = *(const bf16x8*)(Qs + (wave * 16 + l16) * 64 + ((((kd << 2) | qd) ^ l7) << 3));
            __builtin_amdgcn_s_setprio(1);
            #pragma unroll
            for (int nt = 0; nt < 8; ++nt) {
                s[nt] = {0.f, 0.f, 0.f, 0.f};
                #pragma unroll
                for (int kd = 0; kd < 2; ++kd) {
                    bf16x8 bk = *(const bf16x8*)(Ks + (nt * 16 + l16) * 64 + ((((kd << 2) | qd) ^ l7) << 3));
                    s[nt] = __builtin_amdgcn_mfma_f32_16x16x32_bf16(aq[kd], bk, s[nt], 0, 0, 0);
                }
            }
            __builtin_amdgcn_s_setprio(0);
        }
        // scale + mask bias (bias depends on key = col = nt*16+l16)
        #pragma unroll
        for (int nt = 0; nt < 8; ++nt) {
            const float bv = biasv[kt + nt * 16 + l16];
            #pragma unroll
            for (int r = 0; r < 4; ++r) s[nt][r] = s[nt][r] * 0.125f + bv;
        }
        // online softmax: rows live in (qd, r); reduce across 16 l16 lanes
        float alpha[4], rsum[4];
        #pragma unroll
        for (int r = 0; r < 4; ++r) {
            float m = s[0][r];
            #pragma unroll
            for (int nt = 1; nt < 8; ++nt) m = fmaxf(m, s[nt][r]);
            #pragma unroll
            for (int msk = 8; msk >= 1; msk >>= 1) m = fmaxf(m, __shfl_xor(m, msk));
            float mn = fmaxf(m_run[r], m);
            alpha[r] = __expf(m_run[r] - mn);
            m_run[r] = mn;
            rsum[r] = 0.f;
        }
        #pragma unroll
        for (int nt = 0; nt < 8; ++nt)
            #pragma unroll
            for (int r = 0; r < 4; ++r) {
                float p = __expf(s[nt][r] - m_run[r]);
                rsum[r] += p;
                Ps[(wave * 16 + qd * 4 + r) * 136 + nt * 16 + l16] = f2b(p);
            }
        #pragma unroll
        for (int r = 0; r < 4; ++r) {
            float t = rsum[r];
            #pragma unroll
            for (int msk = 8; msk >= 1; msk >>= 1) t += __shfl_xor(t, msk);
            l_run[r] = l_run[r] * alpha[r] + t;
        }
        #pragma unroll
        for (int dt = 0; dt < 4; ++dt)
            #pragma unroll
            for (int r = 0; r < 4; ++r) accO[dt][r] *= alpha[r];
        // no block barrier: Ps band is wave-private; order in-wave write->read
        asm volatile("s_waitcnt lgkmcnt(0)" ::: "memory");

        // ---- PV: O(16x64) += P(16x128) @ V(128x64) ----
        __builtin_amdgcn_s_setprio(1);
        #pragma unroll
        for (int kk = 0; kk < 4; ++kk) {
            bf16x8 ap = *(const bf16x8*)(Ps + (wave * 16 + l16) * 136 + kk * 32 + qd * 8);
            #pragma unroll
            for (int dt = 0; dt < 4; ++dt) {
                const int d = dt * 16 + l16;
                const int blk = (kk * 4 + qd) ^ (d >> 3);
                bf16x8 bv = *(const bf16x8*)(Vt + d * 136 + blk * 8);
                accO[dt] = __builtin_amdgcn_mfma_f32_16x16x32_bf16(ap, bv, accO[dt], 0, 0, 0);
            }
        }
        __builtin_amdgcn_s_setprio(0);
    }

    // epilogue: normalize and write ctx [row][h*64+d]
    #pragma unroll
    for (int r = 0; r < 4; ++r) {
        const int row = qt * 64 + wave * 16 + qd * 4 + r;
        const float inv = 1.0f / l_run[r];
        const size_t obase = ((size_t)b * S_ + row) * H_ + h * 64;
        #pragma unroll
        for (int dt = 0; dt < 4; ++dt)
            Cb[obase + dt * 16 + l16] = f2b(accO[dt][r] * inv);
    }
}

// ---------- head1: hid = tanh(pooled @ Wp1 + bp1) via MFMA, one wave per 16x16 tile ----------
__global__ __launch_bounds__(256) void head1_kernel(
    const u16* __restrict__ xb, const u16* __restrict__ Wp1T,
    const void* __restrict__ bp1, u16* __restrict__ hidb, const int* __restrict__ fl) {
    __shared__ alignas(16) u16 Xs[16 * 776];     // stride 776 breaks 16-way bank alias
    const int bf = fl[0];
    const int tid = threadIdx.x, wave = tid >> 6, lane = tid & 63;
    const int qd = lane >> 4, l16 = lane & 15;
    for (int i = tid; i < 16 * 96; i += 256) {   // 96 uint4 per pooled row
        int b = i / 96, c = (i % 96) * 8;
        *(uint4*)(Xs + b * 776 + c) = *(const uint4*)(xb + ((size_t)b * S_) * H_ + c);
    }
    __syncthreads();
    const int n0 = (blockIdx.x * 4 + wave) * 16;
    f32x4 acc = {0.f, 0.f, 0.f, 0.f};
    for (int k0 = 0; k0 < H_; k0 += 32) {
        bf16x8 a  = *(const bf16x8*)(Xs + l16 * 776 + k0 + qd * 8);
        bf16x8 bb = *(const bf16x8*)(Wp1T + (size_t)(n0 + l16) * H_ + k0 + qd * 8);
        acc = __builtin_amdgcn_mfma_f32_16x16x32_bf16(a, bb, acc, 0, 0, 0);
    }
    // C/D: col=l16 (j), row=qd*4+r (batch)
    #pragma unroll
    for (int r = 0; r < 4; ++r) {
        const int b = qd * 4 + r, j = n0 + l16;
        hidb[b * H_ + j] = f2b(tanhf(acc[r] + lda(bp1, j, bf)));
    }
}

// ---------- head2: logits, wave per (batch, label) ----------
__global__ __launch_bounds__(640) void head2_kernel(
    const u16* __restrict__ hidb, const void* __restrict__ Wp2, const void* __restrict__ bp2,
    float* __restrict__ lg, const int* __restrict__ fl) {
    const int bf = fl[0];
    const int b = blockIdx.x, j = threadIdx.x >> 6, lane = threadIdx.x & 63;
    float s = 0.f;
    for (int k = lane; k < H_; k += 64)
        s += b2f(hidb[b * H_ + k]) * lda(Wp2, (size_t)k * LAB_ + j, bf);
    #pragma unroll
    for (int m = 32; m >= 1; m >>= 1) s += __shfl_xor(s, m);
    if (lane == 0) lg[b * LAB_ + j] = s + lda(bp2, j, bf);
}

// ---------- head3: log-softmax loss + dual-format output ----------
__global__ __launch_bounds__(192) void head3_kernel(
    const float* __restrict__ lg, const int* __restrict__ tgt,
    void* __restrict__ outv, const int* __restrict__ fl) {
    __shared__ float lse[B_];
    const int bf = fl[0], t = threadIdx.x;
    if (t < B_) {
        float mx = -1e30f;
        for (int j = 0; j < LAB_; ++j) mx = fmaxf(mx, lg[t * LAB_ + j]);
        float s = 0.f;
        for (int j = 0; j < LAB_; ++j) s += expf(lg[t * LAB_ + j] - mx);
        lse[t] = mx + logf(s);
    }
    __syncthreads();
    float loss = 0.f;
    if (t == 0) {
        for (int b = 0; b < B_; ++b) loss += lse[b] - lg[b * LAB_ + tgt[b]];
        loss /= (float)B_;
    }
    if (bf) {
        u16* o = (u16*)outv;
        if (t == 0) o[0] = f2b(loss);
        if (t < B_ * LAB_) o[1 + t] = f2b(lg[t]);
    } else {
        float* o = (float*)outv;
        if (t == 0) o[0] = loss;
        if (t < B_ * LAB_) o[1 + t] = lg[t];
    }
}

// ---------- launch ----------
extern "C" void kernel_launch(void* const* d_in, const int* in_sizes, int n_in,
                              void* d_out, int out_size, void* d_ws, size_t ws_size,
                              hipStream_t stream) {
    (void)in_sizes; (void)n_in; (void)out_size; (void)ws_size;
    const int* src = (const int*)d_in[0];
    const int* seg = (const int*)d_in[1];
    const int* tgt = (const int*)d_in[2];
    const int* tib = (const int*)d_in[3];
    const void* we  = d_in[4];
    const void* pe  = d_in[5];
    const void* se  = d_in[6];
    const void* elg = d_in[7];
    const void* elb = d_in[8];
    const void* Wq  = d_in[9];
    const void* bq  = d_in[10];
    const void* Wk  = d_in[11];
    const void* bk  = d_in[12];
    const void* Wv  = d_in[13];
    const void* bv  = d_in[14];
    const void* Wo  = d_in[15];
    const void* bo  = d_in[16];
    const void* l1g = d_in[17];
    const void* l1b = d_in[18];
    const void* Wf1 = d_in[19];
    const void* bf1 = d_in[20];
    const void* Wf2 = d_in[21];
    const void* bf2 = d_in[22];
    const void* l2g = d_in[23];
    const void* l2b = d_in[24];
    const void* Wp1 = d_in[25];
    const void* bp1 = d_in[26];
    const void* Wp2 = d_in[27];
    const void* bp2 = d_in[28];
    const void* sf  = d_in[29];

    const size_t HH   = (size_t)H_ * H_;        // 589824
    const size_t HFF  = (size_t)H_ * FF_;       // 2359296
    const size_t MH   = (size_t)M_ * H_;        // 6291456
    const size_t MQKV = (size_t)M_ * STRQ;      // 18874368
    const size_t MFF  = (size_t)M_ * FF_;       // 25165824
    const size_t QKVW = (size_t)STRQ * H_;      // 1769472 (per-layer merged weight)

    char* w = (char*)d_ws;
    int* dflag  = (int*)w;  w += 256;
    u16* bias_ws = (u16*)w; w += 41472 * 2;     // prep_bias layout
    u16* WqkvT = (u16*)w;  w += L_ * QKVW * 2;
    u16* WoT   = (u16*)w;  w += L_ * HH  * 2;
    u16* Wf1T  = (u16*)w;  w += L_ * HFF * 2;
    u16* Wf2T  = (u16*)w;  w += L_ * HFF * 2;
    u16* Wp1T  = (u16*)w;  w += HH * 2;
    float* x32 = (float*)w; w += MH * 4;
    u16* xb    = (u16*)w;  w += MH * 2;
    u16* qkvb  = (u16*)w;  w += MQKV * 2;
    u16* ctxb  = (u16*)w;  w += MH * 2;
    u16* tmpb  = (u16*)w;  w += MH * 2;
    u16* ffb   = (u16*)w;  w += MFF * 2;
    u16* hidb  = (u16*)w;  w += (size_t)B_ * H_ * 2;
    float* lg  = (float*)w; w += (size_t)B_ * LAB_ * 4;

    u16* bqkv = bias_ws;            // 6 x 2304
    u16* bo6  = bias_ws + 13824;    // 6 x 768
    u16* bf16_= bias_ws + 18432;    // 6 x 3072
    u16* bf26 = bias_ws + 36864;    // 6 x 768

    const dim3 tb(256);
    detect_kernel<<<1, 1, 0, stream>>>((const u32*)elg, dflag);
    prep_bias<<<162, tb, 0, stream>>>(bq, bk, bv, bo, bf1, bf2, bias_ws, dflag);

    // weight transposes+convert; Wq/Wk/Wv interleave into per-layer 2304x768 blocks
    transpose_k<<<dim3(12, 12, 6), tb, 0, stream>>>(Wq, WqkvT,                    H_, H_, (long)HH, (long)QKVW, dflag);
    transpose_k<<<dim3(12, 12, 6), tb, 0, stream>>>(Wk, WqkvT + (size_t)768*768,  H_, H_, (long)HH, (long)QKVW, dflag);
    transpose_k<<<dim3(12, 12, 6), tb, 0, stream>>>(Wv, WqkvT + (size_t)1536*768, H_, H_, (long)HH, (long)QKVW, dflag);
    transpose_k<<<dim3(12, 12, 6), tb, 0, stream>>>(Wo,  WoT,  H_, H_,  (long)HH,  (long)HH,  dflag);
    transpose_k<<<dim3(48, 12, 6), tb, 0, stream>>>(Wf1, Wf1T, H_, FF_, (long)HFF, (long)HFF, dflag);
    transpose_k<<<dim3(12, 48, 6), tb, 0, stream>>>(Wf2, Wf2T, FF_, H_, (long)HFF, (long)HFF, dflag);
    transpose_k<<<dim3(12, 12, 1), tb, 0, stream>>>(Wp1, Wp1T, H_, H_,  (long)HH,  (long)HH,  dflag);

    embed_kernel<<<M_, tb, 0, stream>>>(src, seg, tib, we, pe, se, elg, elb, sf, x32, xb, dflag);

    for (int l = 0; l < L_; ++l) {
        // QKV: M x 2304 x 768 (BN=128, BK=64, 18x64=1152 blocks)
        gemm_bt<128, 64><<<dim3(STRQ / 128, M_ / 128), tb, 0, stream>>>(xb, WqkvT + l * QKVW, bqkv + l * STRQ, qkvb, M_, STRQ, H_, 0);
        // attn: 1D grid 1536 with XCD-group swizzle (same-(b,h) qt-blocks -> same XCD)
        attn_kernel<<<dim3((S_ / 64) * NH_ * B_), tb, 0, stream>>>(qkvb, seg, ctxb);
        // Wo: M x 768 x 768 (BN=64, BK=128, 12x64=768 blocks -> 3 blocks/CU)
        gemm_bt<64, 128><<<dim3(H_ / 64, M_ / 128), tb, 0, stream>>>(ctxb, WoT + l * HH, bo6 + l * H_, tmpb, M_, H_, H_, 0);
        add_ln_kernel<<<M_, tb, 0, stream>>>(x32, tmpb, l1g, l1b, (long)l * H_, x32, xb, dflag);
        // FF1: M x 3072 x 768 + gelu (BN=128, BK=64, 24x64=1536 blocks)
        gemm_bt<128, 64><<<dim3(FF_ / 128, M_ / 128), tb, 0, stream>>>(xb, Wf1T + l * HFF, bf16_ + l * FF_, ffb, M_, FF_, H_, 1);
        // FF2: M x 768 x 3072 (BN=64, BK=128, 768 blocks, 24 K-steps)
        gemm_bt<64, 128><<<dim3(H_ / 64, M_ / 128), tb, 0, stream>>>(ffb, Wf2T + l * HFF, bf26 + l * H_, tmpb, M_, H_, FF_, 0);
        add_ln_kernel<<<M_, tb, 0, stream>>>(x32, tmpb, l2g, l2b, (long)l * H_, x32, xb, dflag);
    }

    head1_kernel<<<12, tb, 0, stream>>>(xb, Wp1T, bp1, hidb, dflag);
    head2_kernel<<<B_, dim3(640), 0, stream>>>(hidb, Wp2, bp2, lg, dflag);
    head3_kernel<<<1, dim3(192), 0, stream>>>(lg, tgt, d_out, dflag);
}